// Round 5
// baseline (1359.728 us; speedup 1.0000x reference)
//
#include <hip/hip_runtime.h>
#include <math.h>

#define BB    32
#define CCH   64
#define DIMN  1024
#define NCLS  10

typedef __attribute__((ext_vector_type(8))) short bf16x8;
typedef __attribute__((ext_vector_type(4))) float f32x4;
typedef __attribute__((ext_vector_type(4))) unsigned short us4;
typedef __attribute__((ext_vector_type(8))) unsigned short us8;

#define MFMA16(a, b, c) __builtin_amdgcn_mfma_f32_16x16x32_bf16(a, b, c, 0, 0, 0)

__device__ __forceinline__ unsigned short f2bf(float x) {
  unsigned u = __float_as_uint(x);
  unsigned r = u + 0x7fffu + ((u >> 16) & 1u);   // round-to-nearest-even
  return (unsigned short)(r >> 16);
}
__device__ __forceinline__ float bf2f(unsigned short h) {
  return __uint_as_float(((unsigned)h) << 16);
}
// x == h + m + l to ~2^-26 relative (software path, used by qkv kernels)
__device__ __forceinline__ void split3(float x, unsigned short& h,
                                       unsigned short& m, unsigned short& l) {
  h = f2bf(x); float hf = bf2f(h);
  float r = x - hf;
  m = f2bf(r); float mf = bf2f(m);
  l = f2bf(r - mf);
}
// packed split3 of TWO floats via v_cvt_pk_bf16_f32 (hardware RNE == f2bf)
__device__ __forceinline__ void split3_pk(float x0, float x1,
                                          unsigned& hp, unsigned& mp,
                                          unsigned& lp) {
  unsigned h, m, l;
  asm("v_cvt_pk_bf16_f32 %0, %1, %2" : "=v"(h) : "v"(x0), "v"(x1));
  const float h0 = __uint_as_float(h << 16);
  const float h1 = __uint_as_float(h & 0xffff0000u);
  const float r0 = x0 - h0, r1 = x1 - h1;
  asm("v_cvt_pk_bf16_f32 %0, %1, %2" : "=v"(m) : "v"(r0), "v"(r1));
  const float m0 = __uint_as_float(m << 16);
  const float m1 = __uint_as_float(m & 0xffff0000u);
  asm("v_cvt_pk_bf16_f32 %0, %1, %2" : "=v"(l) : "v"(r0 - m0), "v"(r1 - m1));
  hp = h; mp = m; lp = l;
}
// 8-element fragment split using the packed path (4x split3_pk)
__device__ __forceinline__ void split3_frag(const float* xv, bf16x8& fh,
                                            bf16x8& fm, bf16x8& fl) {
  union U { bf16x8 v; unsigned d[4]; } uh, um, ul;
  #pragma unroll
  for (int p = 0; p < 4; ++p)
    split3_pk(xv[2 * p], xv[2 * p + 1], uh.d[p], um.d[p], ul.d[p]);
  fh = uh.v; fm = um.v; fl = ul.v;
}
__device__ __forceinline__ bf16x8 ld16B(const unsigned short* p) {
  union { us8 u; bf16x8 v; } c;
  c.u = *(const us8*)p;           // 16B-aligned vector load
  return c.v;
}

// ---------------------------------------------------------------------------
// 1) transpose: image (B,C,DIM) -> X (B,DIM,C)
// ---------------------------------------------------------------------------
__global__ __launch_bounds__(256) void k_transpose(const float* __restrict__ img,
                                                   float* __restrict__ X) {
  __shared__ float tile[64][65];
  const int b  = blockIdx.y;
  const int n0 = blockIdx.x * 64;
  const int tx = threadIdx.x & 63;
  const int ty = threadIdx.x >> 6;
  const float* src = img + (size_t)b * CCH * DIMN;
  #pragma unroll
  for (int c = ty; c < 64; c += 4)
    tile[c][tx] = src[(size_t)c * DIMN + n0 + tx];
  __syncthreads();
  float* dst = X + (size_t)b * DIMN * CCH;
  #pragma unroll
  for (int nn = ty; nn < 64; nn += 4)
    dst[(size_t)(n0 + nn) * CCH + tx] = tile[tx][nn];
}

// ---------------------------------------------------------------------------
// 2) QKV + per-layer pre-split: Q fp32; K 3-term bf16 [t][c];
//    V 3-term bf16 transposed+tiled [b][kt][c][32], columns sigma-permuted:
//    token T (bits c,h1h0,i1i0) -> col (h1h0,c,i1i0) so attention's PV
//    A-fragment is the lane's own P values in-order (no redistribution).
// ---------------------------------------------------------------------------
__global__ __launch_bounds__(256) void k_qkv_split(
    const float* __restrict__ X,
    const float* __restrict__ WQ, const float* __restrict__ WK,
    const float* __restrict__ WV,
    float* __restrict__ Q,
    unsigned short* __restrict__ Kh, unsigned short* __restrict__ Km,
    unsigned short* __restrict__ Kl,
    unsigned short* __restrict__ VhT, unsigned short* __restrict__ VmT,
    unsigned short* __restrict__ VlT) {
  __shared__ float xs[16][64];
  __shared__ unsigned short vs[3][16][64];
  const int c  = threadIdx.x & 63;
  const int tg = threadIdx.x >> 6;
  const size_t t0 = (size_t)blockIdx.x * 16;
  #pragma unroll
  for (int r = tg; r < 16; r += 4)
    xs[r][c] = X[(t0 + r) * 64 + c];
  __syncthreads();
  float qa[4] = {0.f,0.f,0.f,0.f};
  float ka[4] = {0.f,0.f,0.f,0.f};
  float va[4] = {0.f,0.f,0.f,0.f};
  for (int j = 0; j < 64; ++j) {
    const float wq = WQ[j * 64 + c];
    const float wk = WK[j * 64 + c];
    const float wv = WV[j * 64 + c];
    #pragma unroll
    for (int r = 0; r < 4; ++r) {
      const float x = xs[tg * 4 + r][j];
      qa[r] = fmaf(x, wq, qa[r]);
      ka[r] = fmaf(x, wk, ka[r]);
      va[r] = fmaf(x, wv, va[r]);
    }
  }
  #pragma unroll
  for (int r = 0; r < 4; ++r) {
    const int t = tg * 4 + r;
    const size_t idx = (t0 + t) * 64 + c;
    Q[idx] = qa[r];
    unsigned short h, m, l;
    split3(ka[r], h, m, l);
    Kh[idx] = h; Km[idx] = m; Kl[idx] = l;
    split3(va[r], h, m, l);
    vs[0][t][c] = h; vs[1][t][c] = m; vs[2][t][c] = l;
  }
  __syncthreads();
  {
    const int row  = threadIdx.x >> 2;
    const int part = threadIdx.x & 3;
    const size_t bofs = (t0 >> 10) * ((size_t)DIMN * 64);
    const size_t kt   = (t0 & 1023) >> 5;
    const size_t tin  = (size_t)part * 8 + ((t0 & 31) >> 2);   // sigma permute
    unsigned short* dst[3] = {VhT, VmT, VlT};
    #pragma unroll
    for (int term = 0; term < 3; ++term) {
      us4 pk;
      #pragma unroll
      for (int i = 0; i < 4; ++i) pk[i] = vs[term][part * 4 + i][row];
      *(us4*)&dst[term][bofs + kt * 2048 + (size_t)row * 32 + tin] = pk;
    }
  }
}

// ---------------------------------------------------------------------------
// 2b) QKV with FUSED 2-way SPLIT-K MERGE of the previous layer.
// ---------------------------------------------------------------------------
__global__ __launch_bounds__(256) void k_qkv_merge(
    float* __restrict__ X,
    const float* __restrict__ Mp, const float* __restrict__ Lp,
    const float* __restrict__ Op,
    const float* __restrict__ WQ, const float* __restrict__ WK,
    const float* __restrict__ WV,
    float* __restrict__ Q,
    unsigned short* __restrict__ Kh, unsigned short* __restrict__ Km,
    unsigned short* __restrict__ Kl,
    unsigned short* __restrict__ VhT, unsigned short* __restrict__ VmT,
    unsigned short* __restrict__ VlT) {
  __shared__ float xs[16][64];
  __shared__ unsigned short vs[3][16][64];
  const int c  = threadIdx.x & 63;
  const int tg = threadIdx.x >> 6;
  const size_t t0 = (size_t)blockIdx.x * 16;
  #pragma unroll
  for (int r = tg; r < 16; r += 4) {
    const size_t grow = t0 + r;                 // global row 0..32767
    const float m0 = Mp[grow], m1 = Mp[32768 + grow];
    const float l0 = Lp[grow], l1 = Lp[32768 + grow];
    const float mm = fmaxf(m0, m1);
    const float w0 = __expf(m0 - mm), w1 = __expf(m1 - mm);
    const float inv = 1.0f / (l0 * w0 + l1 * w1);
    const float o0 = Op[grow * 64 + c];
    const float o1 = Op[(size_t)2097152 + grow * 64 + c];
    const float xn = X[grow * 64 + c] + (o0 * w0 + o1 * w1) * inv;
    X[grow * 64 + c] = xn;
    xs[r][c] = xn;
  }
  __syncthreads();
  float qa[4] = {0.f,0.f,0.f,0.f};
  float ka[4] = {0.f,0.f,0.f,0.f};
  float va[4] = {0.f,0.f,0.f,0.f};
  for (int j = 0; j < 64; ++j) {
    const float wq = WQ[j * 64 + c];
    const float wk = WK[j * 64 + c];
    const float wv = WV[j * 64 + c];
    #pragma unroll
    for (int r = 0; r < 4; ++r) {
      const float x = xs[tg * 4 + r][j];
      qa[r] = fmaf(x, wq, qa[r]);
      ka[r] = fmaf(x, wk, ka[r]);
      va[r] = fmaf(x, wv, va[r]);
    }
  }
  #pragma unroll
  for (int r = 0; r < 4; ++r) {
    const int t = tg * 4 + r;
    const size_t idx = (t0 + t) * 64 + c;
    Q[idx] = qa[r];
    unsigned short h, m, l;
    split3(ka[r], h, m, l);
    Kh[idx] = h; Km[idx] = m; Kl[idx] = l;
    split3(va[r], h, m, l);
    vs[0][t][c] = h; vs[1][t][c] = m; vs[2][t][c] = l;
  }
  __syncthreads();
  {
    const int row  = threadIdx.x >> 2;
    const int part = threadIdx.x & 3;
    const size_t bofs = (t0 >> 10) * ((size_t)DIMN * 64);
    const size_t kt   = (t0 & 1023) >> 5;
    const size_t tin  = (size_t)part * 8 + ((t0 & 31) >> 2);   // sigma permute
    unsigned short* dst[3] = {VhT, VmT, VlT};
    #pragma unroll
    for (int term = 0; term < 3; ++term) {
      us4 pk;
      #pragma unroll
      for (int i = 0; i < 4; ++i) pk[i] = vs[term][part * 4 + i][row];
      *(us4*)&dst[term][bofs + kt * 2048 + (size_t)row * 32 + tin] = pk;
    }
  }
}

// ---------------------------------------------------------------------------
// 3) MFMA flash attention, SPLIT-K (2 halves), SWAPPED QK^T, NO LDS:
//    K/V fragments are read directly from global (16B/lane, coalesced,
//    L1-resident 24KB/tile shared by all 4 waves). No __syncthreads in the
//    kernel at all -> waves free-run; the stage->barrier->read serialization
//    is gone. Arithmetic bit-identical to round 4 (same operands, same MFMA
//    order; only the data path changed).
// ---------------------------------------------------------------------------
__global__ __launch_bounds__(256, 4) void k_attn_sk(
    const float* __restrict__ Qg,
    const unsigned short* __restrict__ Kh, const unsigned short* __restrict__ Km,
    const unsigned short* __restrict__ Kl,
    const unsigned short* __restrict__ VhT, const unsigned short* __restrict__ VmT,
    const unsigned short* __restrict__ VlT,
    float* __restrict__ Mp, float* __restrict__ Lp, float* __restrict__ Op) {
  const int tid  = threadIdx.x;
  const int w    = tid >> 6;
  const int lane = tid & 63;
  const int ln   = lane & 15;
  const int q    = lane >> 4;

  // XCD-aware swizzle: 1024 blocks; batch pinned to one XCD (locality only)
  const int bid   = blockIdx.x;            // 0..1023
  const int xcd   = bid & 7;
  const int seq   = bid >> 3;              // 0..127
  const int b     = xcd * 4 + (seq >> 5);  // 4 batches per XCD
  const int local = seq & 31;
  const int half  = local >> 4;            // K-split half
  const int i0    = (local & 15) * 64;     // Q tile

  const size_t base = (size_t)b * (DIMN * 64);
  const float scale = 0.03125f;

  // ---- Q fragments: 3-term split (packed), 2 k-chunks (once per block) -----
  bf16x8 qh[2], qm[2], ql[2];
  {
    const int mrow = i0 + 16 * w + ln;
    const float* qp = Qg + base + (size_t)mrow * 64 + 8 * q;
    #pragma unroll
    for (int s = 0; s < 2; ++s) {
      const float4 x0 = ((const float4*)(qp + 32 * s))[0];
      const float4 x1 = ((const float4*)(qp + 32 * s))[1];
      const float xv[8] = {x0.x, x0.y, x0.z, x0.w, x1.x, x1.y, x1.z, x1.w};
      split3_frag(xv, qh[s], qm[s], ql[s]);
    }
  }

  f32x4 O[4];
  #pragma unroll
  for (int ct = 0; ct < 4; ++ct) O[ct] = (f32x4){0.f, 0.f, 0.f, 0.f};
  float m_run = -INFINITY;      // per Q-token (col = ln)
  float l_run = 0.f;

  const int kt0 = half * 16;
  for (int kt = kt0; kt < kt0 + 16; ++kt) {
    const size_t kb = base + (size_t)kt * 2048;   // tile base (shorts)

    // ---- S strip = mfma(K, Q): K fragments straight from global ------------
    f32x4 sacc[2];
    #pragma unroll
    for (int ct = 0; ct < 2; ++ct) {
      f32x4 a = (f32x4){0.f, 0.f, 0.f, 0.f};
      #pragma unroll
      for (int s = 0; s < 2; ++s) {
        const size_t ko = kb + (size_t)(16 * ct + ln) * 64 + 32 * s + 8 * q;
        const bf16x8 bh = ld16B(&Kh[ko]);
        const bf16x8 bm = ld16B(&Km[ko]);
        const bf16x8 bl = ld16B(&Kl[ko]);
        a = MFMA16(bh, ql[s], a);
        a = MFMA16(bl, qh[s], a);
        a = MFMA16(bm, qm[s], a);
        a = MFMA16(bh, qm[s], a);
        a = MFMA16(bm, qh[s], a);
        a = MFMA16(bh, qh[s], a);
      }
      sacc[ct] = a;
    }

    // ---- online softmax, per Q-token (one token per lane) ------------------
    float m8 = fmaxf(fmaxf(fmaxf(sacc[0][0], sacc[0][1]),
                           fmaxf(sacc[0][2], sacc[0][3])),
                     fmaxf(fmaxf(sacc[1][0], sacc[1][1]),
                           fmaxf(sacc[1][2], sacc[1][3])));
    m8 = fmaxf(m8, __shfl_xor(m8, 16, 64));
    m8 = fmaxf(m8, __shfl_xor(m8, 32, 64));
    const float mnew  = fmaxf(m_run, m8 * scale);
    const float alpha = __expf(m_run - mnew);
    m_run = mnew;

    float pv[8];
    float s8 = 0.f;
    #pragma unroll
    for (int ct = 0; ct < 2; ++ct) {
      #pragma unroll
      for (int r = 0; r < 4; ++r) {
        const float p = __expf(sacc[ct][r] * scale - m_run);
        pv[ct * 4 + r] = p;
        s8 += p;
      }
    }
    float sr = s8 + __shfl_xor(s8, 16, 64);
    sr = sr + __shfl_xor(sr, 32, 64);
    l_run = l_run * alpha + sr;

    // alpha broadcast to O-row layout (row token = 4q+r lives at lane 4q+r)
    const int srcb = (lane & 48) + ((lane & 48) >> 2);
    float arow[4];
    #pragma unroll
    for (int r = 0; r < 4; ++r) arow[r] = __shfl(alpha, srcb + r, 64);
    #pragma unroll
    for (int ct = 0; ct < 4; ++ct) {
      #pragma unroll
      for (int r = 0; r < 4; ++r) O[ct][r] *= arow[r];
    }

    // ---- P A-fragment = own pv in slot order (sigma) -----------------------
    bf16x8 ph, pm, pl;
    split3_frag(pv, ph, pm, pl);

    // ---- O += P @ V: V fragments straight from global ----------------------
    #pragma unroll
    for (int ct = 0; ct < 4; ++ct) {
      const size_t vo = kb + (size_t)(16 * ct + ln) * 32 + 8 * q;
      const bf16x8 vvh = ld16B(&VhT[vo]);
      const bf16x8 vvm = ld16B(&VmT[vo]);
      const bf16x8 vvl = ld16B(&VlT[vo]);
      O[ct] = MFMA16(ph, vvh, O[ct]);
      O[ct] = MFMA16(ph, vvm, O[ct]);
      O[ct] = MFMA16(pm, vvh, O[ct]);
      O[ct] = MFMA16(pm, vvm, O[ct]);
      O[ct] = MFMA16(ph, vvl, O[ct]);
      O[ct] = MFMA16(pl, vvh, O[ct]);
    }
  }

  // ---- epilogue: write split-K partials (m, l, raw O) ----------------------
  const size_t hofs = (size_t)half * (32 * 1024);
  #pragma unroll
  for (int r = 0; r < 4; ++r) {
    const int row = i0 + 16 * w + 4 * q + r;
    const size_t grow = hofs + (size_t)b * DIMN + row;
    #pragma unroll
    for (int ct = 0; ct < 4; ++ct)
      Op[grow * 64 + ln + 16 * ct] = O[ct][r];
  }
  if (q == 0) {
    const size_t tgrow = hofs + (size_t)b * DIMN + i0 + 16 * w + ln;
    Mp[tgrow] = m_run;
    Lp[tgrow] = l_run;
  }
}

// ---------------------------------------------------------------------------
// 3b) final merge + channel-mean (layer 7 partials): 256 blocks x 128 tokens
// ---------------------------------------------------------------------------
__global__ __launch_bounds__(256) void k_merge_mean(
    const float* __restrict__ X,
    const float* __restrict__ Mp, const float* __restrict__ Lp,
    const float* __restrict__ Op, float* __restrict__ meanv) {
  const int c  = threadIdx.x & 63;
  const int tg = threadIdx.x >> 6;
  const size_t t0 = (size_t)blockIdx.x * 128;
  for (int i = tg; i < 128; i += 4) {
    const size_t grow = t0 + i;
    const float m0 = Mp[grow], m1 = Mp[32768 + grow];
    const float l0 = Lp[grow], l1 = Lp[32768 + grow];
    const float mm = fmaxf(m0, m1);
    const float w0 = __expf(m0 - mm), w1 = __expf(m1 - mm);
    const float inv = 1.0f / (l0 * w0 + l1 * w1);
    const float o0 = Op[grow * 64 + c];
    const float o1 = Op[(size_t)2097152 + grow * 64 + c];
    float v = X[grow * 64 + c] + (o0 * w0 + o1 * w1) * inv;
    #pragma unroll
    for (int off = 32; off > 0; off >>= 1)
      v += __shfl_down(v, off, 64);
    if (c == 0) meanv[grow] = v * (1.0f / 64.0f);
  }
}

// ---------------------------------------------------------------------------
// 4) head stage 2: pred[b,k] = meanv[b,:] . last_W[k,:] + last_b[k]
// ---------------------------------------------------------------------------
__global__ __launch_bounds__(256) void k_head2(
    const float* __restrict__ meanv, const float* __restrict__ lW,
    const float* __restrict__ lb, float* __restrict__ out) {
  __shared__ float red[256];
  const int b   = blockIdx.x;
  const int tid = threadIdx.x;
  float acc[NCLS];
  #pragma unroll
  for (int k = 0; k < NCLS; ++k) acc[k] = 0.f;
  for (int n = tid; n < DIMN; n += 256) {
    const float m = meanv[(size_t)b * DIMN + n];
    #pragma unroll
    for (int k = 0; k < NCLS; ++k)
      acc[k] = fmaf(m, lW[k * DIMN + n], acc[k]);
  }
  for (int k = 0; k < NCLS; ++k) {
    red[tid] = acc[k];
    __syncthreads();
    for (int s = 128; s > 0; s >>= 1) {
      if (tid < s) red[tid] += red[tid + s];
      __syncthreads();
    }
    if (tid == 0) out[b * NCLS + k] = red[0] + lb[k];
    __syncthreads();
  }
}

// ===========================================================================
// MIDDLE-TIER PATH (ws >= 41 MB but < split-K need): same no-LDS structure
// ===========================================================================
__global__ __launch_bounds__(256, 4) void k_attn_s(
    const float* __restrict__ Qg,
    const unsigned short* __restrict__ Kh, const unsigned short* __restrict__ Km,
    const unsigned short* __restrict__ Kl,
    const unsigned short* __restrict__ VhT, const unsigned short* __restrict__ VmT,
    const unsigned short* __restrict__ VlT,
    float* __restrict__ X, float* __restrict__ meanout) {
  const int tid  = threadIdx.x;
  const int w    = tid >> 6;
  const int lane = tid & 63;
  const int ln   = lane & 15;
  const int q    = lane >> 4;
  const int bid = blockIdx.x;
  const int xcd = bid & 7;
  const int seq = bid >> 3;
  const int b   = xcd * 4 + (seq >> 4);
  const int i0  = (seq & 15) * 64;
  const size_t base = (size_t)b * (DIMN * 64);
  const float scale = 0.03125f;

  bf16x8 qh[2], qm[2], ql[2];
  {
    const int mrow = i0 + 16 * w + ln;
    const float* qp = Qg + base + (size_t)mrow * 64 + 8 * q;
    #pragma unroll
    for (int s = 0; s < 2; ++s) {
      const float4 x0 = ((const float4*)(qp + 32 * s))[0];
      const float4 x1 = ((const float4*)(qp + 32 * s))[1];
      const float xv[8] = {x0.x, x0.y, x0.z, x0.w, x1.x, x1.y, x1.z, x1.w};
      split3_frag(xv, qh[s], qm[s], ql[s]);
    }
  }

  f32x4 O[4];
  #pragma unroll
  for (int ct = 0; ct < 4; ++ct) O[ct] = (f32x4){0.f, 0.f, 0.f, 0.f};
  float m_run = -INFINITY;
  float l_run = 0.f;

  for (int kt = 0; kt < 32; ++kt) {
    const size_t kb = base + (size_t)kt * 2048;

    f32x4 sacc[2];
    #pragma unroll
    for (int ct = 0; ct < 2; ++ct) {
      f32x4 a = (f32x4){0.f, 0.f, 0.f, 0.f};
      #pragma unroll
      for (int s = 0; s < 2; ++s) {
        const size_t ko = kb + (size_t)(16 * ct + ln) * 64 + 32 * s + 8 * q;
        const bf16x8 bh = ld16B(&Kh[ko]);
        const bf16x8 bm = ld16B(&Km[ko]);
        const bf16x8 bl = ld16B(&Kl[ko]);
        a = MFMA16(bh, ql[s], a);
        a = MFMA16(bl, qh[s], a);
        a = MFMA16(bm, qm[s], a);
        a = MFMA16(bh, qm[s], a);
        a = MFMA16(bm, qh[s], a);
        a = MFMA16(bh, qh[s], a);
      }
      sacc[ct] = a;
    }

    float m8 = fmaxf(fmaxf(fmaxf(sacc[0][0], sacc[0][1]),
                           fmaxf(sacc[0][2], sacc[0][3])),
                     fmaxf(fmaxf(sacc[1][0], sacc[1][1]),
                           fmaxf(sacc[1][2], sacc[1][3])));
    m8 = fmaxf(m8, __shfl_xor(m8, 16, 64));
    m8 = fmaxf(m8, __shfl_xor(m8, 32, 64));
    const float mnew  = fmaxf(m_run, m8 * scale);
    const float alpha = __expf(m_run - mnew);
    m_run = mnew;

    float pv[8];
    float s8 = 0.f;
    #pragma unroll
    for (int ct = 0; ct < 2; ++ct) {
      #pragma unroll
      for (int r = 0; r < 4; ++r) {
        const float p = __expf(sacc[ct][r] * scale - m_run);
        pv[ct * 4 + r] = p;
        s8 += p;
      }
    }
    float sr = s8 + __shfl_xor(s8, 16, 64);
    sr = sr + __shfl_xor(sr, 32, 64);
    l_run = l_run * alpha + sr;

    const int srcb = (lane & 48) + ((lane & 48) >> 2);
    float arow[4];
    #pragma unroll
    for (int r = 0; r < 4; ++r) arow[r] = __shfl(alpha, srcb + r, 64);
    #pragma unroll
    for (int ct = 0; ct < 4; ++ct) {
      #pragma unroll
      for (int r = 0; r < 4; ++r) O[ct][r] *= arow[r];
    }

    bf16x8 ph, pm, pl;
    split3_frag(pv, ph, pm, pl);

    #pragma unroll
    for (int ct = 0; ct < 4; ++ct) {
      const size_t vo = kb + (size_t)(16 * ct + ln) * 32 + 8 * q;
      const bf16x8 vvh = ld16B(&VhT[vo]);
      const bf16x8 vvm = ld16B(&VmT[vo]);
      const bf16x8 vvl = ld16B(&VlT[vo]);
      O[ct] = MFMA16(ph, vvh, O[ct]);
      O[ct] = MFMA16(ph, vvm, O[ct]);
      O[ct] = MFMA16(pm, vvh, O[ct]);
      O[ct] = MFMA16(pm, vvm, O[ct]);
      O[ct] = MFMA16(ph, vvl, O[ct]);
      O[ct] = MFMA16(pl, vvh, O[ct]);
    }
  }

  // l for O-rows (token 4q+r) via shuffle from token lanes
  const int srcb = (lane & 48) + ((lane & 48) >> 2);
  float linv[4];
  #pragma unroll
  for (int r = 0; r < 4; ++r) linv[r] = 1.0f / __shfl(l_run, srcb + r, 64);
  #pragma unroll
  for (int r = 0; r < 4; ++r) {
    const int row = i0 + 16 * w + 4 * q + r;
    float srow = 0.f;
    #pragma unroll
    for (int ct = 0; ct < 4; ++ct) {
      float* xp = X + base + (size_t)row * 64 + ln + 16 * ct;
      const float nv = *xp + O[ct][r] * linv[r];
      *xp = nv;
      srow += nv;
    }
    if (meanout) {
      #pragma unroll
      for (int mk = 1; mk <= 8; mk <<= 1)
        srow += __shfl_xor(srow, mk, 64);
      if (ln == 0) meanout[(size_t)b * DIMN + row] = srow * (1.0f / 64.0f);
    }
  }
}

// ---------------------------------------------------------------------------
// launch
// ---------------------------------------------------------------------------
extern "C" void kernel_launch(void* const* d_in, const int* in_sizes, int n_in,
                              void* d_out, int out_size, void* d_ws, size_t ws_size,
                              hipStream_t stream) {
  const float* image = (const float*)d_in[0];
  const float* WV    = (const float*)d_in[1];
  const float* WK    = (const float*)d_in[2];
  const float* WQ    = (const float*)d_in[3];
  const float* lW    = (const float*)d_in[4];
  const float* lb    = (const float*)d_in[5];
  float* out = (float*)d_out;

  float* ws = (float*)d_ws;
  const size_t NELEM = (size_t)BB * DIMN * CCH;   // 2,097,152
  const size_t NROW  = (size_t)BB * DIMN;         // 32,768

  // layout (floats): X | Q | KVsplits(3N) | Op(2N) | Mp(2R) | Lp(2R) | meanv(R)
  const size_t need_sk   = (7 * NELEM + 5 * NROW) * sizeof(float);
  const size_t need_fast = (5 * NELEM + NROW) * sizeof(float);

  if (ws_size >= need_sk) {
    float* X = ws;
    float* Q = ws + NELEM;
    unsigned short* Kh  = (unsigned short*)(ws + 2 * NELEM);
    unsigned short* Km  = Kh + NELEM;
    unsigned short* Kl  = Kh + 2 * NELEM;
    unsigned short* VhT = Kh + 3 * NELEM;
    unsigned short* VmT = Kh + 4 * NELEM;
    unsigned short* VlT = Kh + 5 * NELEM;
    float* Op    = ws + 5 * NELEM;
    float* Mp    = ws + 7 * NELEM;
    float* Lp    = Mp + 2 * NROW;
    float* meanv = Lp + 2 * NROW;

    k_transpose<<<dim3(DIMN / 64, BB), 256, 0, stream>>>(image, X);
    k_qkv_split<<<(BB * DIMN) / 16, 256, 0, stream>>>(
        X, WQ, WK, WV, Q, Kh, Km, Kl, VhT, VmT, VlT);
    for (int layer = 0; layer < 8; ++layer) {
      k_attn_sk<<<1024, 256, 0, stream>>>(
          Q, Kh, Km, Kl, VhT, VmT, VlT, Mp, Lp, Op);
      if (layer < 7)
        k_qkv_merge<<<(BB * DIMN) / 16, 256, 0, stream>>>(
            X, Mp, Lp, Op, WQ, WK, WV, Q, Kh, Km, Kl, VhT, VmT, VlT);
    }
    k_merge_mean<<<256, 256, 0, stream>>>(X, Mp, Lp, Op, meanv);
    k_head2<<<BB, 256, 0, stream>>>(meanv, lW, lb, out);
  } else {
    // middle tier
    float* X = ws;
    float* Q = ws + NELEM;
    unsigned short* Kh  = (unsigned short*)(ws + 2 * NELEM);
    unsigned short* Km  = Kh + NELEM;
    unsigned short* Kl  = Kh + 2 * NELEM;
    unsigned short* VhT = Kh + 3 * NELEM;
    unsigned short* VmT = Kh + 4 * NELEM;
    unsigned short* VlT = Kh + 5 * NELEM;
    float* meanv = ws + 5 * NELEM;
    (void)need_fast;

    k_transpose<<<dim3(DIMN / 64, BB), 256, 0, stream>>>(image, X);
    for (int layer = 0; layer < 8; ++layer) {
      k_qkv_split<<<(BB * DIMN) / 16, 256, 0, stream>>>(
          X, WQ, WK, WV, Q, Kh, Km, Kl, VhT, VmT, VlT);
      k_attn_s<<<512, 256, 0, stream>>>(
          Q, Kh, Km, Kl, VhT, VmT, VlT, X, (layer == 7) ? meanv : nullptr);
    }
    k_head2<<<BB, 256, 0, stream>>>(meanv, lW, lb, out);
  }
}

// Round 7
// 717.729 us; speedup vs baseline: 1.8945x; 1.8945x over previous
//
#include <hip/hip_runtime.h>
#include <math.h>

#define BB    32
#define CCH   64
#define DIMN  1024
#define NCLS  10

typedef __attribute__((ext_vector_type(8))) short bf16x8;
typedef __attribute__((ext_vector_type(4))) float f32x4;
typedef __attribute__((ext_vector_type(4))) unsigned short us4;
typedef __attribute__((ext_vector_type(8))) unsigned short us8;

#define MFMA16(a, b, c) __builtin_amdgcn_mfma_f32_16x16x32_bf16(a, b, c, 0, 0, 0)

__device__ __forceinline__ unsigned short f2bf(float x) {
  unsigned u = __float_as_uint(x);
  unsigned r = u + 0x7fffu + ((u >> 16) & 1u);   // round-to-nearest-even
  return (unsigned short)(r >> 16);
}
__device__ __forceinline__ float bf2f(unsigned short h) {
  return __uint_as_float(((unsigned)h) << 16);
}
// packed split3 of TWO floats via v_cvt_pk_bf16_f32 (hardware RNE == f2bf;
// proven bitwise-safe end-to-end in round 3). Results pre-packed lo/hi.
__device__ __forceinline__ void split3_pk(float x0, float x1,
                                          unsigned& hp, unsigned& mp,
                                          unsigned& lp) {
  unsigned h, m, l;
  asm("v_cvt_pk_bf16_f32 %0, %1, %2" : "=v"(h) : "v"(x0), "v"(x1));
  const float h0 = __uint_as_float(h << 16);
  const float h1 = __uint_as_float(h & 0xffff0000u);
  const float r0 = x0 - h0, r1 = x1 - h1;
  asm("v_cvt_pk_bf16_f32 %0, %1, %2" : "=v"(m) : "v"(r0), "v"(r1));
  const float m0 = __uint_as_float(m << 16);
  const float m1 = __uint_as_float(m & 0xffff0000u);
  asm("v_cvt_pk_bf16_f32 %0, %1, %2" : "=v"(l) : "v"(r0 - m0), "v"(r1 - m1));
  hp = h; mp = m; lp = l;
}
// unpacked-output variant for scalar stores (qkv kernels)
__device__ __forceinline__ void split3_pk2(float x0, float x1,
    unsigned short& h0, unsigned short& m0, unsigned short& l0,
    unsigned short& h1, unsigned short& m1, unsigned short& l1) {
  unsigned h, m, l;
  split3_pk(x0, x1, h, m, l);
  h0 = (unsigned short)h; h1 = (unsigned short)(h >> 16);
  m0 = (unsigned short)m; m1 = (unsigned short)(m >> 16);
  l0 = (unsigned short)l; l1 = (unsigned short)(l >> 16);
}
// 8-element fragment split using the packed path (4x split3_pk)
__device__ __forceinline__ void split3_frag(const float* xv, bf16x8& fh,
                                            bf16x8& fm, bf16x8& fl) {
  union U { bf16x8 v; unsigned d[4]; } uh, um, ul;
  #pragma unroll
  for (int p = 0; p < 4; ++p)
    split3_pk(xv[2 * p], xv[2 * p + 1], uh.d[p], um.d[p], ul.d[p]);
  fh = uh.v; fm = um.v; fl = ul.v;
}
__device__ __forceinline__ bf16x8 ld16B(const unsigned short* p) {
  union { us8 u; bf16x8 v; } c;
  c.u = *(const us8*)p;           // 16B-aligned -> ds_read_b128
  return c.v;
}

// ---------------------------------------------------------------------------
// 1) transpose: image (B,C,DIM) -> X (B,DIM,C)
// ---------------------------------------------------------------------------
__global__ __launch_bounds__(256) void k_transpose(const float* __restrict__ img,
                                                   float* __restrict__ X) {
  __shared__ float tile[64][65];
  const int b  = blockIdx.y;
  const int n0 = blockIdx.x * 64;
  const int tx = threadIdx.x & 63;
  const int ty = threadIdx.x >> 6;
  const float* src = img + (size_t)b * CCH * DIMN;
  #pragma unroll
  for (int c = ty; c < 64; c += 4)
    tile[c][tx] = src[(size_t)c * DIMN + n0 + tx];
  __syncthreads();
  float* dst = X + (size_t)b * DIMN * CCH;
  #pragma unroll
  for (int nn = ty; nn < 64; nn += 4)
    dst[(size_t)(n0 + nn) * CCH + tx] = tile[tx][nn];
}

// ---------------------------------------------------------------------------
// 2) QKV + per-layer pre-split: Q fp32; K 3-term bf16 [t][c];
//    V 3-term bf16 transposed+tiled [b][kt][c][32], columns sigma-permuted.
//    Splits via packed v_cvt_pk_bf16_f32 (round-3-proven bitwise class).
// ---------------------------------------------------------------------------
__global__ __launch_bounds__(256) void k_qkv_split(
    const float* __restrict__ X,
    const float* __restrict__ WQ, const float* __restrict__ WK,
    const float* __restrict__ WV,
    float* __restrict__ Q,
    unsigned short* __restrict__ Kh, unsigned short* __restrict__ Km,
    unsigned short* __restrict__ Kl,
    unsigned short* __restrict__ VhT, unsigned short* __restrict__ VmT,
    unsigned short* __restrict__ VlT) {
  __shared__ float xs[16][64];
  __shared__ unsigned short vs[3][16][64];
  const int c  = threadIdx.x & 63;
  const int tg = threadIdx.x >> 6;
  const size_t t0 = (size_t)blockIdx.x * 16;
  #pragma unroll
  for (int r = tg; r < 16; r += 4)
    xs[r][c] = X[(t0 + r) * 64 + c];
  __syncthreads();
  float qa[4] = {0.f,0.f,0.f,0.f};
  float ka[4] = {0.f,0.f,0.f,0.f};
  float va[4] = {0.f,0.f,0.f,0.f};
  for (int j = 0; j < 64; ++j) {
    const float wq = WQ[j * 64 + c];
    const float wk = WK[j * 64 + c];
    const float wv = WV[j * 64 + c];
    #pragma unroll
    for (int r = 0; r < 4; ++r) {
      const float x = xs[tg * 4 + r][j];
      qa[r] = fmaf(x, wq, qa[r]);
      ka[r] = fmaf(x, wk, ka[r]);
      va[r] = fmaf(x, wv, va[r]);
    }
  }
  #pragma unroll
  for (int pr = 0; pr < 2; ++pr) {
    const int r0 = 2 * pr, r1 = 2 * pr + 1;
    const int ta = tg * 4 + r0, tb = tg * 4 + r1;
    const size_t ia = (t0 + ta) * 64 + c;
    const size_t ib = (t0 + tb) * 64 + c;
    Q[ia] = qa[r0]; Q[ib] = qa[r1];
    unsigned short h0, m0, l0, h1, m1, l1;
    split3_pk2(ka[r0], ka[r1], h0, m0, l0, h1, m1, l1);
    Kh[ia] = h0; Km[ia] = m0; Kl[ia] = l0;
    Kh[ib] = h1; Km[ib] = m1; Kl[ib] = l1;
    split3_pk2(va[r0], va[r1], h0, m0, l0, h1, m1, l1);
    vs[0][ta][c] = h0; vs[1][ta][c] = m0; vs[2][ta][c] = l0;
    vs[0][tb][c] = h1; vs[1][tb][c] = m1; vs[2][tb][c] = l1;
  }
  __syncthreads();
  {
    const int row  = threadIdx.x >> 2;
    const int part = threadIdx.x & 3;
    const size_t bofs = (t0 >> 10) * ((size_t)DIMN * 64);
    const size_t kt   = (t0 & 1023) >> 5;
    const size_t tin  = (size_t)part * 8 + ((t0 & 31) >> 2);   // sigma permute
    unsigned short* dst[3] = {VhT, VmT, VlT};
    #pragma unroll
    for (int term = 0; term < 3; ++term) {
      us4 pk;
      #pragma unroll
      for (int i = 0; i < 4; ++i) pk[i] = vs[term][part * 4 + i][row];
      *(us4*)&dst[term][bofs + kt * 2048 + (size_t)row * 32 + tin] = pk;
    }
  }
}

// ---------------------------------------------------------------------------
// 2b) QKV with FUSED 2-way SPLIT-K MERGE of the previous layer.
// ---------------------------------------------------------------------------
__global__ __launch_bounds__(256) void k_qkv_merge(
    float* __restrict__ X,
    const float* __restrict__ Mp, const float* __restrict__ Lp,
    const float* __restrict__ Op,
    const float* __restrict__ WQ, const float* __restrict__ WK,
    const float* __restrict__ WV,
    float* __restrict__ Q,
    unsigned short* __restrict__ Kh, unsigned short* __restrict__ Km,
    unsigned short* __restrict__ Kl,
    unsigned short* __restrict__ VhT, unsigned short* __restrict__ VmT,
    unsigned short* __restrict__ VlT) {
  __shared__ float xs[16][64];
  __shared__ unsigned short vs[3][16][64];
  const int c  = threadIdx.x & 63;
  const int tg = threadIdx.x >> 6;
  const size_t t0 = (size_t)blockIdx.x * 16;
  #pragma unroll
  for (int r = tg; r < 16; r += 4) {
    const size_t grow = t0 + r;                 // global row 0..32767
    const float m0 = Mp[grow], m1 = Mp[32768 + grow];
    const float l0 = Lp[grow], l1 = Lp[32768 + grow];
    const float mm = fmaxf(m0, m1);
    const float w0 = __expf(m0 - mm), w1 = __expf(m1 - mm);
    const float inv = 1.0f / (l0 * w0 + l1 * w1);
    const float o0 = Op[grow * 64 + c];
    const float o1 = Op[(size_t)2097152 + grow * 64 + c];
    const float xn = X[grow * 64 + c] + (o0 * w0 + o1 * w1) * inv;
    X[grow * 64 + c] = xn;
    xs[r][c] = xn;
  }
  __syncthreads();
  float qa[4] = {0.f,0.f,0.f,0.f};
  float ka[4] = {0.f,0.f,0.f,0.f};
  float va[4] = {0.f,0.f,0.f,0.f};
  for (int j = 0; j < 64; ++j) {
    const float wq = WQ[j * 64 + c];
    const float wk = WK[j * 64 + c];
    const float wv = WV[j * 64 + c];
    #pragma unroll
    for (int r = 0; r < 4; ++r) {
      const float x = xs[tg * 4 + r][j];
      qa[r] = fmaf(x, wq, qa[r]);
      ka[r] = fmaf(x, wk, ka[r]);
      va[r] = fmaf(x, wv, va[r]);
    }
  }
  #pragma unroll
  for (int pr = 0; pr < 2; ++pr) {
    const int r0 = 2 * pr, r1 = 2 * pr + 1;
    const int ta = tg * 4 + r0, tb = tg * 4 + r1;
    const size_t ia = (t0 + ta) * 64 + c;
    const size_t ib = (t0 + tb) * 64 + c;
    Q[ia] = qa[r0]; Q[ib] = qa[r1];
    unsigned short h0, m0, l0, h1, m1, l1;
    split3_pk2(ka[r0], ka[r1], h0, m0, l0, h1, m1, l1);
    Kh[ia] = h0; Km[ia] = m0; Kl[ia] = l0;
    Kh[ib] = h1; Km[ib] = m1; Kl[ib] = l1;
    split3_pk2(va[r0], va[r1], h0, m0, l0, h1, m1, l1);
    vs[0][ta][c] = h0; vs[1][ta][c] = m0; vs[2][ta][c] = l0;
    vs[0][tb][c] = h1; vs[1][tb][c] = m1; vs[2][tb][c] = l1;
  }
  __syncthreads();
  {
    const int row  = threadIdx.x >> 2;
    const int part = threadIdx.x & 3;
    const size_t bofs = (t0 >> 10) * ((size_t)DIMN * 64);
    const size_t kt   = (t0 & 1023) >> 5;
    const size_t tin  = (size_t)part * 8 + ((t0 & 31) >> 2);   // sigma permute
    unsigned short* dst[3] = {VhT, VmT, VlT};
    #pragma unroll
    for (int term = 0; term < 3; ++term) {
      us4 pk;
      #pragma unroll
      for (int i = 0; i < 4; ++i) pk[i] = vs[term][part * 4 + i][row];
      *(us4*)&dst[term][bofs + kt * 2048 + (size_t)row * 32 + tin] = pk;
    }
  }
}

// ---------------------------------------------------------------------------
// 3) MFMA flash attention, SPLIT-K (2 halves), SWAPPED QK^T (round-4 exact,
//    verified absmax 0.0) + s_setprio around MFMA clusters (T5; blocks on a
//    CU free-run at different phases -> scheduler has roles to arbitrate).
// ---------------------------------------------------------------------------
__global__ __launch_bounds__(256, 4) void k_attn_sk(
    const float* __restrict__ Qg,
    const unsigned short* __restrict__ Kh, const unsigned short* __restrict__ Km,
    const unsigned short* __restrict__ Kl,
    const unsigned short* __restrict__ VhT, const unsigned short* __restrict__ VmT,
    const unsigned short* __restrict__ VlT,
    float* __restrict__ Mp, float* __restrict__ Lp, float* __restrict__ Op) {
  __shared__ __align__(16) unsigned short Khs[32 * 72];
  __shared__ __align__(16) unsigned short Kms[32 * 72];
  __shared__ __align__(16) unsigned short Kls[32 * 72];
  __shared__ __align__(16) unsigned short Vhs[64 * 40];   // V^T: [c][slot]
  __shared__ __align__(16) unsigned short Vms[64 * 40];
  __shared__ __align__(16) unsigned short Vls[64 * 40];

  const int tid  = threadIdx.x;
  const int w    = tid >> 6;
  const int lane = tid & 63;
  const int ln   = lane & 15;
  const int q    = lane >> 4;

  // XCD-aware swizzle: 1024 blocks; batch pinned to one XCD (locality only)
  const int bid   = blockIdx.x;            // 0..1023
  const int xcd   = bid & 7;
  const int seq   = bid >> 3;              // 0..127
  const int b     = xcd * 4 + (seq >> 5);  // 4 batches per XCD
  const int local = seq & 31;
  const int half  = local >> 4;            // K-split half
  const int i0    = (local & 15) * 64;     // Q tile

  const size_t base = (size_t)b * (DIMN * 64);
  const float scale = 0.03125f;

  const int kj = tid >> 3, kg = tid & 7;
  const int vc = tid >> 2, vg = tid & 3;
  const int klo = kj * 72 + kg * 8;
  const int vlo = vc * 40 + vg * 8;

  // ---- Q fragments: 3-term split (packed), 2 k-chunks (once per block) -----
  bf16x8 qh[2], qm[2], ql[2];
  {
    const int mrow = i0 + 16 * w + ln;
    const float* qp = Qg + base + (size_t)mrow * 64 + 8 * q;
    #pragma unroll
    for (int s = 0; s < 2; ++s) {
      const float4 x0 = ((const float4*)(qp + 32 * s))[0];
      const float4 x1 = ((const float4*)(qp + 32 * s))[1];
      const float xv[8] = {x0.x, x0.y, x0.z, x0.w, x1.x, x1.y, x1.z, x1.w};
      split3_frag(xv, qh[s], qm[s], ql[s]);
    }
  }

  f32x4 O[4];
  #pragma unroll
  for (int ct = 0; ct < 4; ++ct) O[ct] = (f32x4){0.f, 0.f, 0.f, 0.f};
  float m_run = -INFINITY;      // per Q-token (col = ln)
  float l_run = 0.f;

  const int kt0 = half * 16;
  for (int kt = kt0; kt < kt0 + 16; ++kt) {
    __syncthreads();   // previous iteration's K/V readers done

    // ---- stage pre-split K/V tile: pure 16B copies -------------------------
    {
      const size_t tof = base + (size_t)kt * 2048 + tid * 8;  // shorts
      const us8 a0 = *(const us8*)&Kh[tof];
      const us8 a1 = *(const us8*)&Km[tof];
      const us8 a2 = *(const us8*)&Kl[tof];
      const us8 b0 = *(const us8*)&VhT[tof];
      const us8 b1 = *(const us8*)&VmT[tof];
      const us8 b2 = *(const us8*)&VlT[tof];
      *(us8*)&Khs[klo] = a0;
      *(us8*)&Kms[klo] = a1;
      *(us8*)&Kls[klo] = a2;
      *(us8*)&Vhs[vlo] = b0;
      *(us8*)&Vms[vlo] = b1;
      *(us8*)&Vls[vlo] = b2;
    }
    __syncthreads();

    // ---- S strip = mfma(K, Q): rows = K-tokens, cols = Q-tokens ------------
    f32x4 sacc[2];
    __builtin_amdgcn_s_setprio(1);
    #pragma unroll
    for (int ct = 0; ct < 2; ++ct) {
      f32x4 a = (f32x4){0.f, 0.f, 0.f, 0.f};
      #pragma unroll
      for (int s = 0; s < 2; ++s) {
        const int ko = (16 * ct + ln) * 72 + 32 * s + 8 * q;
        const bf16x8 bh = ld16B(&Khs[ko]);
        const bf16x8 bm = ld16B(&Kms[ko]);
        const bf16x8 bl = ld16B(&Kls[ko]);
        a = MFMA16(bh, ql[s], a);
        a = MFMA16(bl, qh[s], a);
        a = MFMA16(bm, qm[s], a);
        a = MFMA16(bh, qm[s], a);
        a = MFMA16(bm, qh[s], a);
        a = MFMA16(bh, qh[s], a);
      }
      sacc[ct] = a;
    }
    __builtin_amdgcn_s_setprio(0);

    // ---- online softmax, per Q-token (one token per lane) ------------------
    float m8 = fmaxf(fmaxf(fmaxf(sacc[0][0], sacc[0][1]),
                           fmaxf(sacc[0][2], sacc[0][3])),
                     fmaxf(fmaxf(sacc[1][0], sacc[1][1]),
                           fmaxf(sacc[1][2], sacc[1][3])));
    m8 = fmaxf(m8, __shfl_xor(m8, 16, 64));
    m8 = fmaxf(m8, __shfl_xor(m8, 32, 64));
    const float mnew  = fmaxf(m_run, m8 * scale);
    const float alpha = __expf(m_run - mnew);
    m_run = mnew;

    float pv[8];
    float s8 = 0.f;
    #pragma unroll
    for (int ct = 0; ct < 2; ++ct) {
      #pragma unroll
      for (int r = 0; r < 4; ++r) {
        const float p = __expf(sacc[ct][r] * scale - m_run);
        pv[ct * 4 + r] = p;
        s8 += p;
      }
    }
    float sr = s8 + __shfl_xor(s8, 16, 64);
    sr = sr + __shfl_xor(sr, 32, 64);
    l_run = l_run * alpha + sr;

    // alpha broadcast to O-row layout (row token = 4q+r lives at lane 4q+r)
    const int srcb = (lane & 48) + ((lane & 48) >> 2);
    float arow[4];
    #pragma unroll
    for (int r = 0; r < 4; ++r) arow[r] = __shfl(alpha, srcb + r, 64);
    #pragma unroll
    for (int ct = 0; ct < 4; ++ct) {
      #pragma unroll
      for (int r = 0; r < 4; ++r) O[ct][r] *= arow[r];
    }

    // ---- P A-fragment = own pv in slot order (sigma) -----------------------
    bf16x8 ph, pm, pl;
    split3_frag(pv, ph, pm, pl);

    // ---- O += P @ V, 6-product (r5 order) ----------------------------------
    __builtin_amdgcn_s_setprio(1);
    #pragma unroll
    for (int ct = 0; ct < 4; ++ct) {
      const int vo = (16 * ct + ln) * 40 + 8 * q;
      const bf16x8 vvh = ld16B(&Vhs[vo]);
      const bf16x8 vvm = ld16B(&Vms[vo]);
      const bf16x8 vvl = ld16B(&Vls[vo]);
      O[ct] = MFMA16(ph, vvh, O[ct]);
      O[ct] = MFMA16(ph, vvm, O[ct]);
      O[ct] = MFMA16(pm, vvh, O[ct]);
      O[ct] = MFMA16(pm, vvm, O[ct]);
      O[ct] = MFMA16(ph, vvl, O[ct]);
      O[ct] = MFMA16(pl, vvh, O[ct]);
    }
    __builtin_amdgcn_s_setprio(0);
  }

  // ---- epilogue: write split-K partials (m, l, raw O) ----------------------
  const size_t hofs = (size_t)half * (32 * 1024);
  #pragma unroll
  for (int r = 0; r < 4; ++r) {
    const int row = i0 + 16 * w + 4 * q + r;
    const size_t grow = hofs + (size_t)b * DIMN + row;
    #pragma unroll
    for (int ct = 0; ct < 4; ++ct)
      Op[grow * 64 + ln + 16 * ct] = O[ct][r];
  }
  if (q == 0) {
    const size_t tgrow = hofs + (size_t)b * DIMN + i0 + 16 * w + ln;
    Mp[tgrow] = m_run;
    Lp[tgrow] = l_run;
  }
}

// ---------------------------------------------------------------------------
// 3b) final merge + channel-mean (layer 7 partials): 256 blocks x 128 tokens
// ---------------------------------------------------------------------------
__global__ __launch_bounds__(256) void k_merge_mean(
    const float* __restrict__ X,
    const float* __restrict__ Mp, const float* __restrict__ Lp,
    const float* __restrict__ Op, float* __restrict__ meanv) {
  const int c  = threadIdx.x & 63;
  const int tg = threadIdx.x >> 6;
  const size_t t0 = (size_t)blockIdx.x * 128;
  for (int i = tg; i < 128; i += 4) {
    const size_t grow = t0 + i;
    const float m0 = Mp[grow], m1 = Mp[32768 + grow];
    const float l0 = Lp[grow], l1 = Lp[32768 + grow];
    const float mm = fmaxf(m0, m1);
    const float w0 = __expf(m0 - mm), w1 = __expf(m1 - mm);
    const float inv = 1.0f / (l0 * w0 + l1 * w1);
    const float o0 = Op[grow * 64 + c];
    const float o1 = Op[(size_t)2097152 + grow * 64 + c];
    float v = X[grow * 64 + c] + (o0 * w0 + o1 * w1) * inv;
    #pragma unroll
    for (int off = 32; off > 0; off >>= 1)
      v += __shfl_down(v, off, 64);
    if (c == 0) meanv[grow] = v * (1.0f / 64.0f);
  }
}

// ---------------------------------------------------------------------------
// 4) head stage 2: pred[b,k] = meanv[b,:] . last_W[k,:] + last_b[k]
// ---------------------------------------------------------------------------
__global__ __launch_bounds__(256) void k_head2(
    const float* __restrict__ meanv, const float* __restrict__ lW,
    const float* __restrict__ lb, float* __restrict__ out) {
  __shared__ float red[256];
  const int b   = blockIdx.x;
  const int tid = threadIdx.x;
  float acc[NCLS];
  #pragma unroll
  for (int k = 0; k < NCLS; ++k) acc[k] = 0.f;
  for (int n = tid; n < DIMN; n += 256) {
    const float m = meanv[(size_t)b * DIMN + n];
    #pragma unroll
    for (int k = 0; k < NCLS; ++k)
      acc[k] = fmaf(m, lW[k * DIMN + n], acc[k]);
  }
  for (int k = 0; k < NCLS; ++k) {
    red[tid] = acc[k];
    __syncthreads();
    for (int s = 128; s > 0; s >>= 1) {
      if (tid < s) red[tid] += red[tid + s];
      __syncthreads();
    }
    if (tid == 0) out[b * NCLS + k] = red[0] + lb[k];
    __syncthreads();
  }
}

// ===========================================================================
// MIDDLE-TIER PATH (ws >= 41 MB but < split-K need): round-4 structure
// ===========================================================================
__global__ __launch_bounds__(256) void k_attn_s(
    const float* __restrict__ Qg,
    const unsigned short* __restrict__ Kh, const unsigned short* __restrict__ Km,
    const unsigned short* __restrict__ Kl,
    const unsigned short* __restrict__ VhT, const unsigned short* __restrict__ VmT,
    const unsigned short* __restrict__ VlT,
    float* __restrict__ X, float* __restrict__ meanout) {
  __shared__ __align__(16) unsigned short Khs[32 * 72];
  __shared__ __align__(16) unsigned short Kms[32 * 72];
  __shared__ __align__(16) unsigned short Kls[32 * 72];
  __shared__ __align__(16) unsigned short Vhs[64 * 40];
  __shared__ __align__(16) unsigned short Vms[64 * 40];
  __shared__ __align__(16) unsigned short Vls[64 * 40];

  const int tid  = threadIdx.x;
  const int w    = tid >> 6;
  const int lane = tid & 63;
  const int ln   = lane & 15;
  const int q    = lane >> 4;
  const int bid = blockIdx.x;
  const int xcd = bid & 7;
  const int seq = bid >> 3;
  const int b   = xcd * 4 + (seq >> 4);
  const int i0  = (seq & 15) * 64;
  const size_t base = (size_t)b * (DIMN * 64);
  const float scale = 0.03125f;

  const int kj = tid >> 3, kg = tid & 7;
  const int vc = tid >> 2, vg = tid & 3;
  const int klo = kj * 72 + kg * 8;
  const int vlo = vc * 40 + vg * 8;

  bf16x8 qh[2], qm[2], ql[2];
  {
    const int mrow = i0 + 16 * w + ln;
    const float* qp = Qg + base + (size_t)mrow * 64 + 8 * q;
    #pragma unroll
    for (int s = 0; s < 2; ++s) {
      const float4 x0 = ((const float4*)(qp + 32 * s))[0];
      const float4 x1 = ((const float4*)(qp + 32 * s))[1];
      const float xv[8] = {x0.x, x0.y, x0.z, x0.w, x1.x, x1.y, x1.z, x1.w};
      split3_frag(xv, qh[s], qm[s], ql[s]);
    }
  }

  f32x4 O[4];
  #pragma unroll
  for (int ct = 0; ct < 4; ++ct) O[ct] = (f32x4){0.f, 0.f, 0.f, 0.f};
  float m_run = -INFINITY;
  float l_run = 0.f;

  for (int kt = 0; kt < 32; ++kt) {
    __syncthreads();
    {
      const size_t tof = base + (size_t)kt * 2048 + tid * 8;
      const us8 a0 = *(const us8*)&Kh[tof];
      const us8 a1 = *(const us8*)&Km[tof];
      const us8 a2 = *(const us8*)&Kl[tof];
      const us8 b0 = *(const us8*)&VhT[tof];
      const us8 b1 = *(const us8*)&VmT[tof];
      const us8 b2 = *(const us8*)&VlT[tof];
      *(us8*)&Khs[klo] = a0;
      *(us8*)&Kms[klo] = a1;
      *(us8*)&Kls[klo] = a2;
      *(us8*)&Vhs[vlo] = b0;
      *(us8*)&Vms[vlo] = b1;
      *(us8*)&Vls[vlo] = b2;
    }
    __syncthreads();

    f32x4 sacc[2];
    __builtin_amdgcn_s_setprio(1);
    #pragma unroll
    for (int ct = 0; ct < 2; ++ct) {
      f32x4 a = (f32x4){0.f, 0.f, 0.f, 0.f};
      #pragma unroll
      for (int s = 0; s < 2; ++s) {
        const int ko = (16 * ct + ln) * 72 + 32 * s + 8 * q;
        const bf16x8 bh = ld16B(&Khs[ko]);
        const bf16x8 bm = ld16B(&Kms[ko]);
        const bf16x8 bl = ld16B(&Kls[ko]);
        a = MFMA16(bh, ql[s], a);
        a = MFMA16(bl, qh[s], a);
        a = MFMA16(bm, qm[s], a);
        a = MFMA16(bh, qm[s], a);
        a = MFMA16(bm, qh[s], a);
        a = MFMA16(bh, qh[s], a);
      }
      sacc[ct] = a;
    }
    __builtin_amdgcn_s_setprio(0);

    float m8 = fmaxf(fmaxf(fmaxf(sacc[0][0], sacc[0][1]),
                           fmaxf(sacc[0][2], sacc[0][3])),
                     fmaxf(fmaxf(sacc[1][0], sacc[1][1]),
                           fmaxf(sacc[1][2], sacc[1][3])));
    m8 = fmaxf(m8, __shfl_xor(m8, 16, 64));
    m8 = fmaxf(m8, __shfl_xor(m8, 32, 64));
    const float mnew  = fmaxf(m_run, m8 * scale);
    const float alpha = __expf(m_run - mnew);
    m_run = mnew;

    float pv[8];
    float s8 = 0.f;
    #pragma unroll
    for (int ct = 0; ct < 2; ++ct) {
      #pragma unroll
      for (int r = 0; r < 4; ++r) {
        const float p = __expf(sacc[ct][r] * scale - m_run);
        pv[ct * 4 + r] = p;
        s8 += p;
      }
    }
    float sr = s8 + __shfl_xor(s8, 16, 64);
    sr = sr + __shfl_xor(sr, 32, 64);
    l_run = l_run * alpha + sr;

    const int srcb = (lane & 48) + ((lane & 48) >> 2);
    float arow[4];
    #pragma unroll
    for (int r = 0; r < 4; ++r) arow[r] = __shfl(alpha, srcb + r, 64);
    #pragma unroll
    for (int ct = 0; ct < 4; ++ct) {
      #pragma unroll
      for (int r = 0; r < 4; ++r) O[ct][r] *= arow[r];
    }

    bf16x8 ph, pm, pl;
    split3_frag(pv, ph, pm, pl);

    __builtin_amdgcn_s_setprio(1);
    #pragma unroll
    for (int ct = 0; ct < 4; ++ct) {
      const int vo = (16 * ct + ln) * 40 + 8 * q;
      const bf16x8 vvh = ld16B(&Vhs[vo]);
      const bf16x8 vvm = ld16B(&Vms[vo]);
      const bf16x8 vvl = ld16B(&Vls[vo]);
      O[ct] = MFMA16(ph, vvh, O[ct]);
      O[ct] = MFMA16(ph, vvm, O[ct]);
      O[ct] = MFMA16(pm, vvh, O[ct]);
      O[ct] = MFMA16(pm, vvm, O[ct]);
      O[ct] = MFMA16(ph, vvl, O[ct]);
      O[ct] = MFMA16(pl, vvh, O[ct]);
    }
    __builtin_amdgcn_s_setprio(0);
  }

  // l for O-rows (token 4q+r) via shuffle from token lanes
  const int srcb = (lane & 48) + ((lane & 48) >> 2);
  float linv[4];
  #pragma unroll
  for (int r = 0; r < 4; ++r) linv[r] = 1.0f / __shfl(l_run, srcb + r, 64);
  #pragma unroll
  for (int r = 0; r < 4; ++r) {
    const int row = i0 + 16 * w + 4 * q + r;
    float srow = 0.f;
    #pragma unroll
    for (int ct = 0; ct < 4; ++ct) {
      float* xp = X + base + (size_t)row * 64 + ln + 16 * ct;
      const float nv = *xp + O[ct][r] * linv[r];
      *xp = nv;
      srow += nv;
    }
    if (meanout) {
      #pragma unroll
      for (int mk = 1; mk <= 8; mk <<= 1)
        srow += __shfl_xor(srow, mk, 64);
      if (ln == 0) meanout[(size_t)b * DIMN + row] = srow * (1.0f / 64.0f);
    }
  }
}

// ---------------------------------------------------------------------------
// launch
// ---------------------------------------------------------------------------
extern "C" void kernel_launch(void* const* d_in, const int* in_sizes, int n_in,
                              void* d_out, int out_size, void* d_ws, size_t ws_size,
                              hipStream_t stream) {
  const float* image = (const float*)d_in[0];
  const float* WV    = (const float*)d_in[1];
  const float* WK    = (const float*)d_in[2];
  const float* WQ    = (const float*)d_in[3];
  const float* lW    = (const float*)d_in[4];
  const float* lb    = (const float*)d_in[5];
  float* out = (float*)d_out;

  float* ws = (float*)d_ws;
  const size_t NELEM = (size_t)BB * DIMN * CCH;   // 2,097,152
  const size_t NROW  = (size_t)BB * DIMN;         // 32,768

  // layout (floats): X | Q | KVsplits(3N) | Op(2N) | Mp(2R) | Lp(2R) | meanv(R)
  const size_t need_sk   = (7 * NELEM + 5 * NROW) * sizeof(float);
  const size_t need_fast = (5 * NELEM + NROW) * sizeof(float);

  if (ws_size >= need_sk) {
    float* X = ws;
    float* Q = ws + NELEM;
    unsigned short* Kh  = (unsigned short*)(ws + 2 * NELEM);
    unsigned short* Km  = Kh + NELEM;
    unsigned short* Kl  = Kh + 2 * NELEM;
    unsigned short* VhT = Kh + 3 * NELEM;
    unsigned short* VmT = Kh + 4 * NELEM;
    unsigned short* VlT = Kh + 5 * NELEM;
    float* Op    = ws + 5 * NELEM;
    float* Mp    = ws + 7 * NELEM;
    float* Lp    = Mp + 2 * NROW;
    float* meanv = Lp + 2 * NROW;

    k_transpose<<<dim3(DIMN / 64, BB), 256, 0, stream>>>(image, X);
    k_qkv_split<<<(BB * DIMN) / 16, 256, 0, stream>>>(
        X, WQ, WK, WV, Q, Kh, Km, Kl, VhT, VmT, VlT);
    for (int layer = 0; layer < 8; ++layer) {
      k_attn_sk<<<1024, 256, 0, stream>>>(
          Q, Kh, Km, Kl, VhT, VmT, VlT, Mp, Lp, Op);
      if (layer < 7)
        k_qkv_merge<<<(BB * DIMN) / 16, 256, 0, stream>>>(
            X, Mp, Lp, Op, WQ, WK, WV, Q, Kh, Km, Kl, VhT, VmT, VlT);
    }
    k_merge_mean<<<256, 256, 0, stream>>>(X, Mp, Lp, Op, meanv);
    k_head2<<<BB, 256, 0, stream>>>(meanv, lW, lb, out);
  } else {
    // middle tier
    float* X = ws;
    float* Q = ws + NELEM;
    unsigned short* Kh  = (unsigned short*)(ws + 2 * NELEM);
    unsigned short* Km  = Kh + NELEM;
    unsigned short* Kl  = Kh + 2 * NELEM;
    unsigned short* VhT = Kh + 3 * NELEM;
    unsigned short* VmT = Kh + 4 * NELEM;
    unsigned short* VlT = Kh + 5 * NELEM;
    float* meanv = ws + 5 * NELEM;
    (void)need_fast;

    k_transpose<<<dim3(DIMN / 64, BB), 256, 0, stream>>>(image, X);
    for (int layer = 0; layer < 8; ++layer) {
      k_qkv_split<<<(BB * DIMN) / 16, 256, 0, stream>>>(
          X, WQ, WK, WV, Q, Kh, Km, Kl, VhT, VmT, VlT);
      k_attn_s<<<512, 256, 0, stream>>>(
          Q, Kh, Km, Kl, VhT, VmT, VlT, X, (layer == 7) ? meanv : nullptr);
    }
    k_head2<<<BB, 256, 0, stream>>>(meanv, lW, lb, out);
  }
}

// Round 8
// 700.891 us; speedup vs baseline: 1.9400x; 1.0240x over previous
//
#include <hip/hip_runtime.h>
#include <math.h>

#define BB    32
#define CCH   64
#define DIMN  1024
#define NCLS  10

typedef __attribute__((ext_vector_type(8))) short bf16x8;
typedef __attribute__((ext_vector_type(4))) float f32x4;
typedef __attribute__((ext_vector_type(4))) unsigned short us4;
typedef __attribute__((ext_vector_type(8))) unsigned short us8;

#define MFMA16(a, b, c) __builtin_amdgcn_mfma_f32_16x16x32_bf16(a, b, c, 0, 0, 0)

__device__ __forceinline__ unsigned short f2bf(float x) {
  unsigned u = __float_as_uint(x);
  unsigned r = u + 0x7fffu + ((u >> 16) & 1u);   // round-to-nearest-even
  return (unsigned short)(r >> 16);
}
__device__ __forceinline__ float bf2f(unsigned short h) {
  return __uint_as_float(((unsigned)h) << 16);
}
// packed split3 of TWO floats via v_cvt_pk_bf16_f32 (hardware RNE == f2bf;
// proven bitwise-safe end-to-end in round 3). Results pre-packed lo/hi.
__device__ __forceinline__ void split3_pk(float x0, float x1,
                                          unsigned& hp, unsigned& mp,
                                          unsigned& lp) {
  unsigned h, m, l;
  asm("v_cvt_pk_bf16_f32 %0, %1, %2" : "=v"(h) : "v"(x0), "v"(x1));
  const float h0 = __uint_as_float(h << 16);
  const float h1 = __uint_as_float(h & 0xffff0000u);
  const float r0 = x0 - h0, r1 = x1 - h1;
  asm("v_cvt_pk_bf16_f32 %0, %1, %2" : "=v"(m) : "v"(r0), "v"(r1));
  const float m0 = __uint_as_float(m << 16);
  const float m1 = __uint_as_float(m & 0xffff0000u);
  asm("v_cvt_pk_bf16_f32 %0, %1, %2" : "=v"(l) : "v"(r0 - m0), "v"(r1 - m1));
  hp = h; mp = m; lp = l;
}
// unpacked-output variant for scalar stores (qkv kernels)
__device__ __forceinline__ void split3_pk2(float x0, float x1,
    unsigned short& h0, unsigned short& m0, unsigned short& l0,
    unsigned short& h1, unsigned short& m1, unsigned short& l1) {
  unsigned h, m, l;
  split3_pk(x0, x1, h, m, l);
  h0 = (unsigned short)h; h1 = (unsigned short)(h >> 16);
  m0 = (unsigned short)m; m1 = (unsigned short)(m >> 16);
  l0 = (unsigned short)l; l1 = (unsigned short)(l >> 16);
}
// 8-element fragment split using the packed path (4x split3_pk)
__device__ __forceinline__ void split3_frag(const float* xv, bf16x8& fh,
                                            bf16x8& fm, bf16x8& fl) {
  union U { bf16x8 v; unsigned d[4]; } uh, um, ul;
  #pragma unroll
  for (int p = 0; p < 4; ++p)
    split3_pk(xv[2 * p], xv[2 * p + 1], uh.d[p], um.d[p], ul.d[p]);
  fh = uh.v; fm = um.v; fl = ul.v;
}
__device__ __forceinline__ bf16x8 ld16B(const unsigned short* p) {
  union { us8 u; bf16x8 v; } c;
  c.u = *(const us8*)p;           // 16B-aligned -> ds_read_b128
  return c.v;
}

// ---------------------------------------------------------------------------
// 1) transpose: image (B,C,DIM) -> X (B,DIM,C)
// ---------------------------------------------------------------------------
__global__ __launch_bounds__(256) void k_transpose(const float* __restrict__ img,
                                                   float* __restrict__ X) {
  __shared__ float tile[64][65];
  const int b  = blockIdx.y;
  const int n0 = blockIdx.x * 64;
  const int tx = threadIdx.x & 63;
  const int ty = threadIdx.x >> 6;
  const float* src = img + (size_t)b * CCH * DIMN;
  #pragma unroll
  for (int c = ty; c < 64; c += 4)
    tile[c][tx] = src[(size_t)c * DIMN + n0 + tx];
  __syncthreads();
  float* dst = X + (size_t)b * DIMN * CCH;
  #pragma unroll
  for (int nn = ty; nn < 64; nn += 4)
    dst[(size_t)(n0 + nn) * CCH + tx] = tile[tx][nn];
}

// ---------------------------------------------------------------------------
// shared qkv inner product: float4 xs reads (wave-uniform broadcast, 4x fewer
// LDS issues), j-ascending FMA order per accumulator preserved (bitwise).
// ---------------------------------------------------------------------------
__device__ __forceinline__ void qkv_inner(
    const float xs[16][64],
    const float* __restrict__ WQ, const float* __restrict__ WK,
    const float* __restrict__ WV, int c, int tg,
    float qa[4], float ka[4], float va[4]) {
  for (int j = 0; j < 64; j += 4) {
    float4 xv[4];
    #pragma unroll
    for (int r = 0; r < 4; ++r)
      xv[r] = *(const float4*)&xs[tg * 4 + r][j];
    #pragma unroll
    for (int jj = 0; jj < 4; ++jj) {
      const float wq = WQ[(j + jj) * 64 + c];
      const float wk = WK[(j + jj) * 64 + c];
      const float wv = WV[(j + jj) * 64 + c];
      #pragma unroll
      for (int r = 0; r < 4; ++r) {
        const float x = ((const float*)&xv[r])[jj];   // static after unroll
        qa[r] = fmaf(x, wq, qa[r]);
        ka[r] = fmaf(x, wk, ka[r]);
        va[r] = fmaf(x, wv, va[r]);
      }
    }
  }
}

// ---------------------------------------------------------------------------
// 2) QKV + per-layer pre-split: Q fp32; K 3-term bf16 [t][c];
//    V 3-term bf16 transposed+tiled [b][kt][c][32], columns sigma-permuted.
// ---------------------------------------------------------------------------
__global__ __launch_bounds__(256) void k_qkv_split(
    const float* __restrict__ X,
    const float* __restrict__ WQ, const float* __restrict__ WK,
    const float* __restrict__ WV,
    float* __restrict__ Q,
    unsigned short* __restrict__ Kh, unsigned short* __restrict__ Km,
    unsigned short* __restrict__ Kl,
    unsigned short* __restrict__ VhT, unsigned short* __restrict__ VmT,
    unsigned short* __restrict__ VlT) {
  __shared__ float xs[16][64];
  __shared__ unsigned short vs[3][16][64];
  const int c  = threadIdx.x & 63;
  const int tg = threadIdx.x >> 6;
  const size_t t0 = (size_t)blockIdx.x * 16;
  #pragma unroll
  for (int r = tg; r < 16; r += 4)
    xs[r][c] = X[(t0 + r) * 64 + c];
  __syncthreads();
  float qa[4] = {0.f,0.f,0.f,0.f};
  float ka[4] = {0.f,0.f,0.f,0.f};
  float va[4] = {0.f,0.f,0.f,0.f};
  qkv_inner(xs, WQ, WK, WV, c, tg, qa, ka, va);
  #pragma unroll
  for (int pr = 0; pr < 2; ++pr) {
    const int r0 = 2 * pr, r1 = 2 * pr + 1;
    const int ta = tg * 4 + r0, tb = tg * 4 + r1;
    const size_t ia = (t0 + ta) * 64 + c;
    const size_t ib = (t0 + tb) * 64 + c;
    Q[ia] = qa[r0]; Q[ib] = qa[r1];
    unsigned short h0, m0, l0, h1, m1, l1;
    split3_pk2(ka[r0], ka[r1], h0, m0, l0, h1, m1, l1);
    Kh[ia] = h0; Km[ia] = m0; Kl[ia] = l0;
    Kh[ib] = h1; Km[ib] = m1; Kl[ib] = l1;
    split3_pk2(va[r0], va[r1], h0, m0, l0, h1, m1, l1);
    vs[0][ta][c] = h0; vs[1][ta][c] = m0; vs[2][ta][c] = l0;
    vs[0][tb][c] = h1; vs[1][tb][c] = m1; vs[2][tb][c] = l1;
  }
  __syncthreads();
  {
    const int row  = threadIdx.x >> 2;
    const int part = threadIdx.x & 3;
    const size_t bofs = (t0 >> 10) * ((size_t)DIMN * 64);
    const size_t kt   = (t0 & 1023) >> 5;
    const size_t tin  = (size_t)part * 8 + ((t0 & 31) >> 2);   // sigma permute
    unsigned short* dst[3] = {VhT, VmT, VlT};
    #pragma unroll
    for (int term = 0; term < 3; ++term) {
      us4 pk;
      #pragma unroll
      for (int i = 0; i < 4; ++i) pk[i] = vs[term][part * 4 + i][row];
      *(us4*)&dst[term][bofs + kt * 2048 + (size_t)row * 32 + tin] = pk;
    }
  }
}

// ---------------------------------------------------------------------------
// 2b) QKV with FUSED 2-way SPLIT-K MERGE of the previous layer.
// ---------------------------------------------------------------------------
__global__ __launch_bounds__(256) void k_qkv_merge(
    float* __restrict__ X,
    const float* __restrict__ Mp, const float* __restrict__ Lp,
    const float* __restrict__ Op,
    const float* __restrict__ WQ, const float* __restrict__ WK,
    const float* __restrict__ WV,
    float* __restrict__ Q,
    unsigned short* __restrict__ Kh, unsigned short* __restrict__ Km,
    unsigned short* __restrict__ Kl,
    unsigned short* __restrict__ VhT, unsigned short* __restrict__ VmT,
    unsigned short* __restrict__ VlT) {
  __shared__ float xs[16][64];
  __shared__ unsigned short vs[3][16][64];
  const int c  = threadIdx.x & 63;
  const int tg = threadIdx.x >> 6;
  const size_t t0 = (size_t)blockIdx.x * 16;
  #pragma unroll
  for (int r = tg; r < 16; r += 4) {
    const size_t grow = t0 + r;                 // global row 0..32767
    const float m0 = Mp[grow], m1 = Mp[32768 + grow];
    const float l0 = Lp[grow], l1 = Lp[32768 + grow];
    const float mm = fmaxf(m0, m1);
    const float w0 = __expf(m0 - mm), w1 = __expf(m1 - mm);
    const float inv = 1.0f / (l0 * w0 + l1 * w1);
    const float o0 = Op[grow * 64 + c];
    const float o1 = Op[(size_t)2097152 + grow * 64 + c];
    const float xn = X[grow * 64 + c] + (o0 * w0 + o1 * w1) * inv;
    X[grow * 64 + c] = xn;
    xs[r][c] = xn;
  }
  __syncthreads();
  float qa[4] = {0.f,0.f,0.f,0.f};
  float ka[4] = {0.f,0.f,0.f,0.f};
  float va[4] = {0.f,0.f,0.f,0.f};
  qkv_inner(xs, WQ, WK, WV, c, tg, qa, ka, va);
  #pragma unroll
  for (int pr = 0; pr < 2; ++pr) {
    const int r0 = 2 * pr, r1 = 2 * pr + 1;
    const int ta = tg * 4 + r0, tb = tg * 4 + r1;
    const size_t ia = (t0 + ta) * 64 + c;
    const size_t ib = (t0 + tb) * 64 + c;
    Q[ia] = qa[r0]; Q[ib] = qa[r1];
    unsigned short h0, m0, l0, h1, m1, l1;
    split3_pk2(ka[r0], ka[r1], h0, m0, l0, h1, m1, l1);
    Kh[ia] = h0; Km[ia] = m0; Kl[ia] = l0;
    Kh[ib] = h1; Km[ib] = m1; Kl[ib] = l1;
    split3_pk2(va[r0], va[r1], h0, m0, l0, h1, m1, l1);
    vs[0][ta][c] = h0; vs[1][ta][c] = m0; vs[2][ta][c] = l0;
    vs[0][tb][c] = h1; vs[1][tb][c] = m1; vs[2][tb][c] = l1;
  }
  __syncthreads();
  {
    const int row  = threadIdx.x >> 2;
    const int part = threadIdx.x & 3;
    const size_t bofs = (t0 >> 10) * ((size_t)DIMN * 64);
    const size_t kt   = (t0 & 1023) >> 5;
    const size_t tin  = (size_t)part * 8 + ((t0 & 31) >> 2);   // sigma permute
    unsigned short* dst[3] = {VhT, VmT, VlT};
    #pragma unroll
    for (int term = 0; term < 3; ++term) {
      us4 pk;
      #pragma unroll
      for (int i = 0; i < 4; ++i) pk[i] = vs[term][part * 4 + i][row];
      *(us4*)&dst[term][bofs + kt * 2048 + (size_t)row * 32 + tin] = pk;
    }
  }
}

// ---------------------------------------------------------------------------
// 3) MFMA flash attention, SPLIT-K (2 halves), SWAPPED QK^T, TWO Q-TILES per
//    block: same staged K/V tile feeds 96 MFMA instead of 48 (barrier/stage
//    amortized 2x), K/V LDS fragments loaded once and used for both tiles,
//    QK^T(B) overlaps softmax(A). Per-Q-tile arithmetic is round-4 bitwise.
//    Grid 512 (2 blocks/CU), LDS 29184 B, launch_bounds(256,2) for VGPR room.
// ---------------------------------------------------------------------------
__global__ __launch_bounds__(256, 2) void k_attn_sk(
    const float* __restrict__ Qg,
    const unsigned short* __restrict__ Kh, const unsigned short* __restrict__ Km,
    const unsigned short* __restrict__ Kl,
    const unsigned short* __restrict__ VhT, const unsigned short* __restrict__ VmT,
    const unsigned short* __restrict__ VlT,
    float* __restrict__ Mp, float* __restrict__ Lp, float* __restrict__ Op) {
  __shared__ __align__(16) unsigned short Khs[32 * 72];
  __shared__ __align__(16) unsigned short Kms[32 * 72];
  __shared__ __align__(16) unsigned short Kls[32 * 72];
  __shared__ __align__(16) unsigned short Vhs[64 * 40];   // V^T: [c][slot]
  __shared__ __align__(16) unsigned short Vms[64 * 40];
  __shared__ __align__(16) unsigned short Vls[64 * 40];

  const int tid  = threadIdx.x;
  const int w    = tid >> 6;
  const int lane = tid & 63;
  const int ln   = lane & 15;
  const int q    = lane >> 4;

  // XCD-aware swizzle: 512 blocks; batch pinned to one XCD
  const int bid   = blockIdx.x;            // 0..511
  const int xcd   = bid & 7;
  const int seq   = bid >> 3;              // 0..63
  const int b     = xcd * 4 + (seq >> 4);  // 4 batches per XCD
  const int local = seq & 15;
  const int half  = local >> 3;            // K-split half
  const int i0    = (local & 7) * 128;     // Q tile pair base

  const size_t base = (size_t)b * (DIMN * 64);
  const float scale = 0.03125f;

  const int kj = tid >> 3, kg = tid & 7;
  const int vc = tid >> 2, vg = tid & 3;
  const int klo = kj * 72 + kg * 8;
  const int vlo = vc * 40 + vg * 8;

  // ---- Q fragments for both tiles: 3-term split (packed) -------------------
  bf16x8 qh[2][2], qm[2][2], ql[2][2];     // [tile][s]
  #pragma unroll
  for (int t = 0; t < 2; ++t) {
    const int mrow = i0 + 64 * t + 16 * w + ln;
    const float* qp = Qg + base + (size_t)mrow * 64 + 8 * q;
    #pragma unroll
    for (int s = 0; s < 2; ++s) {
      const float4 x0 = ((const float4*)(qp + 32 * s))[0];
      const float4 x1 = ((const float4*)(qp + 32 * s))[1];
      const float xv[8] = {x0.x, x0.y, x0.z, x0.w, x1.x, x1.y, x1.z, x1.w};
      split3_frag(xv, qh[t][s], qm[t][s], ql[t][s]);
    }
  }

  f32x4 O[2][4];
  #pragma unroll
  for (int t = 0; t < 2; ++t)
    #pragma unroll
    for (int ct = 0; ct < 4; ++ct) O[t][ct] = (f32x4){0.f, 0.f, 0.f, 0.f};
  float m_run[2] = {-INFINITY, -INFINITY};
  float l_run[2] = {0.f, 0.f};

  const int kt0 = half * 16;
  for (int kt = kt0; kt < kt0 + 16; ++kt) {
    __syncthreads();   // previous iteration's K/V readers done

    // ---- stage pre-split K/V tile: pure 16B copies -------------------------
    {
      const size_t tof = base + (size_t)kt * 2048 + tid * 8;  // shorts
      const us8 a0 = *(const us8*)&Kh[tof];
      const us8 a1 = *(const us8*)&Km[tof];
      const us8 a2 = *(const us8*)&Kl[tof];
      const us8 b0 = *(const us8*)&VhT[tof];
      const us8 b1 = *(const us8*)&VmT[tof];
      const us8 b2 = *(const us8*)&VlT[tof];
      *(us8*)&Khs[klo] = a0;
      *(us8*)&Kms[klo] = a1;
      *(us8*)&Kls[klo] = a2;
      *(us8*)&Vhs[vlo] = b0;
      *(us8*)&Vms[vlo] = b1;
      *(us8*)&Vls[vlo] = b2;
    }
    __syncthreads();

    // ---- S strips = mfma(K, Q_t): K fragments loaded once, used twice ------
    f32x4 sacc[2][2];                       // [tile][ct]
    __builtin_amdgcn_s_setprio(1);
    #pragma unroll
    for (int ct = 0; ct < 2; ++ct) {
      f32x4 aA = (f32x4){0.f, 0.f, 0.f, 0.f};
      f32x4 aB = (f32x4){0.f, 0.f, 0.f, 0.f};
      #pragma unroll
      for (int s = 0; s < 2; ++s) {
        const int ko = (16 * ct + ln) * 72 + 32 * s + 8 * q;
        const bf16x8 bh = ld16B(&Khs[ko]);
        const bf16x8 bm = ld16B(&Kms[ko]);
        const bf16x8 bl = ld16B(&Kls[ko]);
        aA = MFMA16(bh, ql[0][s], aA);
        aA = MFMA16(bl, qh[0][s], aA);
        aA = MFMA16(bm, qm[0][s], aA);
        aA = MFMA16(bh, qm[0][s], aA);
        aA = MFMA16(bm, qh[0][s], aA);
        aA = MFMA16(bh, qh[0][s], aA);
        aB = MFMA16(bh, ql[1][s], aB);
        aB = MFMA16(bl, qh[1][s], aB);
        aB = MFMA16(bm, qm[1][s], aB);
        aB = MFMA16(bh, qm[1][s], aB);
        aB = MFMA16(bm, qh[1][s], aB);
        aB = MFMA16(bh, qh[1][s], aB);
      }
      sacc[0][ct] = aA; sacc[1][ct] = aB;
    }
    __builtin_amdgcn_s_setprio(0);

    // ---- online softmax per tile (one Q-token per lane) --------------------
    bf16x8 ph[2], pm[2], pl[2];
    const int srcb = (lane & 48) + ((lane & 48) >> 2);
    #pragma unroll
    for (int t = 0; t < 2; ++t) {
      float m8 = fmaxf(fmaxf(fmaxf(sacc[t][0][0], sacc[t][0][1]),
                             fmaxf(sacc[t][0][2], sacc[t][0][3])),
                       fmaxf(fmaxf(sacc[t][1][0], sacc[t][1][1]),
                             fmaxf(sacc[t][1][2], sacc[t][1][3])));
      m8 = fmaxf(m8, __shfl_xor(m8, 16, 64));
      m8 = fmaxf(m8, __shfl_xor(m8, 32, 64));
      const float mnew  = fmaxf(m_run[t], m8 * scale);
      const float alpha = __expf(m_run[t] - mnew);
      m_run[t] = mnew;

      float pv[8];
      float s8 = 0.f;
      #pragma unroll
      for (int ct = 0; ct < 2; ++ct) {
        #pragma unroll
        for (int r = 0; r < 4; ++r) {
          const float p = __expf(sacc[t][ct][r] * scale - m_run[t]);
          pv[ct * 4 + r] = p;
          s8 += p;
        }
      }
      float sr = s8 + __shfl_xor(s8, 16, 64);
      sr = sr + __shfl_xor(sr, 32, 64);
      l_run[t] = l_run[t] * alpha + sr;

      float arow[4];
      #pragma unroll
      for (int r = 0; r < 4; ++r) arow[r] = __shfl(alpha, srcb + r, 64);
      #pragma unroll
      for (int ct = 0; ct < 4; ++ct) {
        #pragma unroll
        for (int r = 0; r < 4; ++r) O[t][ct][r] *= arow[r];
      }

      split3_frag(pv, ph[t], pm[t], pl[t]);
    }

    // ---- O += P @ V: V fragments loaded once, used for both tiles ----------
    __builtin_amdgcn_s_setprio(1);
    #pragma unroll
    for (int ct = 0; ct < 4; ++ct) {
      const int vo = (16 * ct + ln) * 40 + 8 * q;
      const bf16x8 vvh = ld16B(&Vhs[vo]);
      const bf16x8 vvm = ld16B(&Vms[vo]);
      const bf16x8 vvl = ld16B(&Vls[vo]);
      O[0][ct] = MFMA16(ph[0], vvh, O[0][ct]);
      O[0][ct] = MFMA16(ph[0], vvm, O[0][ct]);
      O[0][ct] = MFMA16(pm[0], vvh, O[0][ct]);
      O[0][ct] = MFMA16(pm[0], vvm, O[0][ct]);
      O[0][ct] = MFMA16(ph[0], vvl, O[0][ct]);
      O[0][ct] = MFMA16(pl[0], vvh, O[0][ct]);
      O[1][ct] = MFMA16(ph[1], vvh, O[1][ct]);
      O[1][ct] = MFMA16(ph[1], vvm, O[1][ct]);
      O[1][ct] = MFMA16(pm[1], vvh, O[1][ct]);
      O[1][ct] = MFMA16(pm[1], vvm, O[1][ct]);
      O[1][ct] = MFMA16(ph[1], vvl, O[1][ct]);
      O[1][ct] = MFMA16(pl[1], vvh, O[1][ct]);
    }
    __builtin_amdgcn_s_setprio(0);
  }

  // ---- epilogue: write split-K partials (m, l, raw O) for both tiles -------
  const size_t hofs = (size_t)half * (32 * 1024);
  #pragma unroll
  for (int t = 0; t < 2; ++t) {
    const int ti0 = i0 + 64 * t;
    #pragma unroll
    for (int r = 0; r < 4; ++r) {
      const int row = ti0 + 16 * w + 4 * q + r;
      const size_t grow = hofs + (size_t)b * DIMN + row;
      #pragma unroll
      for (int ct = 0; ct < 4; ++ct)
        Op[grow * 64 + ln + 16 * ct] = O[t][ct][r];
    }
    if (q == 0) {
      const size_t tgrow = hofs + (size_t)b * DIMN + ti0 + 16 * w + ln;
      Mp[tgrow] = m_run[t];
      Lp[tgrow] = l_run[t];
    }
  }
}

// ---------------------------------------------------------------------------
// 3b) final merge + channel-mean (layer 7 partials): 256 blocks x 128 tokens
// ---------------------------------------------------------------------------
__global__ __launch_bounds__(256) void k_merge_mean(
    const float* __restrict__ X,
    const float* __restrict__ Mp, const float* __restrict__ Lp,
    const float* __restrict__ Op, float* __restrict__ meanv) {
  const int c  = threadIdx.x & 63;
  const int tg = threadIdx.x >> 6;
  const size_t t0 = (size_t)blockIdx.x * 128;
  for (int i = tg; i < 128; i += 4) {
    const size_t grow = t0 + i;
    const float m0 = Mp[grow], m1 = Mp[32768 + grow];
    const float l0 = Lp[grow], l1 = Lp[32768 + grow];
    const float mm = fmaxf(m0, m1);
    const float w0 = __expf(m0 - mm), w1 = __expf(m1 - mm);
    const float inv = 1.0f / (l0 * w0 + l1 * w1);
    const float o0 = Op[grow * 64 + c];
    const float o1 = Op[(size_t)2097152 + grow * 64 + c];
    float v = X[grow * 64 + c] + (o0 * w0 + o1 * w1) * inv;
    #pragma unroll
    for (int off = 32; off > 0; off >>= 1)
      v += __shfl_down(v, off, 64);
    if (c == 0) meanv[grow] = v * (1.0f / 64.0f);
  }
}

// ---------------------------------------------------------------------------
// 4) head stage 2: pred[b,k] = meanv[b,:] . last_W[k,:] + last_b[k]
// ---------------------------------------------------------------------------
__global__ __launch_bounds__(256) void k_head2(
    const float* __restrict__ meanv, const float* __restrict__ lW,
    const float* __restrict__ lb, float* __restrict__ out) {
  __shared__ float red[256];
  const int b   = blockIdx.x;
  const int tid = threadIdx.x;
  float acc[NCLS];
  #pragma unroll
  for (int k = 0; k < NCLS; ++k) acc[k] = 0.f;
  for (int n = tid; n < DIMN; n += 256) {
    const float m = meanv[(size_t)b * DIMN + n];
    #pragma unroll
    for (int k = 0; k < NCLS; ++k)
      acc[k] = fmaf(m, lW[k * DIMN + n], acc[k]);
  }
  for (int k = 0; k < NCLS; ++k) {
    red[tid] = acc[k];
    __syncthreads();
    for (int s = 128; s > 0; s >>= 1) {
      if (tid < s) red[tid] += red[tid + s];
      __syncthreads();
    }
    if (tid == 0) out[b * NCLS + k] = red[0] + lb[k];
    __syncthreads();
  }
}

// ===========================================================================
// MIDDLE-TIER PATH (ws >= 41 MB but < split-K need): round-4 structure
// ===========================================================================
__global__ __launch_bounds__(256) void k_attn_s(
    const float* __restrict__ Qg,
    const unsigned short* __restrict__ Kh, const unsigned short* __restrict__ Km,
    const unsigned short* __restrict__ Kl,
    const unsigned short* __restrict__ VhT, const unsigned short* __restrict__ VmT,
    const unsigned short* __restrict__ VlT,
    float* __restrict__ X, float* __restrict__ meanout) {
  __shared__ __align__(16) unsigned short Khs[32 * 72];
  __shared__ __align__(16) unsigned short Kms[32 * 72];
  __shared__ __align__(16) unsigned short Kls[32 * 72];
  __shared__ __align__(16) unsigned short Vhs[64 * 40];
  __shared__ __align__(16) unsigned short Vms[64 * 40];
  __shared__ __align__(16) unsigned short Vls[64 * 40];

  const int tid  = threadIdx.x;
  const int w    = tid >> 6;
  const int lane = tid & 63;
  const int ln   = lane & 15;
  const int q    = lane >> 4;
  const int bid = blockIdx.x;
  const int xcd = bid & 7;
  const int seq = bid >> 3;
  const int b   = xcd * 4 + (seq >> 4);
  const int i0  = (seq & 15) * 64;
  const size_t base = (size_t)b * (DIMN * 64);
  const float scale = 0.03125f;

  const int kj = tid >> 3, kg = tid & 7;
  const int vc = tid >> 2, vg = tid & 3;
  const int klo = kj * 72 + kg * 8;
  const int vlo = vc * 40 + vg * 8;

  bf16x8 qh[2], qm[2], ql[2];
  {
    const int mrow = i0 + 16 * w + ln;
    const float* qp = Qg + base + (size_t)mrow * 64 + 8 * q;
    #pragma unroll
    for (int s = 0; s < 2; ++s) {
      const float4 x0 = ((const float4*)(qp + 32 * s))[0];
      const float4 x1 = ((const float4*)(qp + 32 * s))[1];
      const float xv[8] = {x0.x, x0.y, x0.z, x0.w, x1.x, x1.y, x1.z, x1.w};
      split3_frag(xv, qh[s], qm[s], ql[s]);
    }
  }

  f32x4 O[4];
  #pragma unroll
  for (int ct = 0; ct < 4; ++ct) O[ct] = (f32x4){0.f, 0.f, 0.f, 0.f};
  float m_run = -INFINITY;
  float l_run = 0.f;

  for (int kt = 0; kt < 32; ++kt) {
    __syncthreads();
    {
      const size_t tof = base + (size_t)kt * 2048 + tid * 8;
      const us8 a0 = *(const us8*)&Kh[tof];
      const us8 a1 = *(const us8*)&Km[tof];
      const us8 a2 = *(const us8*)&Kl[tof];
      const us8 b0 = *(const us8*)&VhT[tof];
      const us8 b1 = *(const us8*)&VmT[tof];
      const us8 b2 = *(const us8*)&VlT[tof];
      *(us8*)&Khs[klo] = a0;
      *(us8*)&Kms[klo] = a1;
      *(us8*)&Kls[klo] = a2;
      *(us8*)&Vhs[vlo] = b0;
      *(us8*)&Vms[vlo] = b1;
      *(us8*)&Vls[vlo] = b2;
    }
    __syncthreads();

    f32x4 sacc[2];
    #pragma unroll
    for (int ct = 0; ct < 2; ++ct) {
      f32x4 a = (f32x4){0.f, 0.f, 0.f, 0.f};
      #pragma unroll
      for (int s = 0; s < 2; ++s) {
        const int ko = (16 * ct + ln) * 72 + 32 * s + 8 * q;
        const bf16x8 bh = ld16B(&Khs[ko]);
        const bf16x8 bm = ld16B(&Kms[ko]);
        const bf16x8 bl = ld16B(&Kls[ko]);
        a = MFMA16(bh, ql[s], a);
        a = MFMA16(bl, qh[s], a);
        a = MFMA16(bm, qm[s], a);
        a = MFMA16(bh, qm[s], a);
        a = MFMA16(bm, qh[s], a);
        a = MFMA16(bh, qh[s], a);
      }
      sacc[ct] = a;
    }

    float m8 = fmaxf(fmaxf(fmaxf(sacc[0][0], sacc[0][1]),
                           fmaxf(sacc[0][2], sacc[0][3])),
                     fmaxf(fmaxf(sacc[1][0], sacc[1][1]),
                           fmaxf(sacc[1][2], sacc[1][3])));
    m8 = fmaxf(m8, __shfl_xor(m8, 16, 64));
    m8 = fmaxf(m8, __shfl_xor(m8, 32, 64));
    const float mnew  = fmaxf(m_run, m8 * scale);
    const float alpha = __expf(m_run - mnew);
    m_run = mnew;

    float pv[8];
    float s8 = 0.f;
    #pragma unroll
    for (int ct = 0; ct < 2; ++ct) {
      #pragma unroll
      for (int r = 0; r < 4; ++r) {
        const float p = __expf(sacc[ct][r] * scale - m_run);
        pv[ct * 4 + r] = p;
        s8 += p;
      }
    }
    float sr = s8 + __shfl_xor(s8, 16, 64);
    sr = sr + __shfl_xor(sr, 32, 64);
    l_run = l_run * alpha + sr;

    const int srcb = (lane & 48) + ((lane & 48) >> 2);
    float arow[4];
    #pragma unroll
    for (int r = 0; r < 4; ++r) arow[r] = __shfl(alpha, srcb + r, 64);
    #pragma unroll
    for (int ct = 0; ct < 4; ++ct) {
      #pragma unroll
      for (int r = 0; r < 4; ++r) O[ct][r] *= arow[r];
    }

    bf16x8 ph, pm, pl;
    split3_frag(pv, ph, pm, pl);

    #pragma unroll
    for (int ct = 0; ct < 4; ++ct) {
      const int vo = (16 * ct + ln) * 40 + 8 * q;
      const bf16x8 vvh = ld16B(&Vhs[vo]);
      const bf16x8 vvm = ld16B(&Vms[vo]);
      const bf16x8 vvl = ld16B(&Vls[vo]);
      O[ct] = MFMA16(ph, vvh, O[ct]);
      O[ct] = MFMA16(ph, vvm, O[ct]);
      O[ct] = MFMA16(pm, vvh, O[ct]);
      O[ct] = MFMA16(pm, vvm, O[ct]);
      O[ct] = MFMA16(ph, vvl, O[ct]);
      O[ct] = MFMA16(pl, vvh, O[ct]);
    }
  }

  const int srcb = (lane & 48) + ((lane & 48) >> 2);
  float linv[4];
  #pragma unroll
  for (int r = 0; r < 4; ++r) linv[r] = 1.0f / __shfl(l_run, srcb + r, 64);
  #pragma unroll
  for (int r = 0; r < 4; ++r) {
    const int row = i0 + 16 * w + 4 * q + r;
    float srow = 0.f;
    #pragma unroll
    for (int ct = 0; ct < 4; ++ct) {
      float* xp = X + base + (size_t)row * 64 + ln + 16 * ct;
      const float nv = *xp + O[ct][r] * linv[r];
      *xp = nv;
      srow += nv;
    }
    if (meanout) {
      #pragma unroll
      for (int mk = 1; mk <= 8; mk <<= 1)
        srow += __shfl_xor(srow, mk, 64);
      if (ln == 0) meanout[(size_t)b * DIMN + row] = srow * (1.0f / 64.0f);
    }
  }
}

// ---------------------------------------------------------------------------
// launch
// ---------------------------------------------------------------------------
extern "C" void kernel_launch(void* const* d_in, const int* in_sizes, int n_in,
                              void* d_out, int out_size, void* d_ws, size_t ws_size,
                              hipStream_t stream) {
  const float* image = (const float*)d_in[0];
  const float* WV    = (const float*)d_in[1];
  const float* WK    = (const float*)d_in[2];
  const float* WQ    = (const float*)d_in[3];
  const float* lW    = (const float*)d_in[4];
  const float* lb    = (const float*)d_in[5];
  float* out = (float*)d_out;

  float* ws = (float*)d_ws;
  const size_t NELEM = (size_t)BB * DIMN * CCH;   // 2,097,152
  const size_t NROW  = (size_t)BB * DIMN;         // 32,768

  // layout (floats): X | Q | KVsplits(3N) | Op(2N) | Mp(2R) | Lp(2R) | meanv(R)
  const size_t need_sk   = (7 * NELEM + 5 * NROW) * sizeof(float);
  const size_t need_fast = (5 * NELEM + NROW) * sizeof(float);

  if (ws_size >= need_sk) {
    float* X = ws;
    float* Q = ws + NELEM;
    unsigned short* Kh  = (unsigned short*)(ws + 2 * NELEM);
    unsigned short* Km  = Kh + NELEM;
    unsigned short* Kl  = Kh + 2 * NELEM;
    unsigned short* VhT = Kh + 3 * NELEM;
    unsigned short* VmT = Kh + 4 * NELEM;
    unsigned short* VlT = Kh + 5 * NELEM;
    float* Op    = ws + 5 * NELEM;
    float* Mp    = ws + 7 * NELEM;
    float* Lp    = Mp + 2 * NROW;
    float* meanv = Lp + 2 * NROW;

    k_transpose<<<dim3(DIMN / 64, BB), 256, 0, stream>>>(image, X);
    k_qkv_split<<<(BB * DIMN) / 16, 256, 0, stream>>>(
        X, WQ, WK, WV, Q, Kh, Km, Kl, VhT, VmT, VlT);
    for (int layer = 0; layer < 8; ++layer) {
      k_attn_sk<<<512, 256, 0, stream>>>(
          Q, Kh, Km, Kl, VhT, VmT, VlT, Mp, Lp, Op);
      if (layer < 7)
        k_qkv_merge<<<(BB * DIMN) / 16, 256, 0, stream>>>(
            X, Mp, Lp, Op, WQ, WK, WV, Q, Kh, Km, Kl, VhT, VmT, VlT);
    }
    k_merge_mean<<<256, 256, 0, stream>>>(X, Mp, Lp, Op, meanv);
    k_head2<<<BB, 256, 0, stream>>>(meanv, lW, lb, out);
  } else {
    // middle tier
    float* X = ws;
    float* Q = ws + NELEM;
    unsigned short* Kh  = (unsigned short*)(ws + 2 * NELEM);
    unsigned short* Km  = Kh + NELEM;
    unsigned short* Kl  = Kh + 2 * NELEM;
    unsigned short* VhT = Kh + 3 * NELEM;
    unsigned short* VmT = Kh + 4 * NELEM;
    unsigned short* VlT = Kh + 5 * NELEM;
    float* meanv = ws + 5 * NELEM;
    (void)need_fast;

    k_transpose<<<dim3(DIMN / 64, BB), 256, 0, stream>>>(image, X);
    for (int layer = 0; layer < 8; ++layer) {
      k_qkv_split<<<(BB * DIMN) / 16, 256, 0, stream>>>(
          X, WQ, WK, WV, Q, Kh, Km, Kl, VhT, VmT, VlT);
      k_attn_s<<<512, 256, 0, stream>>>(
          Q, Kh, Km, Kl, VhT, VmT, VlT, X, (layer == 7) ? meanv : nullptr);
    }
    k_head2<<<BB, 256, 0, stream>>>(meanv, lW, lb, out);
  }
}

// Round 9
// 685.971 us; speedup vs baseline: 1.9822x; 1.0217x over previous
//
#include <hip/hip_runtime.h>
#include <math.h>

#define BB    32
#define CCH   64
#define DIMN  1024
#define NCLS  10

typedef __attribute__((ext_vector_type(8))) short bf16x8;
typedef __attribute__((ext_vector_type(4))) float f32x4;
typedef __attribute__((ext_vector_type(4))) unsigned short us4;
typedef __attribute__((ext_vector_type(8))) unsigned short us8;

#define MFMA16(a, b, c) __builtin_amdgcn_mfma_f32_16x16x32_bf16(a, b, c, 0, 0, 0)

__device__ __forceinline__ unsigned short f2bf(float x) {
  unsigned u = __float_as_uint(x);
  unsigned r = u + 0x7fffu + ((u >> 16) & 1u);   // round-to-nearest-even
  return (unsigned short)(r >> 16);
}
__device__ __forceinline__ float bf2f(unsigned short h) {
  return __uint_as_float(((unsigned)h) << 16);
}
// packed split3 of TWO floats via v_cvt_pk_bf16_f32 (hardware RNE == f2bf;
// proven bitwise-safe end-to-end in round 3). Results pre-packed lo/hi.
__device__ __forceinline__ void split3_pk(float x0, float x1,
                                          unsigned& hp, unsigned& mp,
                                          unsigned& lp) {
  unsigned h, m, l;
  asm("v_cvt_pk_bf16_f32 %0, %1, %2" : "=v"(h) : "v"(x0), "v"(x1));
  const float h0 = __uint_as_float(h << 16);
  const float h1 = __uint_as_float(h & 0xffff0000u);
  const float r0 = x0 - h0, r1 = x1 - h1;
  asm("v_cvt_pk_bf16_f32 %0, %1, %2" : "=v"(m) : "v"(r0), "v"(r1));
  const float m0 = __uint_as_float(m << 16);
  const float m1 = __uint_as_float(m & 0xffff0000u);
  asm("v_cvt_pk_bf16_f32 %0, %1, %2" : "=v"(l) : "v"(r0 - m0), "v"(r1 - m1));
  hp = h; mp = m; lp = l;
}
// unpacked-output variant for scalar stores (qkv kernels)
__device__ __forceinline__ void split3_pk2(float x0, float x1,
    unsigned short& h0, unsigned short& m0, unsigned short& l0,
    unsigned short& h1, unsigned short& m1, unsigned short& l1) {
  unsigned h, m, l;
  split3_pk(x0, x1, h, m, l);
  h0 = (unsigned short)h; h1 = (unsigned short)(h >> 16);
  m0 = (unsigned short)m; m1 = (unsigned short)(m >> 16);
  l0 = (unsigned short)l; l1 = (unsigned short)(l >> 16);
}
// 8-element fragment split using the packed path (4x split3_pk)
__device__ __forceinline__ void split3_frag(const float* xv, bf16x8& fh,
                                            bf16x8& fm, bf16x8& fl) {
  union U { bf16x8 v; unsigned d[4]; } uh, um, ul;
  #pragma unroll
  for (int p = 0; p < 4; ++p)
    split3_pk(xv[2 * p], xv[2 * p + 1], uh.d[p], um.d[p], ul.d[p]);
  fh = uh.v; fm = um.v; fl = ul.v;
}
__device__ __forceinline__ bf16x8 ld16B(const unsigned short* p) {
  union { us8 u; bf16x8 v; } c;
  c.u = *(const us8*)p;           // 16B-aligned -> ds_read_b128
  return c.v;
}

// ---------------------------------------------------------------------------
// 1) transpose: image (B,C,DIM) -> X (B,DIM,C)
// ---------------------------------------------------------------------------
__global__ __launch_bounds__(256) void k_transpose(const float* __restrict__ img,
                                                   float* __restrict__ X) {
  __shared__ float tile[64][65];
  const int b  = blockIdx.y;
  const int n0 = blockIdx.x * 64;
  const int tx = threadIdx.x & 63;
  const int ty = threadIdx.x >> 6;
  const float* src = img + (size_t)b * CCH * DIMN;
  #pragma unroll
  for (int c = ty; c < 64; c += 4)
    tile[c][tx] = src[(size_t)c * DIMN + n0 + tx];
  __syncthreads();
  float* dst = X + (size_t)b * DIMN * CCH;
  #pragma unroll
  for (int nn = ty; nn < 64; nn += 4)
    dst[(size_t)(n0 + nn) * CCH + tx] = tile[tx][nn];
}

// ---------------------------------------------------------------------------
// shared qkv inner product: float4 xs reads (wave-uniform broadcast),
// j-ascending FMA order per accumulator preserved (bitwise).
// ---------------------------------------------------------------------------
__device__ __forceinline__ void qkv_inner(
    const float xs[16][64],
    const float* __restrict__ WQ, const float* __restrict__ WK,
    const float* __restrict__ WV, int c, int tg,
    float qa[4], float ka[4], float va[4]) {
  for (int j = 0; j < 64; j += 4) {
    float4 xv[4];
    #pragma unroll
    for (int r = 0; r < 4; ++r)
      xv[r] = *(const float4*)&xs[tg * 4 + r][j];
    #pragma unroll
    for (int jj = 0; jj < 4; ++jj) {
      const float wq = WQ[(j + jj) * 64 + c];
      const float wk = WK[(j + jj) * 64 + c];
      const float wv = WV[(j + jj) * 64 + c];
      #pragma unroll
      for (int r = 0; r < 4; ++r) {
        const float x = ((const float*)&xv[r])[jj];   // static after unroll
        qa[r] = fmaf(x, wq, qa[r]);
        ka[r] = fmaf(x, wk, ka[r]);
        va[r] = fmaf(x, wv, va[r]);
      }
    }
  }
}

// ---------------------------------------------------------------------------
// 2) QKV + per-layer pre-split: Q fp32; K 3-term bf16 [t][c];
//    V 3-term bf16 transposed+tiled [b][kt][c][32], columns sigma-permuted.
// ---------------------------------------------------------------------------
__global__ __launch_bounds__(256) void k_qkv_split(
    const float* __restrict__ X,
    const float* __restrict__ WQ, const float* __restrict__ WK,
    const float* __restrict__ WV,
    float* __restrict__ Q,
    unsigned short* __restrict__ Kh, unsigned short* __restrict__ Km,
    unsigned short* __restrict__ Kl,
    unsigned short* __restrict__ VhT, unsigned short* __restrict__ VmT,
    unsigned short* __restrict__ VlT) {
  __shared__ float xs[16][64];
  __shared__ unsigned short vs[3][16][64];
  const int c  = threadIdx.x & 63;
  const int tg = threadIdx.x >> 6;
  const size_t t0 = (size_t)blockIdx.x * 16;
  #pragma unroll
  for (int r = tg; r < 16; r += 4)
    xs[r][c] = X[(t0 + r) * 64 + c];
  __syncthreads();
  float qa[4] = {0.f,0.f,0.f,0.f};
  float ka[4] = {0.f,0.f,0.f,0.f};
  float va[4] = {0.f,0.f,0.f,0.f};
  qkv_inner(xs, WQ, WK, WV, c, tg, qa, ka, va);
  #pragma unroll
  for (int pr = 0; pr < 2; ++pr) {
    const int r0 = 2 * pr, r1 = 2 * pr + 1;
    const int ta = tg * 4 + r0, tb = tg * 4 + r1;
    const size_t ia = (t0 + ta) * 64 + c;
    const size_t ib = (t0 + tb) * 64 + c;
    Q[ia] = qa[r0]; Q[ib] = qa[r1];
    unsigned short h0, m0, l0, h1, m1, l1;
    split3_pk2(ka[r0], ka[r1], h0, m0, l0, h1, m1, l1);
    Kh[ia] = h0; Km[ia] = m0; Kl[ia] = l0;
    Kh[ib] = h1; Km[ib] = m1; Kl[ib] = l1;
    split3_pk2(va[r0], va[r1], h0, m0, l0, h1, m1, l1);
    vs[0][ta][c] = h0; vs[1][ta][c] = m0; vs[2][ta][c] = l0;
    vs[0][tb][c] = h1; vs[1][tb][c] = m1; vs[2][tb][c] = l1;
  }
  __syncthreads();
  {
    const int row  = threadIdx.x >> 2;
    const int part = threadIdx.x & 3;
    const size_t bofs = (t0 >> 10) * ((size_t)DIMN * 64);
    const size_t kt   = (t0 & 1023) >> 5;
    const size_t tin  = (size_t)part * 8 + ((t0 & 31) >> 2);   // sigma permute
    unsigned short* dst[3] = {VhT, VmT, VlT};
    #pragma unroll
    for (int term = 0; term < 3; ++term) {
      us4 pk;
      #pragma unroll
      for (int i = 0; i < 4; ++i) pk[i] = vs[term][part * 4 + i][row];
      *(us4*)&dst[term][bofs + kt * 2048 + (size_t)row * 32 + tin] = pk;
    }
  }
}

// ---------------------------------------------------------------------------
// 2b) QKV with FUSED 2-way SPLIT-K MERGE of the previous layer.
// ---------------------------------------------------------------------------
__global__ __launch_bounds__(256) void k_qkv_merge(
    float* __restrict__ X,
    const float* __restrict__ Mp, const float* __restrict__ Lp,
    const float* __restrict__ Op,
    const float* __restrict__ WQ, const float* __restrict__ WK,
    const float* __restrict__ WV,
    float* __restrict__ Q,
    unsigned short* __restrict__ Kh, unsigned short* __restrict__ Km,
    unsigned short* __restrict__ Kl,
    unsigned short* __restrict__ VhT, unsigned short* __restrict__ VmT,
    unsigned short* __restrict__ VlT) {
  __shared__ float xs[16][64];
  __shared__ unsigned short vs[3][16][64];
  const int c  = threadIdx.x & 63;
  const int tg = threadIdx.x >> 6;
  const size_t t0 = (size_t)blockIdx.x * 16;
  #pragma unroll
  for (int r = tg; r < 16; r += 4) {
    const size_t grow = t0 + r;                 // global row 0..32767
    const float m0 = Mp[grow], m1 = Mp[32768 + grow];
    const float l0 = Lp[grow], l1 = Lp[32768 + grow];
    const float mm = fmaxf(m0, m1);
    const float w0 = __expf(m0 - mm), w1 = __expf(m1 - mm);
    const float inv = 1.0f / (l0 * w0 + l1 * w1);
    const float o0 = Op[grow * 64 + c];
    const float o1 = Op[(size_t)2097152 + grow * 64 + c];
    const float xn = X[grow * 64 + c] + (o0 * w0 + o1 * w1) * inv;
    X[grow * 64 + c] = xn;
    xs[r][c] = xn;
  }
  __syncthreads();
  float qa[4] = {0.f,0.f,0.f,0.f};
  float ka[4] = {0.f,0.f,0.f,0.f};
  float va[4] = {0.f,0.f,0.f,0.f};
  qkv_inner(xs, WQ, WK, WV, c, tg, qa, ka, va);
  #pragma unroll
  for (int pr = 0; pr < 2; ++pr) {
    const int r0 = 2 * pr, r1 = 2 * pr + 1;
    const int ta = tg * 4 + r0, tb = tg * 4 + r1;
    const size_t ia = (t0 + ta) * 64 + c;
    const size_t ib = (t0 + tb) * 64 + c;
    Q[ia] = qa[r0]; Q[ib] = qa[r1];
    unsigned short h0, m0, l0, h1, m1, l1;
    split3_pk2(ka[r0], ka[r1], h0, m0, l0, h1, m1, l1);
    Kh[ia] = h0; Km[ia] = m0; Kl[ia] = l0;
    Kh[ib] = h1; Km[ib] = m1; Kl[ib] = l1;
    split3_pk2(va[r0], va[r1], h0, m0, l0, h1, m1, l1);
    vs[0][ta][c] = h0; vs[1][ta][c] = m0; vs[2][ta][c] = l0;
    vs[0][tb][c] = h1; vs[1][tb][c] = m1; vs[2][tb][c] = l1;
  }
  __syncthreads();
  {
    const int row  = threadIdx.x >> 2;
    const int part = threadIdx.x & 3;
    const size_t bofs = (t0 >> 10) * ((size_t)DIMN * 64);
    const size_t kt   = (t0 & 1023) >> 5;
    const size_t tin  = (size_t)part * 8 + ((t0 & 31) >> 2);   // sigma permute
    unsigned short* dst[3] = {VhT, VmT, VlT};
    #pragma unroll
    for (int term = 0; term < 3; ++term) {
      us4 pk;
      #pragma unroll
      for (int i = 0; i < 4; ++i) pk[i] = vs[term][part * 4 + i][row];
      *(us4*)&dst[term][bofs + kt * 2048 + (size_t)row * 32 + tin] = pk;
    }
  }
}

// ---------------------------------------------------------------------------
// 3) MFMA flash attention, SPLIT-K (2 halves), SWAPPED QK^T, TWO Q-TILES per
//    block + REGISTER PREFETCH of the next K/V tile (T14: retried now that
//    launch_bounds(256,2) gives VGPR headroom -- round 1's failure was spill
//    at the 128-VGPR/4-block cap, visible as WRITE_SIZE inflation).
//    Loads identical, arithmetic round-8 bitwise; only issue order changed.
// ---------------------------------------------------------------------------
__global__ __launch_bounds__(256, 2) void k_attn_sk(
    const float* __restrict__ Qg,
    const unsigned short* __restrict__ Kh, const unsigned short* __restrict__ Km,
    const unsigned short* __restrict__ Kl,
    const unsigned short* __restrict__ VhT, const unsigned short* __restrict__ VmT,
    const unsigned short* __restrict__ VlT,
    float* __restrict__ Mp, float* __restrict__ Lp, float* __restrict__ Op) {
  __shared__ __align__(16) unsigned short Khs[32 * 72];
  __shared__ __align__(16) unsigned short Kms[32 * 72];
  __shared__ __align__(16) unsigned short Kls[32 * 72];
  __shared__ __align__(16) unsigned short Vhs[64 * 40];   // V^T: [c][slot]
  __shared__ __align__(16) unsigned short Vms[64 * 40];
  __shared__ __align__(16) unsigned short Vls[64 * 40];

  const int tid  = threadIdx.x;
  const int w    = tid >> 6;
  const int lane = tid & 63;
  const int ln   = lane & 15;
  const int q    = lane >> 4;

  // XCD-aware swizzle: 512 blocks; batch pinned to one XCD
  const int bid   = blockIdx.x;            // 0..511
  const int xcd   = bid & 7;
  const int seq   = bid >> 3;              // 0..63
  const int b     = xcd * 4 + (seq >> 4);  // 4 batches per XCD
  const int local = seq & 15;
  const int half  = local >> 3;            // K-split half
  const int i0    = (local & 7) * 128;     // Q tile pair base

  const size_t base = (size_t)b * (DIMN * 64);
  const float scale = 0.03125f;

  const int kj = tid >> 3, kg = tid & 7;
  const int vc = tid >> 2, vg = tid & 3;
  const int klo = kj * 72 + kg * 8;
  const int vlo = vc * 40 + vg * 8;

  // ---- Q fragments for both tiles: 3-term split (packed) -------------------
  bf16x8 qh[2][2], qm[2][2], ql[2][2];     // [tile][s]
  #pragma unroll
  for (int t = 0; t < 2; ++t) {
    const int mrow = i0 + 64 * t + 16 * w + ln;
    const float* qp = Qg + base + (size_t)mrow * 64 + 8 * q;
    #pragma unroll
    for (int s = 0; s < 2; ++s) {
      const float4 x0 = ((const float4*)(qp + 32 * s))[0];
      const float4 x1 = ((const float4*)(qp + 32 * s))[1];
      const float xv[8] = {x0.x, x0.y, x0.z, x0.w, x1.x, x1.y, x1.z, x1.w};
      split3_frag(xv, qh[t][s], qm[t][s], ql[t][s]);
    }
  }

  f32x4 O[2][4];
  #pragma unroll
  for (int t = 0; t < 2; ++t)
    #pragma unroll
    for (int ct = 0; ct < 4; ++ct) O[t][ct] = (f32x4){0.f, 0.f, 0.f, 0.f};
  float m_run[2] = {-INFINITY, -INFINITY};
  float l_run[2] = {0.f, 0.f};

  const int kt0 = half * 16;

  // ---- prologue: prefetch first tile into registers ------------------------
  us8 ra0, ra1, ra2, rb0, rb1, rb2;
  {
    const size_t tof = base + (size_t)kt0 * 2048 + tid * 8;
    ra0 = *(const us8*)&Kh[tof];
    ra1 = *(const us8*)&Km[tof];
    ra2 = *(const us8*)&Kl[tof];
    rb0 = *(const us8*)&VhT[tof];
    rb1 = *(const us8*)&VmT[tof];
    rb2 = *(const us8*)&VlT[tof];
  }

  for (int kt = kt0; kt < kt0 + 16; ++kt) {
    __syncthreads();   // A: previous iteration's K/V readers done

    // ---- write prefetched tile regs -> LDS ---------------------------------
    *(us8*)&Khs[klo] = ra0;
    *(us8*)&Kms[klo] = ra1;
    *(us8*)&Kls[klo] = ra2;
    *(us8*)&Vhs[vlo] = rb0;
    *(us8*)&Vms[vlo] = rb1;
    *(us8*)&Vls[vlo] = rb2;
    __syncthreads();   // B: staged tile visible

    // ---- issue next tile's loads; latency hides under 96 MFMA + softmax ----
    if (kt + 1 < kt0 + 16) {
      const size_t tof = base + (size_t)(kt + 1) * 2048 + tid * 8;
      ra0 = *(const us8*)&Kh[tof];
      ra1 = *(const us8*)&Km[tof];
      ra2 = *(const us8*)&Kl[tof];
      rb0 = *(const us8*)&VhT[tof];
      rb1 = *(const us8*)&VmT[tof];
      rb2 = *(const us8*)&VlT[tof];
    }

    // ---- S strips = mfma(K, Q_t): K fragments loaded once, used twice ------
    f32x4 sacc[2][2];                       // [tile][ct]
    __builtin_amdgcn_s_setprio(1);
    #pragma unroll
    for (int ct = 0; ct < 2; ++ct) {
      f32x4 aA = (f32x4){0.f, 0.f, 0.f, 0.f};
      f32x4 aB = (f32x4){0.f, 0.f, 0.f, 0.f};
      #pragma unroll
      for (int s = 0; s < 2; ++s) {
        const int ko = (16 * ct + ln) * 72 + 32 * s + 8 * q;
        const bf16x8 bh = ld16B(&Khs[ko]);
        const bf16x8 bm = ld16B(&Kms[ko]);
        const bf16x8 bl = ld16B(&Kls[ko]);
        aA = MFMA16(bh, ql[0][s], aA);
        aA = MFMA16(bl, qh[0][s], aA);
        aA = MFMA16(bm, qm[0][s], aA);
        aA = MFMA16(bh, qm[0][s], aA);
        aA = MFMA16(bm, qh[0][s], aA);
        aA = MFMA16(bh, qh[0][s], aA);
        aB = MFMA16(bh, ql[1][s], aB);
        aB = MFMA16(bl, qh[1][s], aB);
        aB = MFMA16(bm, qm[1][s], aB);
        aB = MFMA16(bh, qm[1][s], aB);
        aB = MFMA16(bm, qh[1][s], aB);
        aB = MFMA16(bh, qh[1][s], aB);
      }
      sacc[0][ct] = aA; sacc[1][ct] = aB;
    }
    __builtin_amdgcn_s_setprio(0);

    // ---- online softmax per tile (one Q-token per lane) --------------------
    bf16x8 ph[2], pm[2], pl[2];
    const int srcb = (lane & 48) + ((lane & 48) >> 2);
    #pragma unroll
    for (int t = 0; t < 2; ++t) {
      float m8 = fmaxf(fmaxf(fmaxf(sacc[t][0][0], sacc[t][0][1]),
                             fmaxf(sacc[t][0][2], sacc[t][0][3])),
                       fmaxf(fmaxf(sacc[t][1][0], sacc[t][1][1]),
                             fmaxf(sacc[t][1][2], sacc[t][1][3])));
      m8 = fmaxf(m8, __shfl_xor(m8, 16, 64));
      m8 = fmaxf(m8, __shfl_xor(m8, 32, 64));
      const float mnew  = fmaxf(m_run[t], m8 * scale);
      const float alpha = __expf(m_run[t] - mnew);
      m_run[t] = mnew;

      float pv[8];
      float s8 = 0.f;
      #pragma unroll
      for (int ct = 0; ct < 2; ++ct) {
        #pragma unroll
        for (int r = 0; r < 4; ++r) {
          const float p = __expf(sacc[t][ct][r] * scale - m_run[t]);
          pv[ct * 4 + r] = p;
          s8 += p;
        }
      }
      float sr = s8 + __shfl_xor(s8, 16, 64);
      sr = sr + __shfl_xor(sr, 32, 64);
      l_run[t] = l_run[t] * alpha + sr;

      float arow[4];
      #pragma unroll
      for (int r = 0; r < 4; ++r) arow[r] = __shfl(alpha, srcb + r, 64);
      #pragma unroll
      for (int ct = 0; ct < 4; ++ct) {
        #pragma unroll
        for (int r = 0; r < 4; ++r) O[t][ct][r] *= arow[r];
      }

      split3_frag(pv, ph[t], pm[t], pl[t]);
    }

    // ---- O += P @ V: V fragments loaded once, used for both tiles ----------
    __builtin_amdgcn_s_setprio(1);
    #pragma unroll
    for (int ct = 0; ct < 4; ++ct) {
      const int vo = (16 * ct + ln) * 40 + 8 * q;
      const bf16x8 vvh = ld16B(&Vhs[vo]);
      const bf16x8 vvm = ld16B(&Vms[vo]);
      const bf16x8 vvl = ld16B(&Vls[vo]);
      O[0][ct] = MFMA16(ph[0], vvh, O[0][ct]);
      O[0][ct] = MFMA16(ph[0], vvm, O[0][ct]);
      O[0][ct] = MFMA16(pm[0], vvh, O[0][ct]);
      O[0][ct] = MFMA16(pm[0], vvm, O[0][ct]);
      O[0][ct] = MFMA16(ph[0], vvl, O[0][ct]);
      O[0][ct] = MFMA16(pl[0], vvh, O[0][ct]);
      O[1][ct] = MFMA16(ph[1], vvh, O[1][ct]);
      O[1][ct] = MFMA16(ph[1], vvm, O[1][ct]);
      O[1][ct] = MFMA16(pm[1], vvh, O[1][ct]);
      O[1][ct] = MFMA16(pm[1], vvm, O[1][ct]);
      O[1][ct] = MFMA16(ph[1], vvl, O[1][ct]);
      O[1][ct] = MFMA16(pl[1], vvh, O[1][ct]);
    }
    __builtin_amdgcn_s_setprio(0);
  }

  // ---- epilogue: write split-K partials (m, l, raw O) for both tiles -------
  const size_t hofs = (size_t)half * (32 * 1024);
  #pragma unroll
  for (int t = 0; t < 2; ++t) {
    const int ti0 = i0 + 64 * t;
    #pragma unroll
    for (int r = 0; r < 4; ++r) {
      const int row = ti0 + 16 * w + 4 * q + r;
      const size_t grow = hofs + (size_t)b * DIMN + row;
      #pragma unroll
      for (int ct = 0; ct < 4; ++ct)
        Op[grow * 64 + ln + 16 * ct] = O[t][ct][r];
    }
    if (q == 0) {
      const size_t tgrow = hofs + (size_t)b * DIMN + ti0 + 16 * w + ln;
      Mp[tgrow] = m_run[t];
      Lp[tgrow] = l_run[t];
    }
  }
}

// ---------------------------------------------------------------------------
// 3b) final merge + channel-mean (layer 7 partials): 256 blocks x 128 tokens
// ---------------------------------------------------------------------------
__global__ __launch_bounds__(256) void k_merge_mean(
    const float* __restrict__ X,
    const float* __restrict__ Mp, const float* __restrict__ Lp,
    const float* __restrict__ Op, float* __restrict__ meanv) {
  const int c  = threadIdx.x & 63;
  const int tg = threadIdx.x >> 6;
  const size_t t0 = (size_t)blockIdx.x * 128;
  for (int i = tg; i < 128; i += 4) {
    const size_t grow = t0 + i;
    const float m0 = Mp[grow], m1 = Mp[32768 + grow];
    const float l0 = Lp[grow], l1 = Lp[32768 + grow];
    const float mm = fmaxf(m0, m1);
    const float w0 = __expf(m0 - mm), w1 = __expf(m1 - mm);
    const float inv = 1.0f / (l0 * w0 + l1 * w1);
    const float o0 = Op[grow * 64 + c];
    const float o1 = Op[(size_t)2097152 + grow * 64 + c];
    float v = X[grow * 64 + c] + (o0 * w0 + o1 * w1) * inv;
    #pragma unroll
    for (int off = 32; off > 0; off >>= 1)
      v += __shfl_down(v, off, 64);
    if (c == 0) meanv[grow] = v * (1.0f / 64.0f);
  }
}

// ---------------------------------------------------------------------------
// 4) head stage 2: pred[b,k] = meanv[b,:] . last_W[k,:] + last_b[k]
// ---------------------------------------------------------------------------
__global__ __launch_bounds__(256) void k_head2(
    const float* __restrict__ meanv, const float* __restrict__ lW,
    const float* __restrict__ lb, float* __restrict__ out) {
  __shared__ float red[256];
  const int b   = blockIdx.x;
  const int tid = threadIdx.x;
  float acc[NCLS];
  #pragma unroll
  for (int k = 0; k < NCLS; ++k) acc[k] = 0.f;
  for (int n = tid; n < DIMN; n += 256) {
    const float m = meanv[(size_t)b * DIMN + n];
    #pragma unroll
    for (int k = 0; k < NCLS; ++k)
      acc[k] = fmaf(m, lW[k * DIMN + n], acc[k]);
  }
  for (int k = 0; k < NCLS; ++k) {
    red[tid] = acc[k];
    __syncthreads();
    for (int s = 128; s > 0; s >>= 1) {
      if (tid < s) red[tid] += red[tid + s];
      __syncthreads();
    }
    if (tid == 0) out[b * NCLS + k] = red[0] + lb[k];
    __syncthreads();
  }
}

// ===========================================================================
// MIDDLE-TIER PATH (ws >= 41 MB but < split-K need): round-4 structure
// ===========================================================================
__global__ __launch_bounds__(256) void k_attn_s(
    const float* __restrict__ Qg,
    const unsigned short* __restrict__ Kh, const unsigned short* __restrict__ Km,
    const unsigned short* __restrict__ Kl,
    const unsigned short* __restrict__ VhT, const unsigned short* __restrict__ VmT,
    const unsigned short* __restrict__ VlT,
    float* __restrict__ X, float* __restrict__ meanout) {
  __shared__ __align__(16) unsigned short Khs[32 * 72];
  __shared__ __align__(16) unsigned short Kms[32 * 72];
  __shared__ __align__(16) unsigned short Kls[32 * 72];
  __shared__ __align__(16) unsigned short Vhs[64 * 40];
  __shared__ __align__(16) unsigned short Vms[64 * 40];
  __shared__ __align__(16) unsigned short Vls[64 * 40];

  const int tid  = threadIdx.x;
  const int w    = tid >> 6;
  const int lane = tid & 63;
  const int ln   = lane & 15;
  const int q    = lane >> 4;
  const int bid = blockIdx.x;
  const int xcd = bid & 7;
  const int seq = bid >> 3;
  const int b   = xcd * 4 + (seq >> 4);
  const int i0  = (seq & 15) * 64;
  const size_t base = (size_t)b * (DIMN * 64);
  const float scale = 0.03125f;

  const int kj = tid >> 3, kg = tid & 7;
  const int vc = tid >> 2, vg = tid & 3;
  const int klo = kj * 72 + kg * 8;
  const int vlo = vc * 40 + vg * 8;

  bf16x8 qh[2], qm[2], ql[2];
  {
    const int mrow = i0 + 16 * w + ln;
    const float* qp = Qg + base + (size_t)mrow * 64 + 8 * q;
    #pragma unroll
    for (int s = 0; s < 2; ++s) {
      const float4 x0 = ((const float4*)(qp + 32 * s))[0];
      const float4 x1 = ((const float4*)(qp + 32 * s))[1];
      const float xv[8] = {x0.x, x0.y, x0.z, x0.w, x1.x, x1.y, x1.z, x1.w};
      split3_frag(xv, qh[s], qm[s], ql[s]);
    }
  }

  f32x4 O[4];
  #pragma unroll
  for (int ct = 0; ct < 4; ++ct) O[ct] = (f32x4){0.f, 0.f, 0.f, 0.f};
  float m_run = -INFINITY;
  float l_run = 0.f;

  for (int kt = 0; kt < 32; ++kt) {
    __syncthreads();
    {
      const size_t tof = base + (size_t)kt * 2048 + tid * 8;
      const us8 a0 = *(const us8*)&Kh[tof];
      const us8 a1 = *(const us8*)&Km[tof];
      const us8 a2 = *(const us8*)&Kl[tof];
      const us8 b0 = *(const us8*)&VhT[tof];
      const us8 b1 = *(const us8*)&VmT[tof];
      const us8 b2 = *(const us8*)&VlT[tof];
      *(us8*)&Khs[klo] = a0;
      *(us8*)&Kms[klo] = a1;
      *(us8*)&Kls[klo] = a2;
      *(us8*)&Vhs[vlo] = b0;
      *(us8*)&Vms[vlo] = b1;
      *(us8*)&Vls[vlo] = b2;
    }
    __syncthreads();

    f32x4 sacc[2];
    #pragma unroll
    for (int ct = 0; ct < 2; ++ct) {
      f32x4 a = (f32x4){0.f, 0.f, 0.f, 0.f};
      #pragma unroll
      for (int s = 0; s < 2; ++s) {
        const int ko = (16 * ct + ln) * 72 + 32 * s + 8 * q;
        const bf16x8 bh = ld16B(&Khs[ko]);
        const bf16x8 bm = ld16B(&Kms[ko]);
        const bf16x8 bl = ld16B(&Kls[ko]);
        a = MFMA16(bh, ql[s], a);
        a = MFMA16(bl, qh[s], a);
        a = MFMA16(bm, qm[s], a);
        a = MFMA16(bh, qm[s], a);
        a = MFMA16(bm, qh[s], a);
        a = MFMA16(bh, qh[s], a);
      }
      sacc[ct] = a;
    }

    float m8 = fmaxf(fmaxf(fmaxf(sacc[0][0], sacc[0][1]),
                           fmaxf(sacc[0][2], sacc[0][3])),
                     fmaxf(fmaxf(sacc[1][0], sacc[1][1]),
                           fmaxf(sacc[1][2], sacc[1][3])));
    m8 = fmaxf(m8, __shfl_xor(m8, 16, 64));
    m8 = fmaxf(m8, __shfl_xor(m8, 32, 64));
    const float mnew  = fmaxf(m_run, m8 * scale);
    const float alpha = __expf(m_run - mnew);
    m_run = mnew;

    float pv[8];
    float s8 = 0.f;
    #pragma unroll
    for (int ct = 0; ct < 2; ++ct) {
      #pragma unroll
      for (int r = 0; r < 4; ++r) {
        const float p = __expf(sacc[ct][r] * scale - m_run);
        pv[ct * 4 + r] = p;
        s8 += p;
      }
    }
    float sr = s8 + __shfl_xor(s8, 16, 64);
    sr = sr + __shfl_xor(sr, 32, 64);
    l_run = l_run * alpha + sr;

    const int srcb = (lane & 48) + ((lane & 48) >> 2);
    float arow[4];
    #pragma unroll
    for (int r = 0; r < 4; ++r) arow[r] = __shfl(alpha, srcb + r, 64);
    #pragma unroll
    for (int ct = 0; ct < 4; ++ct) {
      #pragma unroll
      for (int r = 0; r < 4; ++r) O[ct][r] *= arow[r];
    }

    bf16x8 ph, pm, pl;
    split3_frag(pv, ph, pm, pl);

    #pragma unroll
    for (int ct = 0; ct < 4; ++ct) {
      const int vo = (16 * ct + ln) * 40 + 8 * q;
      const bf16x8 vvh = ld16B(&Vhs[vo]);
      const bf16x8 vvm = ld16B(&Vms[vo]);
      const bf16x8 vvl = ld16B(&Vls[vo]);
      O[ct] = MFMA16(ph, vvh, O[ct]);
      O[ct] = MFMA16(ph, vvm, O[ct]);
      O[ct] = MFMA16(pm, vvh, O[ct]);
      O[ct] = MFMA16(pm, vvm, O[ct]);
      O[ct] = MFMA16(ph, vvl, O[ct]);
      O[ct] = MFMA16(pl, vvh, O[ct]);
    }
  }

  const int srcb = (lane & 48) + ((lane & 48) >> 2);
  float linv[4];
  #pragma unroll
  for (int r = 0; r < 4; ++r) linv[r] = 1.0f / __shfl(l_run, srcb + r, 64);
  #pragma unroll
  for (int r = 0; r < 4; ++r) {
    const int row = i0 + 16 * w + 4 * q + r;
    float srow = 0.f;
    #pragma unroll
    for (int ct = 0; ct < 4; ++ct) {
      float* xp = X + base + (size_t)row * 64 + ln + 16 * ct;
      const float nv = *xp + O[ct][r] * linv[r];
      *xp = nv;
      srow += nv;
    }
    if (meanout) {
      #pragma unroll
      for (int mk = 1; mk <= 8; mk <<= 1)
        srow += __shfl_xor(srow, mk, 64);
      if (ln == 0) meanout[(size_t)b * DIMN + row] = srow * (1.0f / 64.0f);
    }
  }
}

// ---------------------------------------------------------------------------
// launch
// ---------------------------------------------------------------------------
extern "C" void kernel_launch(void* const* d_in, const int* in_sizes, int n_in,
                              void* d_out, int out_size, void* d_ws, size_t ws_size,
                              hipStream_t stream) {
  const float* image = (const float*)d_in[0];
  const float* WV    = (const float*)d_in[1];
  const float* WK    = (const float*)d_in[2];
  const float* WQ    = (const float*)d_in[3];
  const float* lW    = (const float*)d_in[4];
  const float* lb    = (const float*)d_in[5];
  float* out = (float*)d_out;

  float* ws = (float*)d_ws;
  const size_t NELEM = (size_t)BB * DIMN * CCH;   // 2,097,152
  const size_t NROW  = (size_t)BB * DIMN;         // 32,768

  // layout (floats): X | Q | KVsplits(3N) | Op(2N) | Mp(2R) | Lp(2R) | meanv(R)
  const size_t need_sk   = (7 * NELEM + 5 * NROW) * sizeof(float);
  const size_t need_fast = (5 * NELEM + NROW) * sizeof(float);

  if (ws_size >= need_sk) {
    float* X = ws;
    float* Q = ws + NELEM;
    unsigned short* Kh  = (unsigned short*)(ws + 2 * NELEM);
    unsigned short* Km  = Kh + NELEM;
    unsigned short* Kl  = Kh + 2 * NELEM;
    unsigned short* VhT = Kh + 3 * NELEM;
    unsigned short* VmT = Kh + 4 * NELEM;
    unsigned short* VlT = Kh + 5 * NELEM;
    float* Op    = ws + 5 * NELEM;
    float* Mp    = ws + 7 * NELEM;
    float* Lp    = Mp + 2 * NROW;
    float* meanv = Lp + 2 * NROW;

    k_transpose<<<dim3(DIMN / 64, BB), 256, 0, stream>>>(image, X);
    k_qkv_split<<<(BB * DIMN) / 16, 256, 0, stream>>>(
        X, WQ, WK, WV, Q, Kh, Km, Kl, VhT, VmT, VlT);
    for (int layer = 0; layer < 8; ++layer) {
      k_attn_sk<<<512, 256, 0, stream>>>(
          Q, Kh, Km, Kl, VhT, VmT, VlT, Mp, Lp, Op);
      if (layer < 7)
        k_qkv_merge<<<(BB * DIMN) / 16, 256, 0, stream>>>(
            X, Mp, Lp, Op, WQ, WK, WV, Q, Kh, Km, Kl, VhT, VmT, VlT);
    }
    k_merge_mean<<<256, 256, 0, stream>>>(X, Mp, Lp, Op, meanv);
    k_head2<<<BB, 256, 0, stream>>>(meanv, lW, lb, out);
  } else {
    // middle tier
    float* X = ws;
    float* Q = ws + NELEM;
    unsigned short* Kh  = (unsigned short*)(ws + 2 * NELEM);
    unsigned short* Km  = Kh + NELEM;
    unsigned short* Kl  = Kh + 2 * NELEM;
    unsigned short* VhT = Kh + 3 * NELEM;
    unsigned short* VmT = Kh + 4 * NELEM;
    unsigned short* VlT = Kh + 5 * NELEM;
    float* meanv = ws + 5 * NELEM;
    (void)need_fast;

    k_transpose<<<dim3(DIMN / 64, BB), 256, 0, stream>>>(image, X);
    for (int layer = 0; layer < 8; ++layer) {
      k_qkv_split<<<(BB * DIMN) / 16, 256, 0, stream>>>(
          X, WQ, WK, WV, Q, Kh, Km, Kl, VhT, VmT, VlT);
      k_attn_s<<<512, 256, 0, stream>>>(
          Q, Kh, Km, Kl, VhT, VmT, VlT, X, (layer == 7) ? meanv : nullptr);
    }
    k_head2<<<BB, 256, 0, stream>>>(meanv, lW, lb, out);
  }
}

// Round 10
// 676.737 us; speedup vs baseline: 2.0092x; 1.0136x over previous
//
#include <hip/hip_runtime.h>
#include <math.h>

#define BB    32
#define CCH   64
#define DIMN  1024
#define NCLS  10

typedef __attribute__((ext_vector_type(8))) short bf16x8;
typedef __attribute__((ext_vector_type(4))) float f32x4;
typedef __attribute__((ext_vector_type(4))) unsigned short us4;
typedef __attribute__((ext_vector_type(8))) unsigned short us8;

#define MFMA16(a, b, c) __builtin_amdgcn_mfma_f32_16x16x32_bf16(a, b, c, 0, 0, 0)

__device__ __forceinline__ unsigned short f2bf(float x) {
  unsigned u = __float_as_uint(x);
  unsigned r = u + 0x7fffu + ((u >> 16) & 1u);   // round-to-nearest-even
  return (unsigned short)(r >> 16);
}
__device__ __forceinline__ float bf2f(unsigned short h) {
  return __uint_as_float(((unsigned)h) << 16);
}
// packed split3 of TWO floats via v_cvt_pk_bf16_f32 (hardware RNE == f2bf;
// proven bitwise-safe end-to-end in round 3). Results pre-packed lo/hi.
__device__ __forceinline__ void split3_pk(float x0, float x1,
                                          unsigned& hp, unsigned& mp,
                                          unsigned& lp) {
  unsigned h, m, l;
  asm("v_cvt_pk_bf16_f32 %0, %1, %2" : "=v"(h) : "v"(x0), "v"(x1));
  const float h0 = __uint_as_float(h << 16);
  const float h1 = __uint_as_float(h & 0xffff0000u);
  const float r0 = x0 - h0, r1 = x1 - h1;
  asm("v_cvt_pk_bf16_f32 %0, %1, %2" : "=v"(m) : "v"(r0), "v"(r1));
  const float m0 = __uint_as_float(m << 16);
  const float m1 = __uint_as_float(m & 0xffff0000u);
  asm("v_cvt_pk_bf16_f32 %0, %1, %2" : "=v"(l) : "v"(r0 - m0), "v"(r1 - m1));
  hp = h; mp = m; lp = l;
}
// unpacked-output variant for scalar stores (qkv kernels)
__device__ __forceinline__ void split3_pk2(float x0, float x1,
    unsigned short& h0, unsigned short& m0, unsigned short& l0,
    unsigned short& h1, unsigned short& m1, unsigned short& l1) {
  unsigned h, m, l;
  split3_pk(x0, x1, h, m, l);
  h0 = (unsigned short)h; h1 = (unsigned short)(h >> 16);
  m0 = (unsigned short)m; m1 = (unsigned short)(m >> 16);
  l0 = (unsigned short)l; l1 = (unsigned short)(l >> 16);
}
// 8-element fragment split using the packed path (4x split3_pk)
__device__ __forceinline__ void split3_frag(const float* xv, bf16x8& fh,
                                            bf16x8& fm, bf16x8& fl) {
  union U { bf16x8 v; unsigned d[4]; } uh, um, ul;
  #pragma unroll
  for (int p = 0; p < 4; ++p)
    split3_pk(xv[2 * p], xv[2 * p + 1], uh.d[p], um.d[p], ul.d[p]);
  fh = uh.v; fm = um.v; fl = ul.v;
}
__device__ __forceinline__ bf16x8 ld16B(const unsigned short* p) {
  union { us8 u; bf16x8 v; } c;
  c.u = *(const us8*)p;           // 16B-aligned -> ds_read_b128
  return c.v;
}

// ---------------------------------------------------------------------------
// 1) transpose: image (B,C,DIM) -> X (B,DIM,C)
// ---------------------------------------------------------------------------
__global__ __launch_bounds__(256) void k_transpose(const float* __restrict__ img,
                                                   float* __restrict__ X) {
  __shared__ float tile[64][65];
  const int b  = blockIdx.y;
  const int n0 = blockIdx.x * 64;
  const int tx = threadIdx.x & 63;
  const int ty = threadIdx.x >> 6;
  const float* src = img + (size_t)b * CCH * DIMN;
  #pragma unroll
  for (int c = ty; c < 64; c += 4)
    tile[c][tx] = src[(size_t)c * DIMN + n0 + tx];
  __syncthreads();
  float* dst = X + (size_t)b * DIMN * CCH;
  #pragma unroll
  for (int nn = ty; nn < 64; nn += 4)
    dst[(size_t)(n0 + nn) * CCH + tx] = tile[tx][nn];
}

// ---------------------------------------------------------------------------
// shared qkv inner product: float4 xs reads (wave-uniform broadcast),
// j-ascending FMA order per accumulator preserved (bitwise).
// ---------------------------------------------------------------------------
__device__ __forceinline__ void qkv_inner(
    const float xs[16][64],
    const float* __restrict__ WQ, const float* __restrict__ WK,
    const float* __restrict__ WV, int c, int tg,
    float qa[4], float ka[4], float va[4]) {
  for (int j = 0; j < 64; j += 4) {
    float4 xv[4];
    #pragma unroll
    for (int r = 0; r < 4; ++r)
      xv[r] = *(const float4*)&xs[tg * 4 + r][j];
    #pragma unroll
    for (int jj = 0; jj < 4; ++jj) {
      const float wq = WQ[(j + jj) * 64 + c];
      const float wk = WK[(j + jj) * 64 + c];
      const float wv = WV[(j + jj) * 64 + c];
      #pragma unroll
      for (int r = 0; r < 4; ++r) {
        const float x = ((const float*)&xv[r])[jj];   // static after unroll
        qa[r] = fmaf(x, wq, qa[r]);
        ka[r] = fmaf(x, wk, ka[r]);
        va[r] = fmaf(x, wv, va[r]);
      }
    }
  }
}

// ---------------------------------------------------------------------------
// 2) QKV + per-layer pre-split: Q fp32; K 3-term bf16 [t][c];
//    V 3-term bf16 transposed+tiled [b][kt][c][32], columns sigma-permuted.
// ---------------------------------------------------------------------------
__global__ __launch_bounds__(256) void k_qkv_split(
    const float* __restrict__ X,
    const float* __restrict__ WQ, const float* __restrict__ WK,
    const float* __restrict__ WV,
    float* __restrict__ Q,
    unsigned short* __restrict__ Kh, unsigned short* __restrict__ Km,
    unsigned short* __restrict__ Kl,
    unsigned short* __restrict__ VhT, unsigned short* __restrict__ VmT,
    unsigned short* __restrict__ VlT) {
  __shared__ float xs[16][64];
  __shared__ unsigned short vs[3][16][64];
  const int c  = threadIdx.x & 63;
  const int tg = threadIdx.x >> 6;
  const size_t t0 = (size_t)blockIdx.x * 16;
  #pragma unroll
  for (int r = tg; r < 16; r += 4)
    xs[r][c] = X[(t0 + r) * 64 + c];
  __syncthreads();
  float qa[4] = {0.f,0.f,0.f,0.f};
  float ka[4] = {0.f,0.f,0.f,0.f};
  float va[4] = {0.f,0.f,0.f,0.f};
  qkv_inner(xs, WQ, WK, WV, c, tg, qa, ka, va);
  #pragma unroll
  for (int pr = 0; pr < 2; ++pr) {
    const int r0 = 2 * pr, r1 = 2 * pr + 1;
    const int ta = tg * 4 + r0, tb = tg * 4 + r1;
    const size_t ia = (t0 + ta) * 64 + c;
    const size_t ib = (t0 + tb) * 64 + c;
    Q[ia] = qa[r0]; Q[ib] = qa[r1];
    unsigned short h0, m0, l0, h1, m1, l1;
    split3_pk2(ka[r0], ka[r1], h0, m0, l0, h1, m1, l1);
    Kh[ia] = h0; Km[ia] = m0; Kl[ia] = l0;
    Kh[ib] = h1; Km[ib] = m1; Kl[ib] = l1;
    split3_pk2(va[r0], va[r1], h0, m0, l0, h1, m1, l1);
    vs[0][ta][c] = h0; vs[1][ta][c] = m0; vs[2][ta][c] = l0;
    vs[0][tb][c] = h1; vs[1][tb][c] = m1; vs[2][tb][c] = l1;
  }
  __syncthreads();
  {
    const int row  = threadIdx.x >> 2;
    const int part = threadIdx.x & 3;
    const size_t bofs = (t0 >> 10) * ((size_t)DIMN * 64);
    const size_t kt   = (t0 & 1023) >> 5;
    const size_t tin  = (size_t)part * 8 + ((t0 & 31) >> 2);   // sigma permute
    unsigned short* dst[3] = {VhT, VmT, VlT};
    #pragma unroll
    for (int term = 0; term < 3; ++term) {
      us4 pk;
      #pragma unroll
      for (int i = 0; i < 4; ++i) pk[i] = vs[term][part * 4 + i][row];
      *(us4*)&dst[term][bofs + kt * 2048 + (size_t)row * 32 + tin] = pk;
    }
  }
}

// ---------------------------------------------------------------------------
// 2b) QKV with FUSED 2-way SPLIT-K MERGE of the previous layer.
// ---------------------------------------------------------------------------
__global__ __launch_bounds__(256) void k_qkv_merge(
    float* __restrict__ X,
    const float* __restrict__ Mp, const float* __restrict__ Lp,
    const float* __restrict__ Op,
    const float* __restrict__ WQ, const float* __restrict__ WK,
    const float* __restrict__ WV,
    float* __restrict__ Q,
    unsigned short* __restrict__ Kh, unsigned short* __restrict__ Km,
    unsigned short* __restrict__ Kl,
    unsigned short* __restrict__ VhT, unsigned short* __restrict__ VmT,
    unsigned short* __restrict__ VlT) {
  __shared__ float xs[16][64];
  __shared__ unsigned short vs[3][16][64];
  const int c  = threadIdx.x & 63;
  const int tg = threadIdx.x >> 6;
  const size_t t0 = (size_t)blockIdx.x * 16;
  #pragma unroll
  for (int r = tg; r < 16; r += 4) {
    const size_t grow = t0 + r;                 // global row 0..32767
    const float m0 = Mp[grow], m1 = Mp[32768 + grow];
    const float l0 = Lp[grow], l1 = Lp[32768 + grow];
    const float mm = fmaxf(m0, m1);
    const float w0 = __expf(m0 - mm), w1 = __expf(m1 - mm);
    const float inv = 1.0f / (l0 * w0 + l1 * w1);
    const float o0 = Op[grow * 64 + c];
    const float o1 = Op[(size_t)2097152 + grow * 64 + c];
    const float xn = X[grow * 64 + c] + (o0 * w0 + o1 * w1) * inv;
    X[grow * 64 + c] = xn;
    xs[r][c] = xn;
  }
  __syncthreads();
  float qa[4] = {0.f,0.f,0.f,0.f};
  float ka[4] = {0.f,0.f,0.f,0.f};
  float va[4] = {0.f,0.f,0.f,0.f};
  qkv_inner(xs, WQ, WK, WV, c, tg, qa, ka, va);
  #pragma unroll
  for (int pr = 0; pr < 2; ++pr) {
    const int r0 = 2 * pr, r1 = 2 * pr + 1;
    const int ta = tg * 4 + r0, tb = tg * 4 + r1;
    const size_t ia = (t0 + ta) * 64 + c;
    const size_t ib = (t0 + tb) * 64 + c;
    Q[ia] = qa[r0]; Q[ib] = qa[r1];
    unsigned short h0, m0, l0, h1, m1, l1;
    split3_pk2(ka[r0], ka[r1], h0, m0, l0, h1, m1, l1);
    Kh[ia] = h0; Km[ia] = m0; Kl[ia] = l0;
    Kh[ib] = h1; Km[ib] = m1; Kl[ib] = l1;
    split3_pk2(va[r0], va[r1], h0, m0, l0, h1, m1, l1);
    vs[0][ta][c] = h0; vs[1][ta][c] = m0; vs[2][ta][c] = l0;
    vs[0][tb][c] = h1; vs[1][tb][c] = m1; vs[2][tb][c] = l1;
  }
  __syncthreads();
  {
    const int row  = threadIdx.x >> 2;
    const int part = threadIdx.x & 3;
    const size_t bofs = (t0 >> 10) * ((size_t)DIMN * 64);
    const size_t kt   = (t0 & 1023) >> 5;
    const size_t tin  = (size_t)part * 8 + ((t0 & 31) >> 2);   // sigma permute
    unsigned short* dst[3] = {VhT, VmT, VlT};
    #pragma unroll
    for (int term = 0; term < 3; ++term) {
      us4 pk;
      #pragma unroll
      for (int i = 0; i < 4; ++i) pk[i] = vs[term][part * 4 + i][row];
      *(us4*)&dst[term][bofs + kt * 2048 + (size_t)row * 32 + tin] = pk;
    }
  }
}

// ---------------------------------------------------------------------------
// 3) MFMA flash attention, SPLIT-K (2 halves), SWAPPED QK^T, TWO Q-TILES per
//    block + DOUBLE-BUFFERED LDS: one barrier per K-tile (was two); the
//    prefetched registers are written to the OTHER buffer after compute
//    issues, so ds_writes hide under MFMA/softmax. Write of buf[cur^1] at
//    iter k races nothing: the barrier at top of iter k proves all reads of
//    buf[cur^1] (iter k-1's compute) finished. Arithmetic round-9 bitwise.
//    LDS 2x29184 = 58368 B -> still 2 blocks/CU.
// ---------------------------------------------------------------------------
__global__ __launch_bounds__(256, 2) void k_attn_sk(
    const float* __restrict__ Qg,
    const unsigned short* __restrict__ Kh, const unsigned short* __restrict__ Km,
    const unsigned short* __restrict__ Kl,
    const unsigned short* __restrict__ VhT, const unsigned short* __restrict__ VmT,
    const unsigned short* __restrict__ VlT,
    float* __restrict__ Mp, float* __restrict__ Lp, float* __restrict__ Op) {
  // per buffer (shorts): Kh 0 | Km 2304 | Kl 4608 | Vh 6912 | Vm 9472 | Vl 12032
  __shared__ __align__(16) unsigned short lds[2][14592];

  const int tid  = threadIdx.x;
  const int w    = tid >> 6;
  const int lane = tid & 63;
  const int ln   = lane & 15;
  const int q    = lane >> 4;

  // XCD-aware swizzle: 512 blocks; batch pinned to one XCD
  const int bid   = blockIdx.x;            // 0..511
  const int xcd   = bid & 7;
  const int seq   = bid >> 3;              // 0..63
  const int b     = xcd * 4 + (seq >> 4);  // 4 batches per XCD
  const int local = seq & 15;
  const int half  = local >> 3;            // K-split half
  const int i0    = (local & 7) * 128;     // Q tile pair base

  const size_t base = (size_t)b * (DIMN * 64);
  const float scale = 0.03125f;

  const int kj = tid >> 3, kg = tid & 7;
  const int vc = tid >> 2, vg = tid & 3;
  const int klo = kj * 72 + kg * 8;
  const int vlo = vc * 40 + vg * 8;

  // ---- Q fragments for both tiles: 3-term split (packed) -------------------
  bf16x8 qh[2][2], qm[2][2], ql[2][2];     // [tile][s]
  #pragma unroll
  for (int t = 0; t < 2; ++t) {
    const int mrow = i0 + 64 * t + 16 * w + ln;
    const float* qp = Qg + base + (size_t)mrow * 64 + 8 * q;
    #pragma unroll
    for (int s = 0; s < 2; ++s) {
      const float4 x0 = ((const float4*)(qp + 32 * s))[0];
      const float4 x1 = ((const float4*)(qp + 32 * s))[1];
      const float xv[8] = {x0.x, x0.y, x0.z, x0.w, x1.x, x1.y, x1.z, x1.w};
      split3_frag(xv, qh[t][s], qm[t][s], ql[t][s]);
    }
  }

  f32x4 O[2][4];
  #pragma unroll
  for (int t = 0; t < 2; ++t)
    #pragma unroll
    for (int ct = 0; ct < 4; ++ct) O[t][ct] = (f32x4){0.f, 0.f, 0.f, 0.f};
  float m_run[2] = {-INFINITY, -INFINITY};
  float l_run[2] = {0.f, 0.f};

  const int kt0 = half * 16;

  // ---- prologue: load first tile and stage into buffer 0 -------------------
  {
    const size_t tof = base + (size_t)kt0 * 2048 + tid * 8;
    const us8 a0 = *(const us8*)&Kh[tof];
    const us8 a1 = *(const us8*)&Km[tof];
    const us8 a2 = *(const us8*)&Kl[tof];
    const us8 b0 = *(const us8*)&VhT[tof];
    const us8 b1 = *(const us8*)&VmT[tof];
    const us8 b2 = *(const us8*)&VlT[tof];
    unsigned short* B = lds[0];
    *(us8*)&B[klo]          = a0;
    *(us8*)&B[2304  + klo]  = a1;
    *(us8*)&B[4608  + klo]  = a2;
    *(us8*)&B[6912  + vlo]  = b0;
    *(us8*)&B[9472  + vlo]  = b1;
    *(us8*)&B[12032 + vlo]  = b2;
  }

  us8 ra0, ra1, ra2, rb0, rb1, rb2;        // prefetch registers

  for (int kt = kt0; kt < kt0 + 16; ++kt) {
    const int cur = (kt - kt0) & 1;
    __syncthreads();   // buf[cur] staged & buf[cur^1] readers (iter-1) done

    // ---- issue next tile's loads; latency hides under compute --------------
    const bool have_next = (kt + 1 < kt0 + 16);
    if (have_next) {
      const size_t tof = base + (size_t)(kt + 1) * 2048 + tid * 8;
      ra0 = *(const us8*)&Kh[tof];
      ra1 = *(const us8*)&Km[tof];
      ra2 = *(const us8*)&Kl[tof];
      rb0 = *(const us8*)&VhT[tof];
      rb1 = *(const us8*)&VmT[tof];
      rb2 = *(const us8*)&VlT[tof];
    }

    const unsigned short* Khs = lds[cur];
    const unsigned short* Kms = lds[cur] + 2304;
    const unsigned short* Kls = lds[cur] + 4608;
    const unsigned short* Vhs = lds[cur] + 6912;
    const unsigned short* Vms = lds[cur] + 9472;
    const unsigned short* Vls = lds[cur] + 12032;

    // ---- S strips = mfma(K, Q_t): K fragments loaded once, used twice ------
    f32x4 sacc[2][2];                       // [tile][ct]
    __builtin_amdgcn_s_setprio(1);
    #pragma unroll
    for (int ct = 0; ct < 2; ++ct) {
      f32x4 aA = (f32x4){0.f, 0.f, 0.f, 0.f};
      f32x4 aB = (f32x4){0.f, 0.f, 0.f, 0.f};
      #pragma unroll
      for (int s = 0; s < 2; ++s) {
        const int ko = (16 * ct + ln) * 72 + 32 * s + 8 * q;
        const bf16x8 bh = ld16B(&Khs[ko]);
        const bf16x8 bm = ld16B(&Kms[ko]);
        const bf16x8 bl = ld16B(&Kls[ko]);
        aA = MFMA16(bh, ql[0][s], aA);
        aA = MFMA16(bl, qh[0][s], aA);
        aA = MFMA16(bm, qm[0][s], aA);
        aA = MFMA16(bh, qm[0][s], aA);
        aA = MFMA16(bm, qh[0][s], aA);
        aA = MFMA16(bh, qh[0][s], aA);
        aB = MFMA16(bh, ql[1][s], aB);
        aB = MFMA16(bl, qh[1][s], aB);
        aB = MFMA16(bm, qm[1][s], aB);
        aB = MFMA16(bh, qm[1][s], aB);
        aB = MFMA16(bm, qh[1][s], aB);
        aB = MFMA16(bh, qh[1][s], aB);
      }
      sacc[0][ct] = aA; sacc[1][ct] = aB;
    }
    __builtin_amdgcn_s_setprio(0);

    // ---- online softmax per tile (one Q-token per lane) --------------------
    bf16x8 ph[2], pm[2], pl[2];
    const int srcb = (lane & 48) + ((lane & 48) >> 2);
    #pragma unroll
    for (int t = 0; t < 2; ++t) {
      float m8 = fmaxf(fmaxf(fmaxf(sacc[t][0][0], sacc[t][0][1]),
                             fmaxf(sacc[t][0][2], sacc[t][0][3])),
                       fmaxf(fmaxf(sacc[t][1][0], sacc[t][1][1]),
                             fmaxf(sacc[t][1][2], sacc[t][1][3])));
      m8 = fmaxf(m8, __shfl_xor(m8, 16, 64));
      m8 = fmaxf(m8, __shfl_xor(m8, 32, 64));
      const float mnew  = fmaxf(m_run[t], m8 * scale);
      const float alpha = __expf(m_run[t] - mnew);
      m_run[t] = mnew;

      float pv[8];
      float s8 = 0.f;
      #pragma unroll
      for (int ct = 0; ct < 2; ++ct) {
        #pragma unroll
        for (int r = 0; r < 4; ++r) {
          const float p = __expf(sacc[t][ct][r] * scale - m_run[t]);
          pv[ct * 4 + r] = p;
          s8 += p;
        }
      }
      float sr = s8 + __shfl_xor(s8, 16, 64);
      sr = sr + __shfl_xor(sr, 32, 64);
      l_run[t] = l_run[t] * alpha + sr;

      float arow[4];
      #pragma unroll
      for (int r = 0; r < 4; ++r) arow[r] = __shfl(alpha, srcb + r, 64);
      #pragma unroll
      for (int ct = 0; ct < 4; ++ct) {
        #pragma unroll
        for (int r = 0; r < 4; ++r) O[t][ct][r] *= arow[r];
      }

      split3_frag(pv, ph[t], pm[t], pl[t]);
    }

    // ---- O += P @ V: V fragments loaded once, used for both tiles ----------
    __builtin_amdgcn_s_setprio(1);
    #pragma unroll
    for (int ct = 0; ct < 4; ++ct) {
      const int vo = (16 * ct + ln) * 40 + 8 * q;
      const bf16x8 vvh = ld16B(&Vhs[vo]);
      const bf16x8 vvm = ld16B(&Vms[vo]);
      const bf16x8 vvl = ld16B(&Vls[vo]);
      O[0][ct] = MFMA16(ph[0], vvh, O[0][ct]);
      O[0][ct] = MFMA16(ph[0], vvm, O[0][ct]);
      O[0][ct] = MFMA16(pm[0], vvh, O[0][ct]);
      O[0][ct] = MFMA16(pm[0], vvm, O[0][ct]);
      O[0][ct] = MFMA16(ph[0], vvl, O[0][ct]);
      O[0][ct] = MFMA16(pl[0], vvh, O[0][ct]);
      O[1][ct] = MFMA16(ph[1], vvh, O[1][ct]);
      O[1][ct] = MFMA16(ph[1], vvm, O[1][ct]);
      O[1][ct] = MFMA16(pm[1], vvh, O[1][ct]);
      O[1][ct] = MFMA16(pm[1], vvm, O[1][ct]);
      O[1][ct] = MFMA16(ph[1], vvl, O[1][ct]);
      O[1][ct] = MFMA16(pl[1], vvh, O[1][ct]);
    }
    __builtin_amdgcn_s_setprio(0);

    // ---- write prefetched tile to the other buffer (hidden under compute) --
    if (have_next) {
      unsigned short* N = lds[cur ^ 1];
      *(us8*)&N[klo]          = ra0;
      *(us8*)&N[2304  + klo]  = ra1;
      *(us8*)&N[4608  + klo]  = ra2;
      *(us8*)&N[6912  + vlo]  = rb0;
      *(us8*)&N[9472  + vlo]  = rb1;
      *(us8*)&N[12032 + vlo]  = rb2;
    }
  }

  // ---- epilogue: write split-K partials (m, l, raw O) for both tiles -------
  const size_t hofs = (size_t)half * (32 * 1024);
  #pragma unroll
  for (int t = 0; t < 2; ++t) {
    const int ti0 = i0 + 64 * t;
    #pragma unroll
    for (int r = 0; r < 4; ++r) {
      const int row = ti0 + 16 * w + 4 * q + r;
      const size_t grow = hofs + (size_t)b * DIMN + row;
      #pragma unroll
      for (int ct = 0; ct < 4; ++ct)
        Op[grow * 64 + ln + 16 * ct] = O[t][ct][r];
    }
    if (q == 0) {
      const size_t tgrow = hofs + (size_t)b * DIMN + ti0 + 16 * w + ln;
      Mp[tgrow] = m_run[t];
      Lp[tgrow] = l_run[t];
    }
  }
}

// ---------------------------------------------------------------------------
// 3b) final merge + channel-mean (layer 7 partials): 256 blocks x 128 tokens
// ---------------------------------------------------------------------------
__global__ __launch_bounds__(256) void k_merge_mean(
    const float* __restrict__ X,
    const float* __restrict__ Mp, const float* __restrict__ Lp,
    const float* __restrict__ Op, float* __restrict__ meanv) {
  const int c  = threadIdx.x & 63;
  const int tg = threadIdx.x >> 6;
  const size_t t0 = (size_t)blockIdx.x * 128;
  for (int i = tg; i < 128; i += 4) {
    const size_t grow = t0 + i;
    const float m0 = Mp[grow], m1 = Mp[32768 + grow];
    const float l0 = Lp[grow], l1 = Lp[32768 + grow];
    const float mm = fmaxf(m0, m1);
    const float w0 = __expf(m0 - mm), w1 = __expf(m1 - mm);
    const float inv = 1.0f / (l0 * w0 + l1 * w1);
    const float o0 = Op[grow * 64 + c];
    const float o1 = Op[(size_t)2097152 + grow * 64 + c];
    float v = X[grow * 64 + c] + (o0 * w0 + o1 * w1) * inv;
    #pragma unroll
    for (int off = 32; off > 0; off >>= 1)
      v += __shfl_down(v, off, 64);
    if (c == 0) meanv[grow] = v * (1.0f / 64.0f);
  }
}

// ---------------------------------------------------------------------------
// 4) head stage 2: pred[b,k] = meanv[b,:] . last_W[k,:] + last_b[k]
// ---------------------------------------------------------------------------
__global__ __launch_bounds__(256) void k_head2(
    const float* __restrict__ meanv, const float* __restrict__ lW,
    const float* __restrict__ lb, float* __restrict__ out) {
  __shared__ float red[256];
  const int b   = blockIdx.x;
  const int tid = threadIdx.x;
  float acc[NCLS];
  #pragma unroll
  for (int k = 0; k < NCLS; ++k) acc[k] = 0.f;
  for (int n = tid; n < DIMN; n += 256) {
    const float m = meanv[(size_t)b * DIMN + n];
    #pragma unroll
    for (int k = 0; k < NCLS; ++k)
      acc[k] = fmaf(m, lW[k * DIMN + n], acc[k]);
  }
  for (int k = 0; k < NCLS; ++k) {
    red[tid] = acc[k];
    __syncthreads();
    for (int s = 128; s > 0; s >>= 1) {
      if (tid < s) red[tid] += red[tid + s];
      __syncthreads();
    }
    if (tid == 0) out[b * NCLS + k] = red[0] + lb[k];
    __syncthreads();
  }
}

// ===========================================================================
// MIDDLE-TIER PATH (ws >= 41 MB but < split-K need): round-4 structure
// ===========================================================================
__global__ __launch_bounds__(256) void k_attn_s(
    const float* __restrict__ Qg,
    const unsigned short* __restrict__ Kh, const unsigned short* __restrict__ Km,
    const unsigned short* __restrict__ Kl,
    const unsigned short* __restrict__ VhT, const unsigned short* __restrict__ VmT,
    const unsigned short* __restrict__ VlT,
    float* __restrict__ X, float* __restrict__ meanout) {
  __shared__ __align__(16) unsigned short Khs[32 * 72];
  __shared__ __align__(16) unsigned short Kms[32 * 72];
  __shared__ __align__(16) unsigned short Kls[32 * 72];
  __shared__ __align__(16) unsigned short Vhs[64 * 40];
  __shared__ __align__(16) unsigned short Vms[64 * 40];
  __shared__ __align__(16) unsigned short Vls[64 * 40];

  const int tid  = threadIdx.x;
  const int w    = tid >> 6;
  const int lane = tid & 63;
  const int ln   = lane & 15;
  const int q    = lane >> 4;
  const int bid = blockIdx.x;
  const int xcd = bid & 7;
  const int seq = bid >> 3;
  const int b   = xcd * 4 + (seq >> 4);
  const int i0  = (seq & 15) * 64;
  const size_t base = (size_t)b * (DIMN * 64);
  const float scale = 0.03125f;

  const int kj = tid >> 3, kg = tid & 7;
  const int vc = tid >> 2, vg = tid & 3;
  const int klo = kj * 72 + kg * 8;
  const int vlo = vc * 40 + vg * 8;

  bf16x8 qh[2], qm[2], ql[2];
  {
    const int mrow = i0 + 16 * w + ln;
    const float* qp = Qg + base + (size_t)mrow * 64 + 8 * q;
    #pragma unroll
    for (int s = 0; s < 2; ++s) {
      const float4 x0 = ((const float4*)(qp + 32 * s))[0];
      const float4 x1 = ((const float4*)(qp + 32 * s))[1];
      const float xv[8] = {x0.x, x0.y, x0.z, x0.w, x1.x, x1.y, x1.z, x1.w};
      split3_frag(xv, qh[s], qm[s], ql[s]);
    }
  }

  f32x4 O[4];
  #pragma unroll
  for (int ct = 0; ct < 4; ++ct) O[ct] = (f32x4){0.f, 0.f, 0.f, 0.f};
  float m_run = -INFINITY;
  float l_run = 0.f;

  for (int kt = 0; kt < 32; ++kt) {
    __syncthreads();
    {
      const size_t tof = base + (size_t)kt * 2048 + tid * 8;
      const us8 a0 = *(const us8*)&Kh[tof];
      const us8 a1 = *(const us8*)&Km[tof];
      const us8 a2 = *(const us8*)&Kl[tof];
      const us8 b0 = *(const us8*)&VhT[tof];
      const us8 b1 = *(const us8*)&VmT[tof];
      const us8 b2 = *(const us8*)&VlT[tof];
      *(us8*)&Khs[klo] = a0;
      *(us8*)&Kms[klo] = a1;
      *(us8*)&Kls[klo] = a2;
      *(us8*)&Vhs[vlo] = b0;
      *(us8*)&Vms[vlo] = b1;
      *(us8*)&Vls[vlo] = b2;
    }
    __syncthreads();

    f32x4 sacc[2];
    #pragma unroll
    for (int ct = 0; ct < 2; ++ct) {
      f32x4 a = (f32x4){0.f, 0.f, 0.f, 0.f};
      #pragma unroll
      for (int s = 0; s < 2; ++s) {
        const int ko = (16 * ct + ln) * 72 + 32 * s + 8 * q;
        const bf16x8 bh = ld16B(&Khs[ko]);
        const bf16x8 bm = ld16B(&Kms[ko]);
        const bf16x8 bl = ld16B(&Kls[ko]);
        a = MFMA16(bh, ql[s], a);
        a = MFMA16(bl, qh[s], a);
        a = MFMA16(bm, qm[s], a);
        a = MFMA16(bh, qm[s], a);
        a = MFMA16(bm, qh[s], a);
        a = MFMA16(bh, qh[s], a);
      }
      sacc[ct] = a;
    }

    float m8 = fmaxf(fmaxf(fmaxf(sacc[0][0], sacc[0][1]),
                           fmaxf(sacc[0][2], sacc[0][3])),
                     fmaxf(fmaxf(sacc[1][0], sacc[1][1]),
                           fmaxf(sacc[1][2], sacc[1][3])));
    m8 = fmaxf(m8, __shfl_xor(m8, 16, 64));
    m8 = fmaxf(m8, __shfl_xor(m8, 32, 64));
    const float mnew  = fmaxf(m_run, m8 * scale);
    const float alpha = __expf(m_run - mnew);
    m_run = mnew;

    float pv[8];
    float s8 = 0.f;
    #pragma unroll
    for (int ct = 0; ct < 2; ++ct) {
      #pragma unroll
      for (int r = 0; r < 4; ++r) {
        const float p = __expf(sacc[ct][r] * scale - m_run);
        pv[ct * 4 + r] = p;
        s8 += p;
      }
    }
    float sr = s8 + __shfl_xor(s8, 16, 64);
    sr = sr + __shfl_xor(sr, 32, 64);
    l_run = l_run * alpha + sr;

    const int srcb = (lane & 48) + ((lane & 48) >> 2);
    float arow[4];
    #pragma unroll
    for (int r = 0; r < 4; ++r) arow[r] = __shfl(alpha, srcb + r, 64);
    #pragma unroll
    for (int ct = 0; ct < 4; ++ct) {
      #pragma unroll
      for (int r = 0; r < 4; ++r) O[ct][r] *= arow[r];
    }

    bf16x8 ph, pm, pl;
    split3_frag(pv, ph, pm, pl);

    #pragma unroll
    for (int ct = 0; ct < 4; ++ct) {
      const int vo = (16 * ct + ln) * 40 + 8 * q;
      const bf16x8 vvh = ld16B(&Vhs[vo]);
      const bf16x8 vvm = ld16B(&Vms[vo]);
      const bf16x8 vvl = ld16B(&Vls[vo]);
      O[ct] = MFMA16(ph, vvh, O[ct]);
      O[ct] = MFMA16(ph, vvm, O[ct]);
      O[ct] = MFMA16(pm, vvh, O[ct]);
      O[ct] = MFMA16(pm, vvm, O[ct]);
      O[ct] = MFMA16(ph, vvl, O[ct]);
      O[ct] = MFMA16(pl, vvh, O[ct]);
    }
  }

  const int srcb = (lane & 48) + ((lane & 48) >> 2);
  float linv[4];
  #pragma unroll
  for (int r = 0; r < 4; ++r) linv[r] = 1.0f / __shfl(l_run, srcb + r, 64);
  #pragma unroll
  for (int r = 0; r < 4; ++r) {
    const int row = i0 + 16 * w + 4 * q + r;
    float srow = 0.f;
    #pragma unroll
    for (int ct = 0; ct < 4; ++ct) {
      float* xp = X + base + (size_t)row * 64 + ln + 16 * ct;
      const float nv = *xp + O[ct][r] * linv[r];
      *xp = nv;
      srow += nv;
    }
    if (meanout) {
      #pragma unroll
      for (int mk = 1; mk <= 8; mk <<= 1)
        srow += __shfl_xor(srow, mk, 64);
      if (ln == 0) meanout[(size_t)b * DIMN + row] = srow * (1.0f / 64.0f);
    }
  }
}

// ---------------------------------------------------------------------------
// launch
// ---------------------------------------------------------------------------
extern "C" void kernel_launch(void* const* d_in, const int* in_sizes, int n_in,
                              void* d_out, int out_size, void* d_ws, size_t ws_size,
                              hipStream_t stream) {
  const float* image = (const float*)d_in[0];
  const float* WV    = (const float*)d_in[1];
  const float* WK    = (const float*)d_in[2];
  const float* WQ    = (const float*)d_in[3];
  const float* lW    = (const float*)d_in[4];
  const float* lb    = (const float*)d_in[5];
  float* out = (float*)d_out;

  float* ws = (float*)d_ws;
  const size_t NELEM = (size_t)BB * DIMN * CCH;   // 2,097,152
  const size_t NROW  = (size_t)BB * DIMN;         // 32,768

  // layout (floats): X | Q | KVsplits(3N) | Op(2N) | Mp(2R) | Lp(2R) | meanv(R)
  const size_t need_sk   = (7 * NELEM + 5 * NROW) * sizeof(float);
  const size_t need_fast = (5 * NELEM + NROW) * sizeof(float);

  if (ws_size >= need_sk) {
    float* X = ws;
    float* Q = ws + NELEM;
    unsigned short* Kh  = (unsigned short*)(ws + 2 * NELEM);
    unsigned short* Km  = Kh + NELEM;
    unsigned short* Kl  = Kh + 2 * NELEM;
    unsigned short* VhT = Kh + 3 * NELEM;
    unsigned short* VmT = Kh + 4 * NELEM;
    unsigned short* VlT = Kh + 5 * NELEM;
    float* Op    = ws + 5 * NELEM;
    float* Mp    = ws + 7 * NELEM;
    float* Lp    = Mp + 2 * NROW;
    float* meanv = Lp + 2 * NROW;

    k_transpose<<<dim3(DIMN / 64, BB), 256, 0, stream>>>(image, X);
    k_qkv_split<<<(BB * DIMN) / 16, 256, 0, stream>>>(
        X, WQ, WK, WV, Q, Kh, Km, Kl, VhT, VmT, VlT);
    for (int layer = 0; layer < 8; ++layer) {
      k_attn_sk<<<512, 256, 0, stream>>>(
          Q, Kh, Km, Kl, VhT, VmT, VlT, Mp, Lp, Op);
      if (layer < 7)
        k_qkv_merge<<<(BB * DIMN) / 16, 256, 0, stream>>>(
            X, Mp, Lp, Op, WQ, WK, WV, Q, Kh, Km, Kl, VhT, VmT, VlT);
    }
    k_merge_mean<<<256, 256, 0, stream>>>(X, Mp, Lp, Op, meanv);
    k_head2<<<BB, 256, 0, stream>>>(meanv, lW, lb, out);
  } else {
    // middle tier
    float* X = ws;
    float* Q = ws + NELEM;
    unsigned short* Kh  = (unsigned short*)(ws + 2 * NELEM);
    unsigned short* Km  = Kh + NELEM;
    unsigned short* Kl  = Kh + 2 * NELEM;
    unsigned short* VhT = Kh + 3 * NELEM;
    unsigned short* VmT = Kh + 4 * NELEM;
    unsigned short* VlT = Kh + 5 * NELEM;
    float* meanv = ws + 5 * NELEM;
    (void)need_fast;

    k_transpose<<<dim3(DIMN / 64, BB), 256, 0, stream>>>(image, X);
    for (int layer = 0; layer < 8; ++layer) {
      k_qkv_split<<<(BB * DIMN) / 16, 256, 0, stream>>>(
          X, WQ, WK, WV, Q, Kh, Km, Kl, VhT, VmT, VlT);
      k_attn_s<<<512, 256, 0, stream>>>(
          Q, Kh, Km, Kl, VhT, VmT, VlT, X, (layer == 7) ? meanv : nullptr);
    }
    k_head2<<<BB, 256, 0, stream>>>(meanv, lW, lb, out);
  }
}

// Round 11
// 656.666 us; speedup vs baseline: 2.0707x; 1.0306x over previous
//
#include <hip/hip_runtime.h>
#include <math.h>

#define BB    32
#define CCH   64
#define DIMN  1024
#define NCLS  10

typedef __attribute__((ext_vector_type(8))) short bf16x8;
typedef __attribute__((ext_vector_type(4))) float f32x4;
typedef __attribute__((ext_vector_type(4))) unsigned short us4;
typedef __attribute__((ext_vector_type(8))) unsigned short us8;

#define MFMA16(a, b, c) __builtin_amdgcn_mfma_f32_16x16x32_bf16(a, b, c, 0, 0, 0)

__device__ __forceinline__ unsigned short f2bf(float x) {
  unsigned u = __float_as_uint(x);
  unsigned r = u + 0x7fffu + ((u >> 16) & 1u);   // round-to-nearest-even
  return (unsigned short)(r >> 16);
}
__device__ __forceinline__ float bf2f(unsigned short h) {
  return __uint_as_float(((unsigned)h) << 16);
}
// packed split3 of TWO floats via v_cvt_pk_bf16_f32 (hardware RNE == f2bf;
// proven bitwise-safe end-to-end in round 3). Results pre-packed lo/hi.
__device__ __forceinline__ void split3_pk(float x0, float x1,
                                          unsigned& hp, unsigned& mp,
                                          unsigned& lp) {
  unsigned h, m, l;
  asm("v_cvt_pk_bf16_f32 %0, %1, %2" : "=v"(h) : "v"(x0), "v"(x1));
  const float h0 = __uint_as_float(h << 16);
  const float h1 = __uint_as_float(h & 0xffff0000u);
  const float r0 = x0 - h0, r1 = x1 - h1;
  asm("v_cvt_pk_bf16_f32 %0, %1, %2" : "=v"(m) : "v"(r0), "v"(r1));
  const float m0 = __uint_as_float(m << 16);
  const float m1 = __uint_as_float(m & 0xffff0000u);
  asm("v_cvt_pk_bf16_f32 %0, %1, %2" : "=v"(l) : "v"(r0 - m0), "v"(r1 - m1));
  hp = h; mp = m; lp = l;
}
// unpacked-output variant for scalar stores (qkv kernels)
__device__ __forceinline__ void split3_pk2(float x0, float x1,
    unsigned short& h0, unsigned short& m0, unsigned short& l0,
    unsigned short& h1, unsigned short& m1, unsigned short& l1) {
  unsigned h, m, l;
  split3_pk(x0, x1, h, m, l);
  h0 = (unsigned short)h; h1 = (unsigned short)(h >> 16);
  m0 = (unsigned short)m; m1 = (unsigned short)(m >> 16);
  l0 = (unsigned short)l; l1 = (unsigned short)(l >> 16);
}
// 8-element fragment split using the packed path (4x split3_pk)
__device__ __forceinline__ void split3_frag(const float* xv, bf16x8& fh,
                                            bf16x8& fm, bf16x8& fl) {
  union U { bf16x8 v; unsigned d[4]; } uh, um, ul;
  #pragma unroll
  for (int p = 0; p < 4; ++p)
    split3_pk(xv[2 * p], xv[2 * p + 1], uh.d[p], um.d[p], ul.d[p]);
  fh = uh.v; fm = um.v; fl = ul.v;
}
__device__ __forceinline__ bf16x8 ld16B(const unsigned short* p) {
  union { us8 u; bf16x8 v; } c;
  c.u = *(const us8*)p;           // 16B-aligned -> ds_read_b128
  return c.v;
}

// ---------------------------------------------------------------------------
// 1) transpose: image (B,C,DIM) -> X (B,DIM,C)
// ---------------------------------------------------------------------------
__global__ __launch_bounds__(256) void k_transpose(const float* __restrict__ img,
                                                   float* __restrict__ X) {
  __shared__ float tile[64][65];
  const int b  = blockIdx.y;
  const int n0 = blockIdx.x * 64;
  const int tx = threadIdx.x & 63;
  const int ty = threadIdx.x >> 6;
  const float* src = img + (size_t)b * CCH * DIMN;
  #pragma unroll
  for (int c = ty; c < 64; c += 4)
    tile[c][tx] = src[(size_t)c * DIMN + n0 + tx];
  __syncthreads();
  float* dst = X + (size_t)b * DIMN * CCH;
  #pragma unroll
  for (int nn = ty; nn < 64; nn += 4)
    dst[(size_t)(n0 + nn) * CCH + tx] = tile[tx][nn];
}

// ---------------------------------------------------------------------------
// qkv compute for 64-token blocks: each thread owns 16 tokens (R=16), so each
// weight load feeds 48 FMAs (was 12) and weight re-streaming drops 4x.
// Per-accumulator FMA order is strictly j-ascending -> bitwise identical.
// ---------------------------------------------------------------------------
__device__ __forceinline__ void qkv_inner16(
    const float xs[64][64],
    const float* __restrict__ WQ, const float* __restrict__ WK,
    const float* __restrict__ WV, int c, int tg,
    float qa[16], float ka[16], float va[16]) {
  for (int j = 0; j < 64; j += 4) {
    float wqv[4], wkv[4], wvv[4];
    #pragma unroll
    for (int jj = 0; jj < 4; ++jj) {
      wqv[jj] = WQ[(j + jj) * 64 + c];
      wkv[jj] = WK[(j + jj) * 64 + c];
      wvv[jj] = WV[(j + jj) * 64 + c];
    }
    #pragma unroll
    for (int r = 0; r < 16; ++r) {
      const float4 xv = *(const float4*)&xs[tg * 16 + r][j];
      #pragma unroll
      for (int jj = 0; jj < 4; ++jj) {
        const float x = ((const float*)&xv)[jj];   // static after unroll
        qa[r] = fmaf(x, wqv[jj], qa[r]);
        ka[r] = fmaf(x, wkv[jj], ka[r]);
        va[r] = fmaf(x, wvv[jj], va[r]);
      }
    }
  }
}

// shared writeback: Q fp32 + K split (global) + V split (to LDS vs)
__device__ __forceinline__ void qkv_store16(
    const float qa[16], const float ka[16], const float va[16],
    unsigned short vs[3][64][64], size_t t0, int c, int tg,
    float* __restrict__ Q,
    unsigned short* __restrict__ Kh, unsigned short* __restrict__ Km,
    unsigned short* __restrict__ Kl) {
  #pragma unroll
  for (int pr = 0; pr < 8; ++pr) {
    const int r0 = 2 * pr, r1 = 2 * pr + 1;
    const int ta = tg * 16 + r0, tb = tg * 16 + r1;
    const size_t ia = (t0 + ta) * 64 + c;
    const size_t ib = (t0 + tb) * 64 + c;
    Q[ia] = qa[r0]; Q[ib] = qa[r1];
    unsigned short h0, m0, l0, h1, m1, l1;
    split3_pk2(ka[r0], ka[r1], h0, m0, l0, h1, m1, l1);
    Kh[ia] = h0; Km[ia] = m0; Kl[ia] = l0;
    Kh[ib] = h1; Km[ib] = m1; Kl[ib] = l1;
    split3_pk2(va[r0], va[r1], h0, m0, l0, h1, m1, l1);
    vs[0][ta][c] = h0; vs[1][ta][c] = m0; vs[2][ta][c] = l0;
    vs[0][tb][c] = h1; vs[1][tb][c] = m1; vs[2][tb][c] = l1;
  }
}

// sigma-permuted V^T writer: the proven 16-token writer looped over 4 slices
__device__ __forceinline__ void v_writer64(
    const unsigned short vs[3][64][64], size_t t0, int tid,
    unsigned short* __restrict__ VhT, unsigned short* __restrict__ VmT,
    unsigned short* __restrict__ VlT) {
  const int row  = tid >> 2;
  const int part = tid & 3;
  const size_t bofs = (t0 >> 10) * ((size_t)DIMN * 64);
  unsigned short* dst[3] = {VhT, VmT, VlT};
  #pragma unroll
  for (int g = 0; g < 4; ++g) {
    const size_t tt = t0 + 16 * g;
    const size_t kt  = (tt & 1023) >> 5;
    const size_t tin = (size_t)part * 8 + ((tt & 31) >> 2);   // sigma permute
    #pragma unroll
    for (int term = 0; term < 3; ++term) {
      us4 pk;
      #pragma unroll
      for (int i = 0; i < 4; ++i)
        pk[i] = vs[term][16 * g + part * 4 + i][row];
      *(us4*)&dst[term][bofs + kt * 2048 + (size_t)row * 32 + tin] = pk;
    }
  }
}

// ---------------------------------------------------------------------------
// 2) QKV + per-layer pre-split (64 tokens/block): Q fp32; K 3-term bf16;
//    V 3-term bf16 transposed+tiled, sigma-permuted.
// ---------------------------------------------------------------------------
__global__ __launch_bounds__(256) void k_qkv_split(
    const float* __restrict__ X,
    const float* __restrict__ WQ, const float* __restrict__ WK,
    const float* __restrict__ WV,
    float* __restrict__ Q,
    unsigned short* __restrict__ Kh, unsigned short* __restrict__ Km,
    unsigned short* __restrict__ Kl,
    unsigned short* __restrict__ VhT, unsigned short* __restrict__ VmT,
    unsigned short* __restrict__ VlT) {
  __shared__ float xs[64][64];
  __shared__ unsigned short vs[3][64][64];
  const int c  = threadIdx.x & 63;
  const int tg = threadIdx.x >> 6;
  const size_t t0 = (size_t)blockIdx.x * 64;
  for (int r = tg; r < 64; r += 4)
    xs[r][c] = X[(t0 + r) * 64 + c];
  __syncthreads();
  float qa[16], ka[16], va[16];
  #pragma unroll
  for (int r = 0; r < 16; ++r) { qa[r] = 0.f; ka[r] = 0.f; va[r] = 0.f; }
  qkv_inner16(xs, WQ, WK, WV, c, tg, qa, ka, va);
  qkv_store16(qa, ka, va, vs, t0, c, tg, Q, Kh, Km, Kl);
  __syncthreads();
  v_writer64(vs, t0, threadIdx.x, VhT, VmT, VlT);
}

// ---------------------------------------------------------------------------
// 2b) QKV with FUSED 2-way SPLIT-K MERGE of the previous layer (64 tok/blk).
// ---------------------------------------------------------------------------
__global__ __launch_bounds__(256) void k_qkv_merge(
    float* __restrict__ X,
    const float* __restrict__ Mp, const float* __restrict__ Lp,
    const float* __restrict__ Op,
    const float* __restrict__ WQ, const float* __restrict__ WK,
    const float* __restrict__ WV,
    float* __restrict__ Q,
    unsigned short* __restrict__ Kh, unsigned short* __restrict__ Km,
    unsigned short* __restrict__ Kl,
    unsigned short* __restrict__ VhT, unsigned short* __restrict__ VmT,
    unsigned short* __restrict__ VlT) {
  __shared__ float xs[64][64];
  __shared__ unsigned short vs[3][64][64];
  const int c  = threadIdx.x & 63;
  const int tg = threadIdx.x >> 6;
  const size_t t0 = (size_t)blockIdx.x * 64;
  for (int r = tg; r < 64; r += 4) {
    const size_t grow = t0 + r;                 // global row 0..32767
    const float m0 = Mp[grow], m1 = Mp[32768 + grow];
    const float l0 = Lp[grow], l1 = Lp[32768 + grow];
    const float mm = fmaxf(m0, m1);
    const float w0 = __expf(m0 - mm), w1 = __expf(m1 - mm);
    const float inv = 1.0f / (l0 * w0 + l1 * w1);
    const float o0 = Op[grow * 64 + c];
    const float o1 = Op[(size_t)2097152 + grow * 64 + c];
    const float xn = X[grow * 64 + c] + (o0 * w0 + o1 * w1) * inv;
    X[grow * 64 + c] = xn;
    xs[r][c] = xn;
  }
  __syncthreads();
  float qa[16], ka[16], va[16];
  #pragma unroll
  for (int r = 0; r < 16; ++r) { qa[r] = 0.f; ka[r] = 0.f; va[r] = 0.f; }
  qkv_inner16(xs, WQ, WK, WV, c, tg, qa, ka, va);
  qkv_store16(qa, ka, va, vs, t0, c, tg, Q, Kh, Km, Kl);
  __syncthreads();
  v_writer64(vs, t0, threadIdx.x, VhT, VmT, VlT);
}

// ---------------------------------------------------------------------------
// 3) MFMA flash attention (round-10 exact: split-K 2, swapped QK^T, 2 Q-tiles,
//    double-buffered LDS, register prefetch, setprio). Verified absmax 0.0.
// ---------------------------------------------------------------------------
__global__ __launch_bounds__(256, 2) void k_attn_sk(
    const float* __restrict__ Qg,
    const unsigned short* __restrict__ Kh, const unsigned short* __restrict__ Km,
    const unsigned short* __restrict__ Kl,
    const unsigned short* __restrict__ VhT, const unsigned short* __restrict__ VmT,
    const unsigned short* __restrict__ VlT,
    float* __restrict__ Mp, float* __restrict__ Lp, float* __restrict__ Op) {
  // per buffer (shorts): Kh 0 | Km 2304 | Kl 4608 | Vh 6912 | Vm 9472 | Vl 12032
  __shared__ __align__(16) unsigned short lds[2][14592];

  const int tid  = threadIdx.x;
  const int w    = tid >> 6;
  const int lane = tid & 63;
  const int ln   = lane & 15;
  const int q    = lane >> 4;

  // XCD-aware swizzle: 512 blocks; batch pinned to one XCD
  const int bid   = blockIdx.x;            // 0..511
  const int xcd   = bid & 7;
  const int seq   = bid >> 3;              // 0..63
  const int b     = xcd * 4 + (seq >> 4);  // 4 batches per XCD
  const int local = seq & 15;
  const int half  = local >> 3;            // K-split half
  const int i0    = (local & 7) * 128;     // Q tile pair base

  const size_t base = (size_t)b * (DIMN * 64);
  const float scale = 0.03125f;

  const int kj = tid >> 3, kg = tid & 7;
  const int vc = tid >> 2, vg = tid & 3;
  const int klo = kj * 72 + kg * 8;
  const int vlo = vc * 40 + vg * 8;

  // ---- Q fragments for both tiles: 3-term split (packed) -------------------
  bf16x8 qh[2][2], qm[2][2], ql[2][2];     // [tile][s]
  #pragma unroll
  for (int t = 0; t < 2; ++t) {
    const int mrow = i0 + 64 * t + 16 * w + ln;
    const float* qp = Qg + base + (size_t)mrow * 64 + 8 * q;
    #pragma unroll
    for (int s = 0; s < 2; ++s) {
      const float4 x0 = ((const float4*)(qp + 32 * s))[0];
      const float4 x1 = ((const float4*)(qp + 32 * s))[1];
      const float xv[8] = {x0.x, x0.y, x0.z, x0.w, x1.x, x1.y, x1.z, x1.w};
      split3_frag(xv, qh[t][s], qm[t][s], ql[t][s]);
    }
  }

  f32x4 O[2][4];
  #pragma unroll
  for (int t = 0; t < 2; ++t)
    #pragma unroll
    for (int ct = 0; ct < 4; ++ct) O[t][ct] = (f32x4){0.f, 0.f, 0.f, 0.f};
  float m_run[2] = {-INFINITY, -INFINITY};
  float l_run[2] = {0.f, 0.f};

  const int kt0 = half * 16;

  // ---- prologue: load first tile and stage into buffer 0 -------------------
  {
    const size_t tof = base + (size_t)kt0 * 2048 + tid * 8;
    const us8 a0 = *(const us8*)&Kh[tof];
    const us8 a1 = *(const us8*)&Km[tof];
    const us8 a2 = *(const us8*)&Kl[tof];
    const us8 b0 = *(const us8*)&VhT[tof];
    const us8 b1 = *(const us8*)&VmT[tof];
    const us8 b2 = *(const us8*)&VlT[tof];
    unsigned short* B = lds[0];
    *(us8*)&B[klo]          = a0;
    *(us8*)&B[2304  + klo]  = a1;
    *(us8*)&B[4608  + klo]  = a2;
    *(us8*)&B[6912  + vlo]  = b0;
    *(us8*)&B[9472  + vlo]  = b1;
    *(us8*)&B[12032 + vlo]  = b2;
  }

  us8 ra0, ra1, ra2, rb0, rb1, rb2;        // prefetch registers

  for (int kt = kt0; kt < kt0 + 16; ++kt) {
    const int cur = (kt - kt0) & 1;
    __syncthreads();   // buf[cur] staged & buf[cur^1] readers (iter-1) done

    // ---- issue next tile's loads; latency hides under compute --------------
    const bool have_next = (kt + 1 < kt0 + 16);
    if (have_next) {
      const size_t tof = base + (size_t)(kt + 1) * 2048 + tid * 8;
      ra0 = *(const us8*)&Kh[tof];
      ra1 = *(const us8*)&Km[tof];
      ra2 = *(const us8*)&Kl[tof];
      rb0 = *(const us8*)&VhT[tof];
      rb1 = *(const us8*)&VmT[tof];
      rb2 = *(const us8*)&VlT[tof];
    }

    const unsigned short* Khs = lds[cur];
    const unsigned short* Kms = lds[cur] + 2304;
    const unsigned short* Kls = lds[cur] + 4608;
    const unsigned short* Vhs = lds[cur] + 6912;
    const unsigned short* Vms = lds[cur] + 9472;
    const unsigned short* Vls = lds[cur] + 12032;

    // ---- S strips = mfma(K, Q_t): K fragments loaded once, used twice ------
    f32x4 sacc[2][2];                       // [tile][ct]
    __builtin_amdgcn_s_setprio(1);
    #pragma unroll
    for (int ct = 0; ct < 2; ++ct) {
      f32x4 aA = (f32x4){0.f, 0.f, 0.f, 0.f};
      f32x4 aB = (f32x4){0.f, 0.f, 0.f, 0.f};
      #pragma unroll
      for (int s = 0; s < 2; ++s) {
        const int ko = (16 * ct + ln) * 72 + 32 * s + 8 * q;
        const bf16x8 bh = ld16B(&Khs[ko]);
        const bf16x8 bm = ld16B(&Kms[ko]);
        const bf16x8 bl = ld16B(&Kls[ko]);
        aA = MFMA16(bh, ql[0][s], aA);
        aA = MFMA16(bl, qh[0][s], aA);
        aA = MFMA16(bm, qm[0][s], aA);
        aA = MFMA16(bh, qm[0][s], aA);
        aA = MFMA16(bm, qh[0][s], aA);
        aA = MFMA16(bh, qh[0][s], aA);
        aB = MFMA16(bh, ql[1][s], aB);
        aB = MFMA16(bl, qh[1][s], aB);
        aB = MFMA16(bm, qm[1][s], aB);
        aB = MFMA16(bh, qm[1][s], aB);
        aB = MFMA16(bm, qh[1][s], aB);
        aB = MFMA16(bh, qh[1][s], aB);
      }
      sacc[0][ct] = aA; sacc[1][ct] = aB;
    }
    __builtin_amdgcn_s_setprio(0);

    // ---- online softmax per tile (one Q-token per lane) --------------------
    bf16x8 ph[2], pm[2], pl[2];
    const int srcb = (lane & 48) + ((lane & 48) >> 2);
    #pragma unroll
    for (int t = 0; t < 2; ++t) {
      float m8 = fmaxf(fmaxf(fmaxf(sacc[t][0][0], sacc[t][0][1]),
                             fmaxf(sacc[t][0][2], sacc[t][0][3])),
                       fmaxf(fmaxf(sacc[t][1][0], sacc[t][1][1]),
                             fmaxf(sacc[t][1][2], sacc[t][1][3])));
      m8 = fmaxf(m8, __shfl_xor(m8, 16, 64));
      m8 = fmaxf(m8, __shfl_xor(m8, 32, 64));
      const float mnew  = fmaxf(m_run[t], m8 * scale);
      const float alpha = __expf(m_run[t] - mnew);
      m_run[t] = mnew;

      float pv[8];
      float s8 = 0.f;
      #pragma unroll
      for (int ct = 0; ct < 2; ++ct) {
        #pragma unroll
        for (int r = 0; r < 4; ++r) {
          const float p = __expf(sacc[t][ct][r] * scale - m_run[t]);
          pv[ct * 4 + r] = p;
          s8 += p;
        }
      }
      float sr = s8 + __shfl_xor(s8, 16, 64);
      sr = sr + __shfl_xor(sr, 32, 64);
      l_run[t] = l_run[t] * alpha + sr;

      float arow[4];
      #pragma unroll
      for (int r = 0; r < 4; ++r) arow[r] = __shfl(alpha, srcb + r, 64);
      #pragma unroll
      for (int ct = 0; ct < 4; ++ct) {
        #pragma unroll
        for (int r = 0; r < 4; ++r) O[t][ct][r] *= arow[r];
      }

      split3_frag(pv, ph[t], pm[t], pl[t]);
    }

    // ---- O += P @ V: V fragments loaded once, used for both tiles ----------
    __builtin_amdgcn_s_setprio(1);
    #pragma unroll
    for (int ct = 0; ct < 4; ++ct) {
      const int vo = (16 * ct + ln) * 40 + 8 * q;
      const bf16x8 vvh = ld16B(&Vhs[vo]);
      const bf16x8 vvm = ld16B(&Vms[vo]);
      const bf16x8 vvl = ld16B(&Vls[vo]);
      O[0][ct] = MFMA16(ph[0], vvh, O[0][ct]);
      O[0][ct] = MFMA16(ph[0], vvm, O[0][ct]);
      O[0][ct] = MFMA16(pm[0], vvh, O[0][ct]);
      O[0][ct] = MFMA16(pm[0], vvm, O[0][ct]);
      O[0][ct] = MFMA16(ph[0], vvl, O[0][ct]);
      O[0][ct] = MFMA16(pl[0], vvh, O[0][ct]);
      O[1][ct] = MFMA16(ph[1], vvh, O[1][ct]);
      O[1][ct] = MFMA16(ph[1], vvm, O[1][ct]);
      O[1][ct] = MFMA16(pm[1], vvh, O[1][ct]);
      O[1][ct] = MFMA16(pm[1], vvm, O[1][ct]);
      O[1][ct] = MFMA16(ph[1], vvl, O[1][ct]);
      O[1][ct] = MFMA16(pl[1], vvh, O[1][ct]);
    }
    __builtin_amdgcn_s_setprio(0);

    // ---- write prefetched tile to the other buffer (hidden under compute) --
    if (have_next) {
      unsigned short* N = lds[cur ^ 1];
      *(us8*)&N[klo]          = ra0;
      *(us8*)&N[2304  + klo]  = ra1;
      *(us8*)&N[4608  + klo]  = ra2;
      *(us8*)&N[6912  + vlo]  = rb0;
      *(us8*)&N[9472  + vlo]  = rb1;
      *(us8*)&N[12032 + vlo]  = rb2;
    }
  }

  // ---- epilogue: write split-K partials (m, l, raw O) for both tiles -------
  const size_t hofs = (size_t)half * (32 * 1024);
  #pragma unroll
  for (int t = 0; t < 2; ++t) {
    const int ti0 = i0 + 64 * t;
    #pragma unroll
    for (int r = 0; r < 4; ++r) {
      const int row = ti0 + 16 * w + 4 * q + r;
      const size_t grow = hofs + (size_t)b * DIMN + row;
      #pragma unroll
      for (int ct = 0; ct < 4; ++ct)
        Op[grow * 64 + ln + 16 * ct] = O[t][ct][r];
    }
    if (q == 0) {
      const size_t tgrow = hofs + (size_t)b * DIMN + ti0 + 16 * w + ln;
      Mp[tgrow] = m_run[t];
      Lp[tgrow] = l_run[t];
    }
  }
}

// ---------------------------------------------------------------------------
// 3b) final merge + channel-mean (layer 7 partials): 256 blocks x 128 tokens
// ---------------------------------------------------------------------------
__global__ __launch_bounds__(256) void k_merge_mean(
    const float* __restrict__ X,
    const float* __restrict__ Mp, const float* __restrict__ Lp,
    const float* __restrict__ Op, float* __restrict__ meanv) {
  const int c  = threadIdx.x & 63;
  const int tg = threadIdx.x >> 6;
  const size_t t0 = (size_t)blockIdx.x * 128;
  for (int i = tg; i < 128; i += 4) {
    const size_t grow = t0 + i;
    const float m0 = Mp[grow], m1 = Mp[32768 + grow];
    const float l0 = Lp[grow], l1 = Lp[32768 + grow];
    const float mm = fmaxf(m0, m1);
    const float w0 = __expf(m0 - mm), w1 = __expf(m1 - mm);
    const float inv = 1.0f / (l0 * w0 + l1 * w1);
    const float o0 = Op[grow * 64 + c];
    const float o1 = Op[(size_t)2097152 + grow * 64 + c];
    float v = X[grow * 64 + c] + (o0 * w0 + o1 * w1) * inv;
    #pragma unroll
    for (int off = 32; off > 0; off >>= 1)
      v += __shfl_down(v, off, 64);
    if (c == 0) meanv[grow] = v * (1.0f / 64.0f);
  }
}

// ---------------------------------------------------------------------------
// 4) head stage 2: pred[b,k] = meanv[b,:] . last_W[k,:] + last_b[k]
// ---------------------------------------------------------------------------
__global__ __launch_bounds__(256) void k_head2(
    const float* __restrict__ meanv, const float* __restrict__ lW,
    const float* __restrict__ lb, float* __restrict__ out) {
  __shared__ float red[256];
  const int b   = blockIdx.x;
  const int tid = threadIdx.x;
  float acc[NCLS];
  #pragma unroll
  for (int k = 0; k < NCLS; ++k) acc[k] = 0.f;
  for (int n = tid; n < DIMN; n += 256) {
    const float m = meanv[(size_t)b * DIMN + n];
    #pragma unroll
    for (int k = 0; k < NCLS; ++k)
      acc[k] = fmaf(m, lW[k * DIMN + n], acc[k]);
  }
  for (int k = 0; k < NCLS; ++k) {
    red[tid] = acc[k];
    __syncthreads();
    for (int s = 128; s > 0; s >>= 1) {
      if (tid < s) red[tid] += red[tid + s];
      __syncthreads();
    }
    if (tid == 0) out[b * NCLS + k] = red[0] + lb[k];
    __syncthreads();
  }
}

// ===========================================================================
// MIDDLE-TIER PATH (ws >= 41 MB but < split-K need): round-4 structure
// ===========================================================================
__global__ __launch_bounds__(256) void k_attn_s(
    const float* __restrict__ Qg,
    const unsigned short* __restrict__ Kh, const unsigned short* __restrict__ Km,
    const unsigned short* __restrict__ Kl,
    const unsigned short* __restrict__ VhT, const unsigned short* __restrict__ VmT,
    const unsigned short* __restrict__ VlT,
    float* __restrict__ X, float* __restrict__ meanout) {
  __shared__ __align__(16) unsigned short Khs[32 * 72];
  __shared__ __align__(16) unsigned short Kms[32 * 72];
  __shared__ __align__(16) unsigned short Kls[32 * 72];
  __shared__ __align__(16) unsigned short Vhs[64 * 40];
  __shared__ __align__(16) unsigned short Vms[64 * 40];
  __shared__ __align__(16) unsigned short Vls[64 * 40];

  const int tid  = threadIdx.x;
  const int w    = tid >> 6;
  const int lane = tid & 63;
  const int ln   = lane & 15;
  const int q    = lane >> 4;
  const int bid = blockIdx.x;
  const int xcd = bid & 7;
  const int seq = bid >> 3;
  const int b   = xcd * 4 + (seq >> 4);
  const int i0  = (seq & 15) * 64;
  const size_t base = (size_t)b * (DIMN * 64);
  const float scale = 0.03125f;

  const int kj = tid >> 3, kg = tid & 7;
  const int vc = tid >> 2, vg = tid & 3;
  const int klo = kj * 72 + kg * 8;
  const int vlo = vc * 40 + vg * 8;

  bf16x8 qh[2], qm[2], ql[2];
  {
    const int mrow = i0 + 16 * w + ln;
    const float* qp = Qg + base + (size_t)mrow * 64 + 8 * q;
    #pragma unroll
    for (int s = 0; s < 2; ++s) {
      const float4 x0 = ((const float4*)(qp + 32 * s))[0];
      const float4 x1 = ((const float4*)(qp + 32 * s))[1];
      const float xv[8] = {x0.x, x0.y, x0.z, x0.w, x1.x, x1.y, x1.z, x1.w};
      split3_frag(xv, qh[s], qm[s], ql[s]);
    }
  }

  f32x4 O[4];
  #pragma unroll
  for (int ct = 0; ct < 4; ++ct) O[ct] = (f32x4){0.f, 0.f, 0.f, 0.f};
  float m_run = -INFINITY;
  float l_run = 0.f;

  for (int kt = 0; kt < 32; ++kt) {
    __syncthreads();
    {
      const size_t tof = base + (size_t)kt * 2048 + tid * 8;
      const us8 a0 = *(const us8*)&Kh[tof];
      const us8 a1 = *(const us8*)&Km[tof];
      const us8 a2 = *(const us8*)&Kl[tof];
      const us8 b0 = *(const us8*)&VhT[tof];
      const us8 b1 = *(const us8*)&VmT[tof];
      const us8 b2 = *(const us8*)&VlT[tof];
      *(us8*)&Khs[klo] = a0;
      *(us8*)&Kms[klo] = a1;
      *(us8*)&Kls[klo] = a2;
      *(us8*)&Vhs[vlo] = b0;
      *(us8*)&Vms[vlo] = b1;
      *(us8*)&Vls[vlo] = b2;
    }
    __syncthreads();

    f32x4 sacc[2];
    #pragma unroll
    for (int ct = 0; ct < 2; ++ct) {
      f32x4 a = (f32x4){0.f, 0.f, 0.f, 0.f};
      #pragma unroll
      for (int s = 0; s < 2; ++s) {
        const int ko = (16 * ct + ln) * 72 + 32 * s + 8 * q;
        const bf16x8 bh = ld16B(&Khs[ko]);
        const bf16x8 bm = ld16B(&Kms[ko]);
        const bf16x8 bl = ld16B(&Kls[ko]);
        a = MFMA16(bh, ql[s], a);
        a = MFMA16(bl, qh[s], a);
        a = MFMA16(bm, qm[s], a);
        a = MFMA16(bh, qm[s], a);
        a = MFMA16(bm, qh[s], a);
        a = MFMA16(bh, qh[s], a);
      }
      sacc[ct] = a;
    }

    float m8 = fmaxf(fmaxf(fmaxf(sacc[0][0], sacc[0][1]),
                           fmaxf(sacc[0][2], sacc[0][3])),
                     fmaxf(fmaxf(sacc[1][0], sacc[1][1]),
                           fmaxf(sacc[1][2], sacc[1][3])));
    m8 = fmaxf(m8, __shfl_xor(m8, 16, 64));
    m8 = fmaxf(m8, __shfl_xor(m8, 32, 64));
    const float mnew  = fmaxf(m_run, m8 * scale);
    const float alpha = __expf(m_run - mnew);
    m_run = mnew;

    float pv[8];
    float s8 = 0.f;
    #pragma unroll
    for (int ct = 0; ct < 2; ++ct) {
      #pragma unroll
      for (int r = 0; r < 4; ++r) {
        const float p = __expf(sacc[ct][r] * scale - m_run);
        pv[ct * 4 + r] = p;
        s8 += p;
      }
    }
    float sr = s8 + __shfl_xor(s8, 16, 64);
    sr = sr + __shfl_xor(sr, 32, 64);
    l_run = l_run * alpha + sr;

    const int srcb = (lane & 48) + ((lane & 48) >> 2);
    float arow[4];
    #pragma unroll
    for (int r = 0; r < 4; ++r) arow[r] = __shfl(alpha, srcb + r, 64);
    #pragma unroll
    for (int ct = 0; ct < 4; ++ct) {
      #pragma unroll
      for (int r = 0; r < 4; ++r) O[ct][r] *= arow[r];
    }

    bf16x8 ph, pm, pl;
    split3_frag(pv, ph, pm, pl);

    #pragma unroll
    for (int ct = 0; ct < 4; ++ct) {
      const int vo = (16 * ct + ln) * 40 + 8 * q;
      const bf16x8 vvh = ld16B(&Vhs[vo]);
      const bf16x8 vvm = ld16B(&Vms[vo]);
      const bf16x8 vvl = ld16B(&Vls[vo]);
      O[ct] = MFMA16(ph, vvh, O[ct]);
      O[ct] = MFMA16(ph, vvm, O[ct]);
      O[ct] = MFMA16(pm, vvh, O[ct]);
      O[ct] = MFMA16(pm, vvm, O[ct]);
      O[ct] = MFMA16(ph, vvl, O[ct]);
      O[ct] = MFMA16(pl, vvh, O[ct]);
    }
  }

  const int srcb = (lane & 48) + ((lane & 48) >> 2);
  float linv[4];
  #pragma unroll
  for (int r = 0; r < 4; ++r) linv[r] = 1.0f / __shfl(l_run, srcb + r, 64);
  #pragma unroll
  for (int r = 0; r < 4; ++r) {
    const int row = i0 + 16 * w + 4 * q + r;
    float srow = 0.f;
    #pragma unroll
    for (int ct = 0; ct < 4; ++ct) {
      float* xp = X + base + (size_t)row * 64 + ln + 16 * ct;
      const float nv = *xp + O[ct][r] * linv[r];
      *xp = nv;
      srow += nv;
    }
    if (meanout) {
      #pragma unroll
      for (int mk = 1; mk <= 8; mk <<= 1)
        srow += __shfl_xor(srow, mk, 64);
      if (ln == 0) meanout[(size_t)b * DIMN + row] = srow * (1.0f / 64.0f);
    }
  }
}

// ---------------------------------------------------------------------------
// launch
// ---------------------------------------------------------------------------
extern "C" void kernel_launch(void* const* d_in, const int* in_sizes, int n_in,
                              void* d_out, int out_size, void* d_ws, size_t ws_size,
                              hipStream_t stream) {
  const float* image = (const float*)d_in[0];
  const float* WV    = (const float*)d_in[1];
  const float* WK    = (const float*)d_in[2];
  const float* WQ    = (const float*)d_in[3];
  const float* lW    = (const float*)d_in[4];
  const float* lb    = (const float*)d_in[5];
  float* out = (float*)d_out;

  float* ws = (float*)d_ws;
  const size_t NELEM = (size_t)BB * DIMN * CCH;   // 2,097,152
  const size_t NROW  = (size_t)BB * DIMN;         // 32,768

  // layout (floats): X | Q | KVsplits(3N) | Op(2N) | Mp(2R) | Lp(2R) | meanv(R)
  const size_t need_sk   = (7 * NELEM + 5 * NROW) * sizeof(float);
  const size_t need_fast = (5 * NELEM + NROW) * sizeof(float);

  if (ws_size >= need_sk) {
    float* X = ws;
    float* Q = ws + NELEM;
    unsigned short* Kh  = (unsigned short*)(ws + 2 * NELEM);
    unsigned short* Km  = Kh + NELEM;
    unsigned short* Kl  = Kh + 2 * NELEM;
    unsigned short* VhT = Kh + 3 * NELEM;
    unsigned short* VmT = Kh + 4 * NELEM;
    unsigned short* VlT = Kh + 5 * NELEM;
    float* Op    = ws + 5 * NELEM;
    float* Mp    = ws + 7 * NELEM;
    float* Lp    = Mp + 2 * NROW;
    float* meanv = Lp + 2 * NROW;

    k_transpose<<<dim3(DIMN / 64, BB), 256, 0, stream>>>(image, X);
    k_qkv_split<<<(BB * DIMN) / 64, 256, 0, stream>>>(
        X, WQ, WK, WV, Q, Kh, Km, Kl, VhT, VmT, VlT);
    for (int layer = 0; layer < 8; ++layer) {
      k_attn_sk<<<512, 256, 0, stream>>>(
          Q, Kh, Km, Kl, VhT, VmT, VlT, Mp, Lp, Op);
      if (layer < 7)
        k_qkv_merge<<<(BB * DIMN) / 64, 256, 0, stream>>>(
            X, Mp, Lp, Op, WQ, WK, WV, Q, Kh, Km, Kl, VhT, VmT, VlT);
    }
    k_merge_mean<<<256, 256, 0, stream>>>(X, Mp, Lp, Op, meanv);
    k_head2<<<BB, 256, 0, stream>>>(meanv, lW, lb, out);
  } else {
    // middle tier
    float* X = ws;
    float* Q = ws + NELEM;
    unsigned short* Kh  = (unsigned short*)(ws + 2 * NELEM);
    unsigned short* Km  = Kh + NELEM;
    unsigned short* Kl  = Kh + 2 * NELEM;
    unsigned short* VhT = Kh + 3 * NELEM;
    unsigned short* VmT = Kh + 4 * NELEM;
    unsigned short* VlT = Kh + 5 * NELEM;
    float* meanv = ws + 5 * NELEM;
    (void)need_fast;

    k_transpose<<<dim3(DIMN / 64, BB), 256, 0, stream>>>(image, X);
    for (int layer = 0; layer < 8; ++layer) {
      k_qkv_split<<<(BB * DIMN) / 64, 256, 0, stream>>>(
          X, WQ, WK, WV, Q, Kh, Km, Kl, VhT, VmT, VlT);
      k_attn_s<<<512, 256, 0, stream>>>(
          Q, Kh, Km, Kl, VhT, VmT, VlT, X, (layer == 7) ? meanv : nullptr);
    }
    k_head2<<<BB, 256, 0, stream>>>(meanv, lW, lb, out);
  }
}